// Round 1
// 1323.151 us; speedup vs baseline: 1.2650x; 1.2650x over previous
//
#include <hip/hip_runtime.h>
#include <hip/hip_bf16.h>
#include <math.h>

#define BB 16
#define TT 1024
#define SS 1024
#define CCH 512
#define EE 768
#define EPSV 1e-15f
#define CLIPV (1.0f - 1e-5f)

#define BM 128
#define BN 128
#define BK 32
#define LDT 40   // LDS row stride in shorts (80 B, 16B-aligned)

typedef __attribute__((ext_vector_type(8))) short short8_t;
typedef __attribute__((ext_vector_type(4))) short short4_t;
typedef __attribute__((ext_vector_type(4))) float floatx4;

union BFU { __hip_bfloat16 b; short s; };

static __device__ __forceinline__ void bsplit(float x, short& h, short& l) {
  BFU u1; u1.b = __float2bfloat16(x);
  float hf = __bfloat162float(u1.b);
  BFU u2; u2.b = __float2bfloat16(x - hf);
  h = u1.s; l = u2.s;
}

__device__ __forceinline__ float block_sum(float v, float* red) {
  int t = threadIdx.x;
  red[t] = v; __syncthreads();
  #pragma unroll
  for (int s = 128; s > 0; s >>= 1) { if (t < s) red[t] += red[t + s]; __syncthreads(); }
  float r = red[0]; __syncthreads();
  return r;
}

__device__ __forceinline__ float block_max(float v, float* red) {
  int t = threadIdx.x;
  red[t] = v; __syncthreads();
  #pragma unroll
  for (int s = 128; s > 0; s >>= 1) { if (t < s) red[t] = fmaxf(red[t], red[t + s]); __syncthreads(); }
  float r = red[0]; __syncthreads();
  return r;
}

// ---------- mask dtype detection + conversion ----------
__global__ void k_maskdet(const unsigned char* __restrict__ mb, int* __restrict__ flag) {
  __shared__ int any;
  if (threadIdx.x == 0) any = 0;
  __syncthreads();
  int local = 0;
  for (int i = threadIdx.x; i < BB * SS; i += 256)
    if ((i & 3) && mb[i]) local = 1;
  if (local) atomicOr(&any, 1);
  __syncthreads();
  if (threadIdx.x == 0) *flag = any;
}

__global__ void k_maskconv(const void* __restrict__ mraw, const int* __restrict__ flag,
                           float* __restrict__ fmask) {
  int i = blockIdx.x * 256 + threadIdx.x;
  if (i >= BB * SS) return;
  int f = *flag;
  int v = f ? (int)((const unsigned char*)mraw)[i] : ((const int*)mraw)[i];
  fmask[i] = v ? 1.0f : 0.0f;
}

// ---------- prep ----------
// one block per output column e; 256 threads stride K; LDS tree reduce.
// (previous version: grid = N/256 blocks with serial K loop -> 0.09% occupancy,
//  latency-bound, ~305 us per launch. This form: N blocks, trip count K/256.)
__global__ void k_colnorm(const float* __restrict__ z, float* __restrict__ zn, int K, int N) {
  __shared__ float red[256];
  int e = blockIdx.x;
  float s = 0.f;
  for (int k = threadIdx.x; k < K; k += 256) {
    float v = z[(long)k * N + e];
    s += v * v;
  }
  s = block_sum(s, red);
  if (threadIdx.x == 0) zn[e] = sqrtf(fmaxf(s, EPSV));
}

__global__ void k_row2(const float* __restrict__ xp, float* __restrict__ out, int D) {
  __shared__ float red[256];
  long row = blockIdx.x;
  float s = 0.f;
  for (int c = threadIdx.x; c < D; c += 256) { float v = xp[row * D + c]; s += v * v; }
  s = block_sum(s, red);
  if (threadIdx.x == 0) out[row] = s;
}

// gamma[b,s] = 2/max(1-|encb row|^2, EPS)
__global__ void k_gamma(const float* __restrict__ encb, float* __restrict__ gam) {
  __shared__ float red[256];
  long row = blockIdx.x;
  int t = threadIdx.x;
  float s2 = 0.f;
  #pragma unroll
  for (int j = 0; j < 3; j++) { float v = encb[row * EE + t + j * 256]; s2 += v * v; }
  s2 = block_sum(s2, red);
  if (t == 0) gam[row] = 2.0f / fmaxf(1.0f - s2, EPSV);
}

// y2a[b,s] = sum_e enc_a[b,e,s]^2  (enc_a is [B,E,S]); grid (S/64, B), 256 thr
__global__ void k_y2b(const float* __restrict__ enca, float* __restrict__ y2a) {
  __shared__ float red[256];
  int b = blockIdx.y, s0 = blockIdx.x * 64;
  int si = threadIdx.x & 63, eg = threadIdx.x >> 6;
  const float* p = enca + (long)b * EE * SS + s0 + si;
  float acc = 0.f;
  for (int e = eg; e < EE; e += 4) { float v = p[(long)e * SS]; acc += v * v; }
  red[threadIdx.x] = acc; __syncthreads();
  if (eg == 0)
    y2a[(long)b * SS + s0 + si] = red[si] + red[si + 64] + red[si + 128] + red[si + 192];
}

__global__ void k_sb(const float* __restrict__ fmask, float* __restrict__ ssb) {
  __shared__ float red[256];
  int b = blockIdx.x;
  float cnt = 0.f;
  for (int s = threadIdx.x; s < SS; s += 256) cnt += fmask[(long)b * SS + s];
  cnt = block_sum(cnt, red);
  if (threadIdx.x == 0) ssb[b] = sqrtf((float)SS - cnt);
}

// ---------- transpose + bf16 hi/lo split (optional per-input-row scale) ----------
// in: [R,C] fp32 (batch stride sin). out: [C,R] bf16 hi/lo (batch stride sout).
// rs: per-input-row scale (rs[z*R + r]) or nullptr. grid (C/32, R/32, B), block (32,8).
__global__ void k_tsp(const float* __restrict__ in, short* __restrict__ oh,
                      short* __restrict__ ol, const float* __restrict__ rs,
                      int R, int C, long sin, long sout) {
  __shared__ float tile[32][33];
  int z = blockIdx.z;
  const float* ib = in + (long)z * sin;
  short* ohb = oh + (long)z * sout;
  short* olb = ol + (long)z * sout;
  int c0 = blockIdx.x * 32, r0 = blockIdx.y * 32;
  int tx = threadIdx.x, ty = threadIdx.y;
  #pragma unroll
  for (int i = 0; i < 4; i++) {
    int rr = ty + i * 8;
    float v = ib[(long)(r0 + rr) * C + c0 + tx];
    if (rs) v *= rs[(long)z * R + r0 + rr];
    tile[rr][tx] = v;
  }
  __syncthreads();
  #pragma unroll
  for (int i = 0; i < 4; i++) {
    int cc = ty + i * 8;
    float v = tile[tx][cc];
    short h, l; bsplit(v, h, l);
    long o = (long)(c0 + cc) * R + r0 + tx;
    ohb[o] = h; olb[o] = l;
  }
}

// ---------- split-bf16 MFMA GEMM:  C = A(f32,[M,K]) @ B, with B given as
// BT hi/lo bf16 in [N,K] layout. EPI=1 fuses the Poincare distance+mask. ----------
template <int EPI>
__global__ __launch_bounds__(256)
void mgemm(const float* __restrict__ A, const short* __restrict__ BTh,
           const short* __restrict__ BTl, float* __restrict__ Cm,
           int M, int N, int K, long sA, long sBT, long sC,
           const float* __restrict__ q2, const float* __restrict__ y2a,
           const float* __restrict__ fmask, const float* __restrict__ scalep) {
  __shared__ short Ah[BM * LDT];
  __shared__ short Al[BM * LDT];
  __shared__ short Bh[BN * LDT];
  __shared__ short Bl[BN * LDT];

  int z = blockIdx.z;
  const float* Ab = A + (long)z * sA;
  const short* Bhb = BTh + (long)z * sBT;
  const short* Blb = BTl + (long)z * sBT;
  float* Cb = Cm + (long)z * sC;
  int m0 = blockIdx.y * BM, n0 = blockIdx.x * BN;
  int t = threadIdx.x;
  int w = t >> 6, l = t & 63;
  int wr = w >> 1, wc = w & 1;
  int quad = l >> 4, lm = l & 15;

  floatx4 acc[4][4];
  #pragma unroll
  for (int i = 0; i < 4; i++)
    #pragma unroll
    for (int j = 0; j < 4; j++) acc[i][j] = (floatx4){0.f, 0.f, 0.f, 0.f};

  for (int k0 = 0; k0 < K; k0 += BK) {
    // stage A (fp32 -> hi/lo bf16)
    #pragma unroll
    for (int u = 0; u < 4; u++) {
      int idx = t + u * 256;
      int row = idx >> 3, c4 = (idx & 7) * 4;
      floatx4 v = *(const floatx4*)&Ab[(long)(m0 + row) * K + k0 + c4];
      short4_t h4, l4;
      #pragma unroll
      for (int c = 0; c < 4; c++) { short hh, ll; bsplit(v[c], hh, ll); h4[c] = hh; l4[c] = ll; }
      *(short4_t*)&Ah[row * LDT + c4] = h4;
      *(short4_t*)&Al[row * LDT + c4] = l4;
    }
    // stage B (already bf16 hi/lo in [N,K])
    #pragma unroll
    for (int u = 0; u < 2; u++) {
      int idx = t + u * 256;
      int row = idx >> 2, c8 = (idx & 3) * 8;
      *(short8_t*)&Bh[row * LDT + c8] = *(const short8_t*)&Bhb[(long)(n0 + row) * K + k0 + c8];
      *(short8_t*)&Bl[row * LDT + c8] = *(const short8_t*)&Blb[(long)(n0 + row) * K + k0 + c8];
    }
    __syncthreads();

    short8_t bfh[4], bfl[4];
    #pragma unroll
    for (int nj = 0; nj < 4; nj++) {
      int n = wc * 64 + nj * 16 + lm;
      bfh[nj] = *(const short8_t*)&Bh[n * LDT + quad * 8];
      bfl[nj] = *(const short8_t*)&Bl[n * LDT + quad * 8];
    }
    #pragma unroll
    for (int mi = 0; mi < 4; mi++) {
      int m = wr * 64 + mi * 16 + lm;
      short8_t afh = *(const short8_t*)&Ah[m * LDT + quad * 8];
      short8_t afl = *(const short8_t*)&Al[m * LDT + quad * 8];
      #pragma unroll
      for (int nj = 0; nj < 4; nj++) {
        acc[mi][nj] = __builtin_amdgcn_mfma_f32_16x16x32_bf16(afh, bfh[nj], acc[mi][nj], 0, 0, 0);
        acc[mi][nj] = __builtin_amdgcn_mfma_f32_16x16x32_bf16(afh, bfl[nj], acc[mi][nj], 0, 0, 0);
        acc[mi][nj] = __builtin_amdgcn_mfma_f32_16x16x32_bf16(afl, bfh[nj], acc[mi][nj], 0, 0, 0);
      }
    }
    __syncthreads();
  }

  float inv_es = 1.0f;
  if constexpr (EPI == 1) inv_es = 1.0f / expf(scalep[0]);

  #pragma unroll
  for (int mi = 0; mi < 4; mi++) {
    #pragma unroll
    for (int r = 0; r < 4; r++) {
      int gm = m0 + wr * 64 + mi * 16 + quad * 4 + r;
      #pragma unroll
      for (int nj = 0; nj < 4; nj++) {
        int gn = n0 + wc * 64 + nj * 16 + lm;
        float c = acc[mi][nj][r];
        if constexpr (EPI == 0) {
          Cb[(long)gm * N + gn] = c;
        } else {
          float xv = q2[(long)z * M + gm];
          float yv = y2a[(long)z * N + gn];
          float num = fmaxf(xv - 2.0f * c + yv, 0.0f);
          float den = fmaxf(1.0f - 2.0f * c + xv * yv, EPSV);
          float mm = sqrtf(num / den);
          float sc = -2.0f * atanhf(fminf(mm, CLIPV)) * inv_es;
          if (fmask[(long)z * N + gn] > 0.5f) sc = -INFINITY;
          Cb[(long)gm * N + gn] = sc;
        }
      }
    }
  }
}

// ---------- q = msm(sqrt(.5), mobius_add(tgt, poincare_linear(x,w_in,b_in))) ----------
__global__ void k_q(float* __restrict__ Q, const float* __restrict__ tgt,
                    const float* __restrict__ bin, const float* __restrict__ znin,
                    const float* __restrict__ x2, float* __restrict__ q2) {
  __shared__ float red[256];
  long row = blockIdx.x;
  int t = threadIdx.x;
  float cx2 = x2[row];
  float dpl = fmaxf(1.0f - cx2, EPSV);

  float wv[3]; float sw2 = 0.f;
  #pragma unroll
  for (int j = 0; j < 3; j++) {
    int e = t + j * 256;
    float zn = znin[e];
    float u = Q[row * EE + e] / zn;
    float r2 = 2.0f * bin[e];
    float nm = 2.0f * u * coshf(r2) - (1.0f + cx2) * sinhf(r2);
    float y = 2.0f * zn * asinhf(nm / dpl);
    wv[j] = sinhf(y);
    sw2 += wv[j] * wv[j];
  }
  sw2 = block_sum(sw2, red);
  float pden = 1.0f + sqrtf(1.0f + sw2);

  float pv[3], tv[3];
  float tp = 0.f, p2 = 0.f, t2 = 0.f;
  #pragma unroll
  for (int j = 0; j < 3; j++) {
    int e = t + j * 256;
    pv[j] = wv[j] / pden;
    tv[j] = tgt[row * EE + e];
    tp += tv[j] * pv[j]; p2 += pv[j] * pv[j]; t2 += tv[j] * tv[j];
  }
  tp = block_sum(tp, red);
  p2 = block_sum(p2, red);
  t2 = block_sum(t2, red);

  float mden = fmaxf(1.0f + 2.0f * tp + t2 * p2, EPSV);
  float cT = 1.0f + 2.0f * tp + p2;
  float cP = 1.0f - t2;
  float av[3]; float n2 = 0.f;
  #pragma unroll
  for (int j = 0; j < 3; j++) { av[j] = (cT * tv[j] + cP * pv[j]) / mden; n2 += av[j] * av[j]; }
  n2 = block_sum(n2, red);

  float n = sqrtf(fmaxf(n2, EPSV));
  float f = tanhf(0.70710678118654752f * atanhf(fminf(n, CLIPV))) / n;
  #pragma unroll
  for (int j = 0; j < 3; j++) { int e = t + j * 256; Q[row * EE + e] = f * av[j]; }
  if (t == 0) q2[row] = f * f * n2;
}

// ---------- softmax in-place; den = sum attn*(gamma-1) ----------
__global__ void k_softmax(float* __restrict__ A, const float* __restrict__ gam,
                          float* __restrict__ denr) {
  __shared__ float red[256];
  long row = blockIdx.x;
  int b = (int)(row / TT);
  int t = threadIdx.x;
  float* rowp = A + row * SS;

  float v[4];
  float mx = -INFINITY;
  #pragma unroll
  for (int j = 0; j < 4; j++) { v[j] = rowp[t + j * 256]; mx = fmaxf(mx, v[j]); }
  mx = block_max(mx, red);
  bool dead = !(mx > -INFINITY) || (mx != mx);
  float sum = 0.f;
  #pragma unroll
  for (int j = 0; j < 4; j++) { v[j] = dead ? 0.f : expf(v[j] - mx); sum += v[j]; }
  sum = block_sum(sum, red);
  float inv = (sum > 0.f) ? 1.0f / sum : 0.f;
  float ds = 0.f;
  #pragma unroll
  for (int j = 0; j < 4; j++) {
    int s = t + j * 256;
    float a = v[j] * inv;
    rowp[s] = a;
    ds += a * (gam[(long)b * SS + s] - 1.0f);
  }
  ds = block_sum(ds, red);
  if (t == 0) denr[row] = (inv == 0.f) ? 1.0f : ds;
}

// ---------- out2 = msm(sqrt(s_b), msm(0.5, nom/den)) ----------
__global__ void k_mid(float* __restrict__ Q, const float* __restrict__ denr,
                      const float* __restrict__ ssb, float* __restrict__ o2) {
  __shared__ float red[256];
  long row = blockIdx.x;
  int b = (int)(row / TT);
  int t = threadIdx.x;
  float d = denr[row];
  if (fabsf(d) < 1e-10f) d = 1e-10f;

  float v[3]; float n2 = 0.f;
  #pragma unroll
  for (int j = 0; j < 3; j++) { int e = t + j * 256; v[j] = Q[row * EE + e] / d; n2 += v[j] * v[j]; }
  n2 = block_sum(n2, red);
  float n = sqrtf(fmaxf(n2, EPSV));
  float f1 = tanhf(0.5f * atanhf(fminf(n, CLIPV))) / n;

  float m2 = 0.f;
  #pragma unroll
  for (int j = 0; j < 3; j++) { v[j] *= f1; m2 += v[j] * v[j]; }
  m2 = block_sum(m2, red);
  float n1 = sqrtf(fmaxf(m2, EPSV));
  float f2 = tanhf(ssb[b] * atanhf(fminf(n1, CLIPV))) / n1;

  float s2 = 0.f;
  #pragma unroll
  for (int j = 0; j < 3; j++) { int e = t + j * 256; v[j] *= f2; s2 += v[j] * v[j]; Q[row * EE + e] = v[j]; }
  s2 = block_sum(s2, red);
  if (t == 0) o2[row] = s2;
}

// ---------- final epilogue ----------
__global__ void k_final(const float* __restrict__ G, const float* __restrict__ xin,
                        const float* __restrict__ bout, const float* __restrict__ znout,
                        const float* __restrict__ x2, const float* __restrict__ o2,
                        float* __restrict__ outp) {
  __shared__ float red[256];
  long row = blockIdx.x;
  int t = threadIdx.x;
  float cx2 = o2[row];
  float dpl = fmaxf(1.0f - cx2, EPSV);

  float wv[2]; float sw2 = 0.f;
  #pragma unroll
  for (int j = 0; j < 2; j++) {
    int c = t + j * 256;
    float zn = znout[c];
    float u = G[row * CCH + c] / zn;
    float r2 = 2.0f * bout[c];
    float nm = 2.0f * u * coshf(r2) - (1.0f + cx2) * sinhf(r2);
    float y = 2.0f * zn * asinhf(nm / dpl);
    wv[j] = sinhf(y);
    sw2 += wv[j] * wv[j];
  }
  sw2 = block_sum(sw2, red);
  float pden = 1.0f + sqrtf(1.0f + sw2);

  float pv[2], xv[2];
  float xp = 0.f, p2 = 0.f;
  #pragma unroll
  for (int j = 0; j < 2; j++) {
    int c = t + j * 256;
    pv[j] = wv[j] / pden;
    xv[j] = xin[row * CCH + c];
    xp += xv[j] * pv[j]; p2 += pv[j] * pv[j];
  }
  xp = block_sum(xp, red);
  p2 = block_sum(p2, red);

  float xx = x2[row];
  float mden = fmaxf(1.0f + 2.0f * xp + xx * p2, EPSV);
  float cX = 1.0f + 2.0f * xp + p2;
  float cP = 1.0f - xx;
  float av[2]; float n2 = 0.f;
  #pragma unroll
  for (int j = 0; j < 2; j++) { av[j] = (cX * xv[j] + cP * pv[j]) / mden; n2 += av[j] * av[j]; }
  n2 = block_sum(n2, red);

  float n = sqrtf(fmaxf(n2, EPSV));
  float f = tanhf(0.70710678118654752f * atanhf(fminf(n, CLIPV))) / n;
  #pragma unroll
  for (int j = 0; j < 2; j++) { int c = t + j * 256; outp[row * CCH + c] = f * av[j]; }
}

extern "C" void kernel_launch(void* const* d_in, const int* in_sizes, int n_in,
                              void* d_out, int out_size, void* d_ws, size_t ws_size,
                              hipStream_t stream) {
  const float* x    = (const float*)d_in[0];
  const float* tgt  = (const float*)d_in[1];
  const float* enca = (const float*)d_in[2];
  const float* encb = (const float*)d_in[3];
  const void*  mraw = d_in[4];
  const float* win  = (const float*)d_in[5];
  const float* bin  = (const float*)d_in[6];
  const float* wout = (const float*)d_in[7];
  const float* bout = (const float*)d_in[8];
  const float* scalep = (const float*)d_in[9];

  float* out_main = (float*)d_out;
  float* out_attn = out_main + (long)BB * TT * CCH;   // [B,T,S] f32 scores->attn

  char* wb = (char*)d_ws;
  const long QW_B   = (long)BB * TT * EE * 4;          // 50.3 MB
  const long TSP_H  = (long)BB * SS * EE * 2;          // 25.2 MB (one bf16 plane)
  float* Qw      = (float*)wb;                  wb += QW_B;
  short* tspH    = (short*)wb;                  wb += TSP_H;
  short* tspL    = (short*)wb;                  wb += TSP_H;
  float* Gw      = (float*)tspH;                // GEMM5 out (33.5MB), after ebT dead
  short* winTh   = (short*)wb;                  wb += (long)CCH * EE * 2;
  short* winTl   = (short*)wb;                  wb += (long)CCH * EE * 2;
  short* woutTh  = (short*)wb;                  wb += (long)EE * CCH * 2;
  short* woutTl  = (short*)wb;                  wb += (long)EE * CCH * 2;
  float* sm      = (float*)wb;
  float* x2a  = sm; sm += BB * TT;
  float* q2a  = sm; sm += BB * TT;
  float* y2a  = sm; sm += BB * SS;
  float* gam  = sm; sm += BB * SS;
  float* denr = sm; sm += BB * TT;
  float* o2a  = sm; sm += BB * TT;
  float* znin = sm; sm += EE;
  float* znout= sm; sm += CCH;
  float* ssb  = sm; sm += BB;
  float* fmask= sm; sm += BB * SS;
  int*   mflag= (int*)sm; sm += 1;

  // mask canonicalization
  k_maskdet<<<1, 256, 0, stream>>>((const unsigned char*)mraw, mflag);
  k_maskconv<<<BB * SS / 256, 256, 0, stream>>>(mraw, mflag, fmask);

  // prep — colnorm now one block per column (was 3/2 blocks total, ~305 us each)
  k_colnorm<<<EE, 256, 0, stream>>>(win, znin, CCH, EE);
  k_colnorm<<<CCH, 256, 0, stream>>>(wout, znout, EE, CCH);
  k_row2<<<BB * TT, 256, 0, stream>>>(x, x2a, CCH);
  k_gamma<<<BB * SS, 256, 0, stream>>>(encb, gam);
  k_y2b<<<dim3(SS / 64, BB), 256, 0, stream>>>(enca, y2a);
  k_sb<<<BB, 256, 0, stream>>>(fmask, ssb);

  // weight transposes + split
  k_tsp<<<dim3(EE / 32, CCH / 32, 1), dim3(32, 8), 0, stream>>>(
      win, winTh, winTl, nullptr, CCH, EE, 0, 0);
  k_tsp<<<dim3(CCH / 32, EE / 32, 1), dim3(32, 8), 0, stream>>>(
      wout, woutTh, woutTl, nullptr, EE, CCH, 0, 0);

  // enc_a [E,S] -> eaT [S,E] hi/lo  (into tsp buffers)
  k_tsp<<<dim3(SS / 32, EE / 32, BB), dim3(32, 8), 0, stream>>>(
      enca, tspH, tspL, nullptr, EE, SS, (long)EE * SS, (long)SS * EE);

  // GEMM1: M1 = x @ w_in -> Qw
  mgemm<0><<<dim3(EE / BN, BB * TT / BM, 1), 256, 0, stream>>>(
      x, winTh, winTl, Qw, BB * TT, EE, CCH, 0, 0, 0,
      nullptr, nullptr, nullptr, nullptr);

  k_q<<<BB * TT, 256, 0, stream>>>(Qw, tgt, bin, znin, x2a, q2a);

  // GEMM2 (batched) + dist epilogue: scores -> out_attn
  mgemm<1><<<dim3(SS / BN, TT / BM, BB), 256, 0, stream>>>(
      Qw, tspH, tspL, out_attn, TT, SS, EE,
      (long)TT * EE, (long)SS * EE, (long)TT * SS, q2a, y2a, fmask, scalep);

  // enc_b [S,E] scaled by gamma -> ebT [E,S] hi/lo (overwrites eaT)
  k_tsp<<<dim3(EE / 32, SS / 32, BB), dim3(32, 8), 0, stream>>>(
      encb, tspH, tspL, gam, SS, EE, (long)SS * EE, (long)EE * SS);

  k_softmax<<<BB * TT, 256, 0, stream>>>(out_attn, gam, denr);

  // GEMM4 (batched): nom = attn @ (gamma*enc_b) -> Qw
  mgemm<0><<<dim3(EE / BN, TT / BM, BB), 256, 0, stream>>>(
      out_attn, tspH, tspL, Qw, TT, EE, SS,
      (long)TT * SS, (long)EE * SS, (long)TT * EE, nullptr, nullptr, nullptr, nullptr);

  k_mid<<<BB * TT, 256, 0, stream>>>(Qw, denr, ssb, o2a);

  // GEMM5: M3 = out2 @ w_out -> Gw (aliases tsp buffers; ebT dead)
  mgemm<0><<<dim3(CCH / BN, BB * TT / BM, 1), 256, 0, stream>>>(
      Qw, woutTh, woutTl, Gw, BB * TT, CCH, EE, 0, 0, 0,
      nullptr, nullptr, nullptr, nullptr);

  k_final<<<BB * TT, 256, 0, stream>>>(Gw, x, bout, znout, x2a, o2a, out_main);
}

// Round 3
// 1267.450 us; speedup vs baseline: 1.3206x; 1.0439x over previous
//
#include <hip/hip_runtime.h>
#include <hip/hip_bf16.h>
#include <math.h>

#define BB 16
#define TT 1024
#define SS 1024
#define CCH 512
#define EE 768
#define EPSV 1e-15f
#define CLIPV (1.0f - 1e-5f)

#define BM 128
#define BN 128
#define BK 32

typedef __attribute__((ext_vector_type(8))) short short8_t;
typedef __attribute__((ext_vector_type(4))) short short4_t;
typedef __attribute__((ext_vector_type(4))) float floatx4;

union BFU { __hip_bfloat16 b; short s; };

static __device__ __forceinline__ void bsplit(float x, short& h, short& l) {
  BFU u1; u1.b = __float2bfloat16(x);
  float hf = __bfloat162float(u1.b);
  BFU u2; u2.b = __float2bfloat16(x - hf);
  h = u1.s; l = u2.s;
}

static __device__ __forceinline__ float bf2f(short s) {
  BFU u; u.s = s; return __bfloat162float(u.b);
}

// async global->LDS, 16 B per lane; LDS dest = wave-uniform base + lane*16
static __device__ __forceinline__ void gl16(const short* g, short* lds_base) {
  __builtin_amdgcn_global_load_lds(
      (const __attribute__((address_space(1))) unsigned int*)g,
      (__attribute__((address_space(3))) unsigned int*)lds_base, 16, 0, 0);
}

__device__ __forceinline__ float block_sum(float v, float* red) {
  int t = threadIdx.x;
  red[t] = v; __syncthreads();
  #pragma unroll
  for (int s = 128; s > 0; s >>= 1) { if (t < s) red[t] += red[t + s]; __syncthreads(); }
  float r = red[0]; __syncthreads();
  return r;
}

__device__ __forceinline__ float block_max(float v, float* red) {
  int t = threadIdx.x;
  red[t] = v; __syncthreads();
  #pragma unroll
  for (int s = 128; s > 0; s >>= 1) { if (t < s) red[t] = fmaxf(red[t], red[t + s]); __syncthreads(); }
  float r = red[0]; __syncthreads();
  return r;
}

// ---------- mask dtype detection + conversion ----------
__global__ void k_maskdet(const unsigned char* __restrict__ mb, int* __restrict__ flag) {
  __shared__ int any;
  if (threadIdx.x == 0) any = 0;
  __syncthreads();
  int local = 0;
  for (int i = threadIdx.x; i < BB * SS; i += 256)
    if ((i & 3) && mb[i]) local = 1;
  if (local) atomicOr(&any, 1);
  __syncthreads();
  if (threadIdx.x == 0) *flag = any;
}

__global__ void k_maskconv(const void* __restrict__ mraw, const int* __restrict__ flag,
                           float* __restrict__ fmask) {
  int i = blockIdx.x * 256 + threadIdx.x;
  if (i >= BB * SS) return;
  int f = *flag;
  int v = f ? (int)((const unsigned char*)mraw)[i] : ((const int*)mraw)[i];
  fmask[i] = v ? 1.0f : 0.0f;
}

// ---------- prep ----------
__global__ void k_colnorm(const float* __restrict__ z, float* __restrict__ zn, int K, int N) {
  __shared__ float red[256];
  int e = blockIdx.x;
  float s = 0.f;
  for (int k = threadIdx.x; k < K; k += 256) {
    float v = z[(long)k * N + e];
    s += v * v;
  }
  s = block_sum(s, red);
  if (threadIdx.x == 0) zn[e] = sqrtf(fmaxf(s, EPSV));
}

__global__ void k_row2(const float* __restrict__ xp, float* __restrict__ out, int D) {
  __shared__ float red[256];
  long row = blockIdx.x;
  float s = 0.f;
  for (int c = threadIdx.x; c < D; c += 256) { float v = xp[row * D + c]; s += v * v; }
  s = block_sum(s, red);
  if (threadIdx.x == 0) out[row] = s;
}

// gamma[b,s] = 2/max(1-|encb row|^2, EPS)
__global__ void k_gamma(const float* __restrict__ encb, float* __restrict__ gam) {
  __shared__ float red[256];
  long row = blockIdx.x;
  int t = threadIdx.x;
  float s2 = 0.f;
  #pragma unroll
  for (int j = 0; j < 3; j++) { float v = encb[row * EE + t + j * 256]; s2 += v * v; }
  s2 = block_sum(s2, red);
  if (t == 0) gam[row] = 2.0f / fmaxf(1.0f - s2, EPSV);
}

// y2a[b,s] = sum_e enc_a[b,e,s]^2  (enc_a is [B,E,S]); grid (S/64, B), 256 thr
__global__ void k_y2b(const float* __restrict__ enca, float* __restrict__ y2a) {
  __shared__ float red[256];
  int b = blockIdx.y, s0 = blockIdx.x * 64;
  int si = threadIdx.x & 63, eg = threadIdx.x >> 6;
  const float* p = enca + (long)b * EE * SS + s0 + si;
  float acc = 0.f;
  for (int e = eg; e < EE; e += 4) { float v = p[(long)e * SS]; acc += v * v; }
  red[threadIdx.x] = acc; __syncthreads();
  if (eg == 0)
    y2a[(long)b * SS + s0 + si] = red[si] + red[si + 64] + red[si + 128] + red[si + 192];
}

__global__ void k_sb(const float* __restrict__ fmask, float* __restrict__ ssb) {
  __shared__ float red[256];
  int b = blockIdx.x;
  float cnt = 0.f;
  for (int s = threadIdx.x; s < SS; s += 256) cnt += fmask[(long)b * SS + s];
  cnt = block_sum(cnt, red);
  if (threadIdx.x == 0) ssb[b] = sqrtf((float)SS - cnt);
}

// ---------- fp32 -> bf16 hi/lo plane split (row-major copy, vectorized) ----------
__global__ void k_split(const float* __restrict__ in, short* __restrict__ oh,
                        short* __restrict__ ol, long n4) {
  long i = (long)blockIdx.x * 256 + threadIdx.x;
  if (i >= n4) return;
  floatx4 v = ((const floatx4*)in)[i];
  short4_t h4, l4;
  #pragma unroll
  for (int c = 0; c < 4; c++) { short hh, ll; bsplit(v[c], hh, ll); h4[c] = hh; l4[c] = ll; }
  ((short4_t*)oh)[i] = h4;
  ((short4_t*)ol)[i] = l4;
}

// ---------- attn f32 reconstruction from hi/lo planes ----------
__global__ void k_rec(const short* __restrict__ ah, const short* __restrict__ al,
                      float* __restrict__ outp, long n4) {
  long i = (long)blockIdx.x * 256 + threadIdx.x;
  if (i >= n4) return;
  short4_t h4 = ((const short4_t*)ah)[i];
  short4_t l4 = ((const short4_t*)al)[i];
  floatx4 r;
  #pragma unroll
  for (int c = 0; c < 4; c++) r[c] = bf2f(h4[c]) + bf2f(l4[c]);
  ((floatx4*)outp)[i] = r;
}

// ---------- transpose + bf16 hi/lo split (optional per-input-row scale) ----------
__global__ void k_tsp(const float* __restrict__ in, short* __restrict__ oh,
                      short* __restrict__ ol, const float* __restrict__ rs,
                      int R, int C, long sin, long sout) {
  __shared__ float tile[32][33];
  int z = blockIdx.z;
  const float* ib = in + (long)z * sin;
  short* ohb = oh + (long)z * sout;
  short* olb = ol + (long)z * sout;
  int c0 = blockIdx.x * 32, r0 = blockIdx.y * 32;
  int tx = threadIdx.x, ty = threadIdx.y;
  #pragma unroll
  for (int i = 0; i < 4; i++) {
    int rr = ty + i * 8;
    float v = ib[(long)(r0 + rr) * C + c0 + tx];
    if (rs) v *= rs[(long)z * R + r0 + rr];
    tile[rr][tx] = v;
  }
  __syncthreads();
  #pragma unroll
  for (int i = 0; i < 4; i++) {
    int cc = ty + i * 8;
    float v = tile[tx][cc];
    short h, l; bsplit(v, h, l);
    long o = (long)(c0 + cc) * R + r0 + tx;
    ohb[o] = h; olb[o] = l;
  }
}

// ---------- split-bf16 MFMA GEMM. A and B both bf16 hi/lo planes, [rows,K]
// K-contiguous. Staging = pure global_load_lds width-16, linear LDS.
// EPI: 0 = f32 store, 1 = Poincare distance+mask epilogue, 2 = hi/lo plane store ----------
template <int EPI>
__global__ __launch_bounds__(256)
void mgemm(const short* __restrict__ Agh, const short* __restrict__ Agl,
           const short* __restrict__ BTh, const short* __restrict__ BTl,
           float* __restrict__ Cm, short* __restrict__ Ch, short* __restrict__ Cl,
           int M, int N, int K, long sA, long sBT, long sC,
           const float* __restrict__ q2, const float* __restrict__ y2a,
           const float* __restrict__ fmask, const float* __restrict__ scalep) {
  __shared__ alignas(16) short Ah[BM * BK];
  __shared__ alignas(16) short Al[BM * BK];
  __shared__ alignas(16) short Bh[BN * BK];
  __shared__ alignas(16) short Bl[BN * BK];

  int z = blockIdx.z;
  const short* Ahb = Agh + (long)z * sA;
  const short* Alb = Agl + (long)z * sA;
  const short* Bhb = BTh + (long)z * sBT;
  const short* Blb = BTl + (long)z * sBT;
  int m0 = blockIdx.y * BM, n0 = blockIdx.x * BN;
  int t = threadIdx.x;
  int w = t >> 6, l = t & 63;
  int wr = w >> 1, wc = w & 1;
  int quad = l >> 4, lm = l & 15;

  // staging geometry: wave w covers tile rows [w*32, w*32+32); issue u covers 16 rows.
  int srow = (w << 5) + (l >> 2);   // + u*16
  int scol = (l & 3) << 3;          // shorts
  short* ldsA_h0 = &Ah[(w << 10)];  // w*1024 shorts = 32 rows
  short* ldsA_l0 = &Al[(w << 10)];
  short* ldsB_h0 = &Bh[(w << 10)];
  short* ldsB_l0 = &Bl[(w << 10)];

  floatx4 acc[4][4];
  #pragma unroll
  for (int i = 0; i < 4; i++)
    #pragma unroll
    for (int j = 0; j < 4; j++) acc[i][j] = (floatx4){0.f, 0.f, 0.f, 0.f};

  for (int k0 = 0; k0 < K; k0 += BK) {
    const short* gAh = Ahb + (long)(m0 + srow) * K + k0 + scol;
    const short* gAl = Alb + (long)(m0 + srow) * K + k0 + scol;
    const short* gBh = Bhb + (long)(n0 + srow) * K + k0 + scol;
    const short* gBl = Blb + (long)(n0 + srow) * K + k0 + scol;
    #pragma unroll
    for (int u = 0; u < 2; u++) {
      long go = (long)(u * 16) * K;
      gl16(gAh + go, ldsA_h0 + (u << 9));
      gl16(gAl + go, ldsA_l0 + (u << 9));
      gl16(gBh + go, ldsB_h0 + (u << 9));
      gl16(gBl + go, ldsB_l0 + (u << 9));
    }
    __syncthreads();   // drains vmcnt(0): tile resident in LDS

    short8_t bfh[4], bfl[4];
    #pragma unroll
    for (int nj = 0; nj < 4; nj++) {
      int n = wc * 64 + nj * 16 + lm;
      bfh[nj] = *(const short8_t*)&Bh[n * BK + quad * 8];
      bfl[nj] = *(const short8_t*)&Bl[n * BK + quad * 8];
    }
    #pragma unroll
    for (int mi = 0; mi < 4; mi++) {
      int m = wr * 64 + mi * 16 + lm;
      short8_t afh = *(const short8_t*)&Ah[m * BK + quad * 8];
      short8_t afl = *(const short8_t*)&Al[m * BK + quad * 8];
      #pragma unroll
      for (int nj = 0; nj < 4; nj++) {
        acc[mi][nj] = __builtin_amdgcn_mfma_f32_16x16x32_bf16(afh, bfh[nj], acc[mi][nj], 0, 0, 0);
        acc[mi][nj] = __builtin_amdgcn_mfma_f32_16x16x32_bf16(afh, bfl[nj], acc[mi][nj], 0, 0, 0);
        acc[mi][nj] = __builtin_amdgcn_mfma_f32_16x16x32_bf16(afl, bfh[nj], acc[mi][nj], 0, 0, 0);
      }
    }
    __syncthreads();   // compute done, safe to overwrite tile
  }

  float* Cb = Cm + (long)z * sC;
  short* Chb = Ch + (long)z * sC;
  short* Clb = Cl + (long)z * sC;
  float inv_es = 1.0f;
  if constexpr (EPI == 1) inv_es = 1.0f / expf(scalep[0]);

  #pragma unroll
  for (int mi = 0; mi < 4; mi++) {
    #pragma unroll
    for (int r = 0; r < 4; r++) {
      int gm = m0 + wr * 64 + mi * 16 + quad * 4 + r;
      #pragma unroll
      for (int nj = 0; nj < 4; nj++) {
        int gn = n0 + wc * 64 + nj * 16 + lm;
        float c = acc[mi][nj][r];
        if constexpr (EPI == 0) {
          Cb[(long)gm * N + gn] = c;
        } else if constexpr (EPI == 2) {
          short hh, ll; bsplit(c, hh, ll);
          Chb[(long)gm * N + gn] = hh;
          Clb[(long)gm * N + gn] = ll;
        } else {
          float xv = q2[(long)z * M + gm];
          float yv = y2a[(long)z * N + gn];
          float num = fmaxf(xv - 2.0f * c + yv, 0.0f);
          float den = fmaxf(1.0f - 2.0f * c + xv * yv, EPSV);
          float mm = sqrtf(num / den);
          float sc = -2.0f * atanhf(fminf(mm, CLIPV)) * inv_es;
          if (fmask[(long)z * N + gn] > 0.5f) sc = -INFINITY;
          Cb[(long)gm * N + gn] = sc;
        }
      }
    }
  }
}

// ---------- q = msm(sqrt(.5), mobius_add(tgt, poincare_linear(x,w_in,b_in))) ----------
// IN-PLACE on hi/lo planes: reads GEMM1 result planes, writes q planes (same rows).
__global__ void k_q(short* gh, short* gl, const float* __restrict__ tgt,
                    const float* __restrict__ bin, const float* __restrict__ znin,
                    const float* __restrict__ x2, float* __restrict__ q2) {
  __shared__ float red[256];
  long row = blockIdx.x;
  int t = threadIdx.x;
  float cx2 = x2[row];
  float dpl = fmaxf(1.0f - cx2, EPSV);

  float wv[3]; float sw2 = 0.f;
  #pragma unroll
  for (int j = 0; j < 3; j++) {
    int e = t + j * 256;
    float zn = znin[e];
    float u = (bf2f(gh[row * EE + e]) + bf2f(gl[row * EE + e])) / zn;
    float r2 = 2.0f * bin[e];
    float nm = 2.0f * u * coshf(r2) - (1.0f + cx2) * sinhf(r2);
    float y = 2.0f * zn * asinhf(nm / dpl);
    wv[j] = sinhf(y);
    sw2 += wv[j] * wv[j];
  }
  sw2 = block_sum(sw2, red);
  float pden = 1.0f + sqrtf(1.0f + sw2);

  float pv[3], tv[3];
  float tp = 0.f, p2 = 0.f, t2 = 0.f;
  #pragma unroll
  for (int j = 0; j < 3; j++) {
    int e = t + j * 256;
    pv[j] = wv[j] / pden;
    tv[j] = tgt[row * EE + e];
    tp += tv[j] * pv[j]; p2 += pv[j] * pv[j]; t2 += tv[j] * tv[j];
  }
  tp = block_sum(tp, red);
  p2 = block_sum(p2, red);
  t2 = block_sum(t2, red);

  float mden = fmaxf(1.0f + 2.0f * tp + t2 * p2, EPSV);
  float cT = 1.0f + 2.0f * tp + p2;
  float cP = 1.0f - t2;
  float av[3]; float n2 = 0.f;
  #pragma unroll
  for (int j = 0; j < 3; j++) { av[j] = (cT * tv[j] + cP * pv[j]) / mden; n2 += av[j] * av[j]; }
  n2 = block_sum(n2, red);

  float n = sqrtf(fmaxf(n2, EPSV));
  float f = tanhf(0.70710678118654752f * atanhf(fminf(n, CLIPV))) / n;
  #pragma unroll
  for (int j = 0; j < 3; j++) {
    int e = t + j * 256;
    short h, lo; bsplit(f * av[j], h, lo);
    gh[row * EE + e] = h; gl[row * EE + e] = lo;
  }
  if (t == 0) q2[row] = f * f * n2;
}

// ---------- softmax: reads f32 scores, writes attn hi/lo planes + den ----------
__global__ void k_softmax(const float* __restrict__ S, const float* __restrict__ gam,
                          float* __restrict__ denr,
                          short* __restrict__ ah, short* __restrict__ al) {
  __shared__ float red[256];
  long row = blockIdx.x;
  int b = (int)(row / TT);
  int t = threadIdx.x;
  const float* rowp = S + row * SS;

  float v[4];
  float mx = -INFINITY;
  #pragma unroll
  for (int j = 0; j < 4; j++) { v[j] = rowp[t + j * 256]; mx = fmaxf(mx, v[j]); }
  mx = block_max(mx, red);
  bool dead = !(mx > -INFINITY) || (mx != mx);
  float sum = 0.f;
  #pragma unroll
  for (int j = 0; j < 4; j++) { v[j] = dead ? 0.f : expf(v[j] - mx); sum += v[j]; }
  sum = block_sum(sum, red);
  float inv = (sum > 0.f) ? 1.0f / sum : 0.f;
  float ds = 0.f;
  #pragma unroll
  for (int j = 0; j < 4; j++) {
    int s = t + j * 256;
    float a = v[j] * inv;
    short h, lo; bsplit(a, h, lo);
    ah[row * SS + s] = h; al[row * SS + s] = lo;
    ds += a * (gam[(long)b * SS + s] - 1.0f);
  }
  ds = block_sum(ds, red);
  if (t == 0) denr[row] = (inv == 0.f) ? 1.0f : ds;
}

// ---------- out2 = msm(sqrt(s_b), msm(0.5, nom/den)) — IN-PLACE on planes ----------
__global__ void k_mid(short* gh, short* gl, const float* __restrict__ denr,
                      const float* __restrict__ ssb, float* __restrict__ o2) {
  __shared__ float red[256];
  long row = blockIdx.x;
  int b = (int)(row / TT);
  int t = threadIdx.x;
  float d = denr[row];
  if (fabsf(d) < 1e-10f) d = 1e-10f;

  float v[3]; float n2 = 0.f;
  #pragma unroll
  for (int j = 0; j < 3; j++) {
    int e = t + j * 256;
    v[j] = (bf2f(gh[row * EE + e]) + bf2f(gl[row * EE + e])) / d;
    n2 += v[j] * v[j];
  }
  n2 = block_sum(n2, red);
  float n = sqrtf(fmaxf(n2, EPSV));
  float f1 = tanhf(0.5f * atanhf(fminf(n, CLIPV))) / n;

  float m2 = 0.f;
  #pragma unroll
  for (int j = 0; j < 3; j++) { v[j] *= f1; m2 += v[j] * v[j]; }
  m2 = block_sum(m2, red);
  float n1 = sqrtf(fmaxf(m2, EPSV));
  float f2 = tanhf(ssb[b] * atanhf(fminf(n1, CLIPV))) / n1;

  float s2 = 0.f;
  #pragma unroll
  for (int j = 0; j < 3; j++) {
    int e = t + j * 256;
    v[j] *= f2; s2 += v[j] * v[j];
    short h, lo; bsplit(v[j], h, lo);
    gh[row * EE + e] = h; gl[row * EE + e] = lo;
  }
  s2 = block_sum(s2, red);
  if (t == 0) o2[row] = s2;
}

// ---------- final epilogue ----------
__global__ void k_final(const float* __restrict__ G, const float* __restrict__ xin,
                        const float* __restrict__ bout, const float* __restrict__ znout,
                        const float* __restrict__ x2, const float* __restrict__ o2,
                        float* __restrict__ outp) {
  __shared__ float red[256];
  long row = blockIdx.x;
  int t = threadIdx.x;
  float cx2 = o2[row];
  float dpl = fmaxf(1.0f - cx2, EPSV);

  float wv[2]; float sw2 = 0.f;
  #pragma unroll
  for (int j = 0; j < 2; j++) {
    int c = t + j * 256;
    float zn = znout[c];
    float u = G[row * CCH + c] / zn;
    float r2 = 2.0f * bout[c];
    float nm = 2.0f * u * coshf(r2) - (1.0f + cx2) * sinhf(r2);
    float y = 2.0f * zn * asinhf(nm / dpl);
    wv[j] = sinhf(y);
    sw2 += wv[j] * wv[j];
  }
  sw2 = block_sum(sw2, red);
  float pden = 1.0f + sqrtf(1.0f + sw2);

  float pv[2], xv[2];
  float xp = 0.f, p2 = 0.f;
  #pragma unroll
  for (int j = 0; j < 2; j++) {
    int c = t + j * 256;
    pv[j] = wv[j] / pden;
    xv[j] = xin[row * CCH + c];
    xp += xv[j] * pv[j]; p2 += pv[j] * pv[j];
  }
  xp = block_sum(xp, red);
  p2 = block_sum(p2, red);

  float xx = x2[row];
  float mden = fmaxf(1.0f + 2.0f * xp + xx * p2, EPSV);
  float cX = 1.0f + 2.0f * xp + p2;
  float cP = 1.0f - xx;
  float av[2]; float n2 = 0.f;
  #pragma unroll
  for (int j = 0; j < 2; j++) { av[j] = (cX * xv[j] + cP * pv[j]) / mden; n2 += av[j] * av[j]; }
  n2 = block_sum(n2, red);

  float n = sqrtf(fmaxf(n2, EPSV));
  float f = tanhf(0.70710678118654752f * atanhf(fminf(n, CLIPV))) / n;
  #pragma unroll
  for (int j = 0; j < 2; j++) { int c = t + j * 256; outp[row * CCH + c] = f * av[j]; }
}

extern "C" void kernel_launch(void* const* d_in, const int* in_sizes, int n_in,
                              void* d_out, int out_size, void* d_ws, size_t ws_size,
                              hipStream_t stream) {
  const float* x    = (const float*)d_in[0];
  const float* tgt  = (const float*)d_in[1];
  const float* enca = (const float*)d_in[2];
  const float* encb = (const float*)d_in[3];
  const void*  mraw = d_in[4];
  const float* win  = (const float*)d_in[5];
  const float* bin  = (const float*)d_in[6];
  const float* wout = (const float*)d_in[7];
  const float* bout = (const float*)d_in[8];
  const float* scalep = (const float*)d_in[9];

  float* out_main = (float*)d_out;                       // [B,T,CCH] f32 (33.55 MB)
  float* out_attn = out_main + (long)BB * TT * CCH;      // [B,T,S]  f32 (67.11 MB)

  // ---- d_out scratch aliases (all dead before their final contents are written) ----
  short* xh  = (short*)out_attn;                         // [B*T,CCH] planes, dead after GEMM1
  short* xl  = xh + (long)BB * TT * CCH;
  short* G4h = (short*)out_attn;                         // [B*T,EE] GEMM4-out planes -> k_mid in-place -> M planes
  short* G4l = G4h + (long)BB * TT * EE;
  short* ATh = (short*)out_main;                         // [B*T,SS] attn hi plane (exact 33.55 MB fit)

  // ---- workspace (104.1 MB total, same budget as the proven R1 layout) ----
  char* wb = (char*)d_ws;
  short* P0   = (short*)wb;  wb += (long)BB * TT * EE * 2;   // 25.17 MB
  short* P1   = (short*)wb;  wb += (long)BB * TT * EE * 2;   // 25.17 MB
  short* G1h = P0, *G1l = P1;        // GEMM1-out planes -> k_q in-place -> q planes
  short* ATl = P0;                   // attn lo plane (33.55 MB, spans P0+part of P1; q dead)
  short* tspH = (short*)wb;  wb += (long)BB * SS * EE * 2;   // 25.17 MB (eaT -> ebT)
  short* tspL = (short*)wb;  wb += (long)BB * SS * EE * 2;   // 25.17 MB
  float* Gw   = (float*)tspH;        // GEMM5 out f32 (33.55 MB <= 50.33; ebT dead)
  short* winTh  = (short*)wb;  wb += (long)CCH * EE * 2;
  short* winTl  = (short*)wb;  wb += (long)CCH * EE * 2;
  short* woutTh = (short*)wb;  wb += (long)EE * CCH * 2;
  short* woutTl = (short*)wb;  wb += (long)EE * CCH * 2;
  float* sm     = (float*)wb;
  float* x2a  = sm; sm += BB * TT;
  float* q2a  = sm; sm += BB * TT;
  float* y2a  = sm; sm += BB * SS;
  float* gam  = sm; sm += BB * SS;
  float* denr = sm; sm += BB * TT;
  float* o2a  = sm; sm += BB * TT;
  float* znin = sm; sm += EE;
  float* znout= sm; sm += CCH;
  float* ssb  = sm; sm += BB;
  float* fmask= sm; sm += BB * SS;
  int*   mflag= (int*)sm; sm += 1;

  // mask canonicalization
  k_maskdet<<<1, 256, 0, stream>>>((const unsigned char*)mraw, mflag);
  k_maskconv<<<BB * SS / 256, 256, 0, stream>>>(mraw, mflag, fmask);

  // prep
  k_colnorm<<<EE, 256, 0, stream>>>(win, znin, CCH, EE);
  k_colnorm<<<CCH, 256, 0, stream>>>(wout, znout, EE, CCH);
  k_row2<<<BB * TT, 256, 0, stream>>>(x, x2a, CCH);
  k_gamma<<<BB * SS, 256, 0, stream>>>(encb, gam);
  k_y2b<<<dim3(SS / 64, BB), 256, 0, stream>>>(enca, y2a);
  k_sb<<<BB, 256, 0, stream>>>(fmask, ssb);

  // weight transposes + split
  k_tsp<<<dim3(EE / 32, CCH / 32, 1), dim3(32, 8), 0, stream>>>(
      win, winTh, winTl, nullptr, CCH, EE, 0, 0);
  k_tsp<<<dim3(CCH / 32, EE / 32, 1), dim3(32, 8), 0, stream>>>(
      wout, woutTh, woutTl, nullptr, EE, CCH, 0, 0);

  // enc_a [E,S] -> eaT [S,E] hi/lo
  k_tsp<<<dim3(SS / 32, EE / 32, BB), dim3(32, 8), 0, stream>>>(
      enca, tspH, tspL, nullptr, EE, SS, (long)EE * SS, (long)SS * EE);

  // x -> hi/lo planes (GEMM1 A), scratch in out_attn region (free until GEMM2)
  k_split<<<(BB * TT * CCH / 4 + 255) / 256, 256, 0, stream>>>(
      x, xh, xl, (long)BB * TT * CCH / 4);

  // GEMM1: x @ w_in -> G1 planes (P0/P1)
  mgemm<2><<<dim3(EE / BN, BB * TT / BM, 1), 256, 0, stream>>>(
      xh, xl, winTh, winTl, nullptr, G1h, G1l, BB * TT, EE, CCH, 0, 0, 0,
      nullptr, nullptr, nullptr, nullptr);

  // k_q: in-place G1 planes -> q planes (+ q2)
  k_q<<<BB * TT, 256, 0, stream>>>(G1h, G1l, tgt, bin, znin, x2a, q2a);

  // GEMM2 (batched) + dist epilogue: scores -> out_attn f32 (x planes dead)
  mgemm<1><<<dim3(SS / BN, TT / BM, BB), 256, 0, stream>>>(
      G1h, G1l, tspH, tspL, out_attn, nullptr, nullptr, TT, SS, EE,
      (long)TT * EE, (long)SS * EE, (long)TT * SS, q2a, y2a, fmask, scalep);

  // enc_b [S,E] scaled by gamma -> ebT [E,S] hi/lo (overwrites eaT)
  k_tsp<<<dim3(EE / 32, SS / 32, BB), dim3(32, 8), 0, stream>>>(
      encb, tspH, tspL, gam, SS, EE, (long)SS * EE, (long)EE * SS);

  // softmax: scores f32 -> attn planes (ATh in out_main, ATl in pool) + denr
  k_softmax<<<BB * TT, 256, 0, stream>>>(out_attn, gam, denr, ATh, ATl);

  // GEMM4 (batched): attn @ (gamma*enc_b) -> G4 planes (out_attn region; scores dead)
  mgemm<2><<<dim3(EE / BN, TT / BM, BB), 256, 0, stream>>>(
      ATh, ATl, tspH, tspL, nullptr, G4h, G4l, TT, EE, SS,
      (long)TT * SS, (long)EE * SS, (long)TT * EE, nullptr, nullptr, nullptr, nullptr);

  // k_mid: in-place G4 planes -> M planes (+ o2)
  k_mid<<<BB * TT, 256, 0, stream>>>(G4h, G4l, denr, ssb, o2a);

  // GEMM5: M @ w_out -> Gw f32 (T region; ebT dead)
  mgemm<0><<<dim3(CCH / BN, BB * TT / BM, 1), 256, 0, stream>>>(
      G4h, G4l, woutTh, woutTl, Gw, nullptr, nullptr, BB * TT, CCH, EE, 0, 0, 0,
      nullptr, nullptr, nullptr, nullptr);

  // reconstruct attn f32 output from planes (M planes dead after GEMM5)
  k_rec<<<(int)((long)BB * TT * SS / 4 / 256), 256, 0, stream>>>(
      ATh, ATl, out_attn, (long)BB * TT * SS / 4);

  // final epilogue (overwrites out_main; ATh dead after k_rec)
  k_final<<<BB * TT, 256, 0, stream>>>(Gw, x, bout, znout, x2a, o2a, out_main);
}

// Round 4
// 1074.870 us; speedup vs baseline: 1.5572x; 1.1792x over previous
//
#include <hip/hip_runtime.h>
#include <hip/hip_bf16.h>
#include <math.h>

#define BB 16
#define TT 1024
#define SS 1024
#define CCH 512
#define EE 768
#define EPSV 1e-15f
#define CLIPV (1.0f - 1e-5f)

#define BM 128
#define BN 128
#define BK 32

typedef __attribute__((ext_vector_type(8))) short short8_t;
typedef __attribute__((ext_vector_type(4))) short short4_t;
typedef __attribute__((ext_vector_type(4))) float floatx4;

union BFU { __hip_bfloat16 b; short s; };

static __device__ __forceinline__ void bsplit(float x, short& h, short& l) {
  BFU u1; u1.b = __float2bfloat16(x);
  float hf = __bfloat162float(u1.b);
  BFU u2; u2.b = __float2bfloat16(x - hf);
  h = u1.s; l = u2.s;
}

static __device__ __forceinline__ float bf2f(short s) {
  BFU u; u.s = s; return __bfloat162float(u.b);
}

// async global->LDS, 16 B per lane; LDS dest = wave-uniform base + lane*16
static __device__ __forceinline__ void gl16(const short* g, short* lds_base) {
  __builtin_amdgcn_global_load_lds(
      (const __attribute__((address_space(1))) unsigned int*)g,
      (__attribute__((address_space(3))) unsigned int*)lds_base, 16, 0, 0);
}

__device__ __forceinline__ float block_sum(float v, float* red) {
  int t = threadIdx.x;
  red[t] = v; __syncthreads();
  #pragma unroll
  for (int s = 128; s > 0; s >>= 1) { if (t < s) red[t] += red[t + s]; __syncthreads(); }
  float r = red[0]; __syncthreads();
  return r;
}

__device__ __forceinline__ float block_max(float v, float* red) {
  int t = threadIdx.x;
  red[t] = v; __syncthreads();
  #pragma unroll
  for (int s = 128; s > 0; s >>= 1) { if (t < s) red[t] = fmaxf(red[t], red[t + s]); __syncthreads(); }
  float r = red[0]; __syncthreads();
  return r;
}

// ---------- mask dtype detection + conversion ----------
__global__ void k_maskdet(const unsigned char* __restrict__ mb, int* __restrict__ flag) {
  __shared__ int any;
  if (threadIdx.x == 0) any = 0;
  __syncthreads();
  int local = 0;
  for (int i = threadIdx.x; i < BB * SS; i += 256)
    if ((i & 3) && mb[i]) local = 1;
  if (local) atomicOr(&any, 1);
  __syncthreads();
  if (threadIdx.x == 0) *flag = any;
}

__global__ void k_maskconv(const void* __restrict__ mraw, const int* __restrict__ flag,
                           float* __restrict__ fmask) {
  int i = blockIdx.x * 256 + threadIdx.x;
  if (i >= BB * SS) return;
  int f = *flag;
  int v = f ? (int)((const unsigned char*)mraw)[i] : ((const int*)mraw)[i];
  fmask[i] = v ? 1.0f : 0.0f;
}

// ---------- prep ----------
__global__ void k_colnorm(const float* __restrict__ z, float* __restrict__ zn, int K, int N) {
  __shared__ float red[256];
  int e = blockIdx.x;
  float s = 0.f;
  for (int k = threadIdx.x; k < K; k += 256) {
    float v = z[(long)k * N + e];
    s += v * v;
  }
  s = block_sum(s, red);
  if (threadIdx.x == 0) zn[e] = sqrtf(fmaxf(s, EPSV));
}

__global__ void k_row2(const float* __restrict__ xp, float* __restrict__ out, int D) {
  __shared__ float red[256];
  long row = blockIdx.x;
  float s = 0.f;
  for (int c = threadIdx.x; c < D; c += 256) { float v = xp[row * D + c]; s += v * v; }
  s = block_sum(s, red);
  if (threadIdx.x == 0) out[row] = s;
}

// gamma[b,s] = 2/max(1-|encb row|^2, EPS)
__global__ void k_gamma(const float* __restrict__ encb, float* __restrict__ gam) {
  __shared__ float red[256];
  long row = blockIdx.x;
  int t = threadIdx.x;
  float s2 = 0.f;
  #pragma unroll
  for (int j = 0; j < 3; j++) { float v = encb[row * EE + t + j * 256]; s2 += v * v; }
  s2 = block_sum(s2, red);
  if (t == 0) gam[row] = 2.0f / fmaxf(1.0f - s2, EPSV);
}

// y2a[b,s] = sum_e enc_a[b,e,s]^2  (enc_a is [B,E,S]); grid (S/64, B), 256 thr
__global__ void k_y2b(const float* __restrict__ enca, float* __restrict__ y2a) {
  __shared__ float red[256];
  int b = blockIdx.y, s0 = blockIdx.x * 64;
  int si = threadIdx.x & 63, eg = threadIdx.x >> 6;
  const float* p = enca + (long)b * EE * SS + s0 + si;
  float acc = 0.f;
  for (int e = eg; e < EE; e += 4) { float v = p[(long)e * SS]; acc += v * v; }
  red[threadIdx.x] = acc; __syncthreads();
  if (eg == 0)
    y2a[(long)b * SS + s0 + si] = red[si] + red[si + 64] + red[si + 128] + red[si + 192];
}

__global__ void k_sb(const float* __restrict__ fmask, float* __restrict__ ssb) {
  __shared__ float red[256];
  int b = blockIdx.x;
  float cnt = 0.f;
  for (int s = threadIdx.x; s < SS; s += 256) cnt += fmask[(long)b * SS + s];
  cnt = block_sum(cnt, red);
  if (threadIdx.x == 0) ssb[b] = sqrtf((float)SS - cnt);
}

// ---------- fp32 -> bf16 hi/lo plane split (row-major copy, vectorized) ----------
__global__ void k_split(const float* __restrict__ in, short* __restrict__ oh,
                        short* __restrict__ ol, long n4) {
  long i = (long)blockIdx.x * 256 + threadIdx.x;
  if (i >= n4) return;
  floatx4 v = ((const floatx4*)in)[i];
  short4_t h4, l4;
  #pragma unroll
  for (int c = 0; c < 4; c++) { short hh, ll; bsplit(v[c], hh, ll); h4[c] = hh; l4[c] = ll; }
  ((short4_t*)oh)[i] = h4;
  ((short4_t*)ol)[i] = l4;
}

// ---------- attn f32 reconstruction from hi/lo planes ----------
__global__ void k_rec(const short* __restrict__ ah, const short* __restrict__ al,
                      float* __restrict__ outp, long n4) {
  long i = (long)blockIdx.x * 256 + threadIdx.x;
  if (i >= n4) return;
  short4_t h4 = ((const short4_t*)ah)[i];
  short4_t l4 = ((const short4_t*)al)[i];
  floatx4 r;
  #pragma unroll
  for (int c = 0; c < 4; c++) r[c] = bf2f(h4[c]) + bf2f(l4[c]);
  ((floatx4*)outp)[i] = r;
}

// ---------- transpose + bf16 hi/lo split (optional per-input-row scale) ----------
__global__ void k_tsp(const float* __restrict__ in, short* __restrict__ oh,
                      short* __restrict__ ol, const float* __restrict__ rs,
                      int R, int C, long sin, long sout) {
  __shared__ float tile[32][33];
  int z = blockIdx.z;
  const float* ib = in + (long)z * sin;
  short* ohb = oh + (long)z * sout;
  short* olb = ol + (long)z * sout;
  int c0 = blockIdx.x * 32, r0 = blockIdx.y * 32;
  int tx = threadIdx.x, ty = threadIdx.y;
  #pragma unroll
  for (int i = 0; i < 4; i++) {
    int rr = ty + i * 8;
    float v = ib[(long)(r0 + rr) * C + c0 + tx];
    if (rs) v *= rs[(long)z * R + r0 + rr];
    tile[rr][tx] = v;
  }
  __syncthreads();
  #pragma unroll
  for (int i = 0; i < 4; i++) {
    int cc = ty + i * 8;
    float v = tile[tx][cc];
    short h, l; bsplit(v, h, l);
    long o = (long)(c0 + cc) * R + r0 + tx;
    ohb[o] = h; olb[o] = l;
  }
}

// ---------- split-bf16 MFMA GEMM, double-buffered (T3-minimum 2-phase).
// A and B both bf16 hi/lo planes, [rows,K] K-contiguous. Staging = pure
// global_load_lds width-16 into linear LDS; stage(t+1) issued BEFORE compute(t),
// ONE barrier per K-step so the vmcnt(0) drain lands after compute has covered
// the load latency. EPI: 0=f32 store, 1=Poincare distance+mask, 2=hi/lo planes. ----------
template <int EPI>
__global__ __launch_bounds__(256)
void mgemm(const short* __restrict__ Agh, const short* __restrict__ Agl,
           const short* __restrict__ BTh, const short* __restrict__ BTl,
           float* __restrict__ Cm, short* __restrict__ Ch, short* __restrict__ Cl,
           int M, int N, int K, long sA, long sBT, long sC,
           const float* __restrict__ q2, const float* __restrict__ y2a,
           const float* __restrict__ fmask, const float* __restrict__ scalep) {
  __shared__ alignas(16) short Ah[2][BM * BK];
  __shared__ alignas(16) short Al[2][BM * BK];
  __shared__ alignas(16) short Bh[2][BN * BK];
  __shared__ alignas(16) short Bl[2][BN * BK];

  // bijective XCD swizzle over the flattened grid (all launches: nwg % 8 == 0).
  // Same-XCD blocks (round-robin on dispatch index) become consecutive tiles ->
  // shared A-panel / neighboring B-panels hit the XCD-private L2.
  int gx = gridDim.x, gy = gridDim.y;
  int nwg = gx * gy * gridDim.z;
  int lin = blockIdx.x + gx * (blockIdx.y + gy * blockIdx.z);
  int swz = (lin & 7) * (nwg >> 3) + (lin >> 3);
  int bx = swz % gx; int tmp = swz / gx; int by = tmp % gy; int bz = tmp / gy;

  int z = bz;
  const short* Ahb = Agh + (long)z * sA;
  const short* Alb = Agl + (long)z * sA;
  const short* Bhb = BTh + (long)z * sBT;
  const short* Blb = BTl + (long)z * sBT;
  int m0 = by * BM, n0 = bx * BN;
  int t = threadIdx.x;
  int w = t >> 6, l = t & 63;
  int wr = w >> 1, wc = w & 1;
  int quad = l >> 4, lm = l & 15;

  // staging geometry: wave w covers tile rows [w*32, w*32+32); issue u covers 16 rows.
  int srow = (w << 5) + (l >> 2);   // + u*16
  int scol = (l & 3) << 3;          // shorts
  int wbase = (w << 10);            // w*1024 shorts = 32 rows in LDS

  auto STAGE = [&](int buf, int kk) {
    const short* gAh = Ahb + (long)(m0 + srow) * K + kk + scol;
    const short* gAl = Alb + (long)(m0 + srow) * K + kk + scol;
    const short* gBh = Bhb + (long)(n0 + srow) * K + kk + scol;
    const short* gBl = Blb + (long)(n0 + srow) * K + kk + scol;
    #pragma unroll
    for (int u = 0; u < 2; u++) {
      long go = (long)(u * 16) * K;
      gl16(gAh + go, &Ah[buf][wbase + (u << 9)]);
      gl16(gAl + go, &Al[buf][wbase + (u << 9)]);
      gl16(gBh + go, &Bh[buf][wbase + (u << 9)]);
      gl16(gBl + go, &Bl[buf][wbase + (u << 9)]);
    }
  };

  floatx4 acc[4][4];
  #pragma unroll
  for (int i = 0; i < 4; i++)
    #pragma unroll
    for (int j = 0; j < 4; j++) acc[i][j] = (floatx4){0.f, 0.f, 0.f, 0.f};

  STAGE(0, 0);
  __syncthreads();   // drain prologue loads: buf0 resident
  int cur = 0;

  for (int k0 = 0; k0 < K; k0 += BK) {
    int nxt = k0 + BK;
    if (nxt < K) STAGE(cur ^ 1, nxt);   // issue next-tile loads (stay in flight)

    short8_t bfh[4], bfl[4];
    #pragma unroll
    for (int nj = 0; nj < 4; nj++) {
      int n = wc * 64 + nj * 16 + lm;
      bfh[nj] = *(const short8_t*)&Bh[cur][n * BK + quad * 8];
      bfl[nj] = *(const short8_t*)&Bl[cur][n * BK + quad * 8];
    }
    #pragma unroll
    for (int mi = 0; mi < 4; mi++) {
      int m = wr * 64 + mi * 16 + lm;
      short8_t afh = *(const short8_t*)&Ah[cur][m * BK + quad * 8];
      short8_t afl = *(const short8_t*)&Al[cur][m * BK + quad * 8];
      #pragma unroll
      for (int nj = 0; nj < 4; nj++) {
        acc[mi][nj] = __builtin_amdgcn_mfma_f32_16x16x32_bf16(afh, bfh[nj], acc[mi][nj], 0, 0, 0);
        acc[mi][nj] = __builtin_amdgcn_mfma_f32_16x16x32_bf16(afh, bfl[nj], acc[mi][nj], 0, 0, 0);
        acc[mi][nj] = __builtin_amdgcn_mfma_f32_16x16x32_bf16(afl, bfh[nj], acc[mi][nj], 0, 0, 0);
      }
    }
    __syncthreads();   // one barrier/K-step: drains next-tile loads (post-compute)
                       // and orders all readers of buf[cur] before its restage
    cur ^= 1;
  }

  float* Cb = Cm + (long)z * sC;
  short* Chb = Ch + (long)z * sC;
  short* Clb = Cl + (long)z * sC;
  float inv_es = 1.0f;
  if constexpr (EPI == 1) inv_es = 1.0f / expf(scalep[0]);

  #pragma unroll
  for (int mi = 0; mi < 4; mi++) {
    #pragma unroll
    for (int r = 0; r < 4; r++) {
      int gm = m0 + wr * 64 + mi * 16 + quad * 4 + r;
      #pragma unroll
      for (int nj = 0; nj < 4; nj++) {
        int gn = n0 + wc * 64 + nj * 16 + lm;
        float c = acc[mi][nj][r];
        if constexpr (EPI == 0) {
          Cb[(long)gm * N + gn] = c;
        } else if constexpr (EPI == 2) {
          short hh, ll; bsplit(c, hh, ll);
          Chb[(long)gm * N + gn] = hh;
          Clb[(long)gm * N + gn] = ll;
        } else {
          float xv = q2[(long)z * M + gm];
          float yv = y2a[(long)z * N + gn];
          float num = fmaxf(xv - 2.0f * c + yv, 0.0f);
          float den = fmaxf(1.0f - 2.0f * c + xv * yv, EPSV);
          float mm = sqrtf(num / den);
          float sc = -2.0f * atanhf(fminf(mm, CLIPV)) * inv_es;
          if (fmask[(long)z * N + gn] > 0.5f) sc = -INFINITY;
          Cb[(long)gm * N + gn] = sc;
        }
      }
    }
  }
}

// ---------- q = msm(sqrt(.5), mobius_add(tgt, poincare_linear(x,w_in,b_in))) ----------
// IN-PLACE on hi/lo planes: reads GEMM1 result planes, writes q planes (same rows).
__global__ void k_q(short* gh, short* gl, const float* __restrict__ tgt,
                    const float* __restrict__ bin, const float* __restrict__ znin,
                    const float* __restrict__ x2, float* __restrict__ q2) {
  __shared__ float red[256];
  long row = blockIdx.x;
  int t = threadIdx.x;
  float cx2 = x2[row];
  float dpl = fmaxf(1.0f - cx2, EPSV);

  float wv[3]; float sw2 = 0.f;
  #pragma unroll
  for (int j = 0; j < 3; j++) {
    int e = t + j * 256;
    float zn = znin[e];
    float u = (bf2f(gh[row * EE + e]) + bf2f(gl[row * EE + e])) / zn;
    float r2 = 2.0f * bin[e];
    float nm = 2.0f * u * coshf(r2) - (1.0f + cx2) * sinhf(r2);
    float y = 2.0f * zn * asinhf(nm / dpl);
    wv[j] = sinhf(y);
    sw2 += wv[j] * wv[j];
  }
  sw2 = block_sum(sw2, red);
  float pden = 1.0f + sqrtf(1.0f + sw2);

  float pv[3], tv[3];
  float tp = 0.f, p2 = 0.f, t2 = 0.f;
  #pragma unroll
  for (int j = 0; j < 3; j++) {
    int e = t + j * 256;
    pv[j] = wv[j] / pden;
    tv[j] = tgt[row * EE + e];
    tp += tv[j] * pv[j]; p2 += pv[j] * pv[j]; t2 += tv[j] * tv[j];
  }
  tp = block_sum(tp, red);
  p2 = block_sum(p2, red);
  t2 = block_sum(t2, red);

  float mden = fmaxf(1.0f + 2.0f * tp + t2 * p2, EPSV);
  float cT = 1.0f + 2.0f * tp + p2;
  float cP = 1.0f - t2;
  float av[3]; float n2 = 0.f;
  #pragma unroll
  for (int j = 0; j < 3; j++) { av[j] = (cT * tv[j] + cP * pv[j]) / mden; n2 += av[j] * av[j]; }
  n2 = block_sum(n2, red);

  float n = sqrtf(fmaxf(n2, EPSV));
  float f = tanhf(0.70710678118654752f * atanhf(fminf(n, CLIPV))) / n;
  #pragma unroll
  for (int j = 0; j < 3; j++) {
    int e = t + j * 256;
    short h, lo; bsplit(f * av[j], h, lo);
    gh[row * EE + e] = h; gl[row * EE + e] = lo;
  }
  if (t == 0) q2[row] = f * f * n2;
}

// ---------- softmax: reads f32 scores, writes attn hi/lo planes + den ----------
__global__ void k_softmax(const float* __restrict__ S, const float* __restrict__ gam,
                          float* __restrict__ denr,
                          short* __restrict__ ah, short* __restrict__ al) {
  __shared__ float red[256];
  long row = blockIdx.x;
  int b = (int)(row / TT);
  int t = threadIdx.x;
  const float* rowp = S + row * SS;

  float v[4];
  float mx = -INFINITY;
  #pragma unroll
  for (int j = 0; j < 4; j++) { v[j] = rowp[t + j * 256]; mx = fmaxf(mx, v[j]); }
  mx = block_max(mx, red);
  bool dead = !(mx > -INFINITY) || (mx != mx);
  float sum = 0.f;
  #pragma unroll
  for (int j = 0; j < 4; j++) { v[j] = dead ? 0.f : expf(v[j] - mx); sum += v[j]; }
  sum = block_sum(sum, red);
  float inv = (sum > 0.f) ? 1.0f / sum : 0.f;
  float ds = 0.f;
  #pragma unroll
  for (int j = 0; j < 4; j++) {
    int s = t + j * 256;
    float a = v[j] * inv;
    short h, lo; bsplit(a, h, lo);
    ah[row * SS + s] = h; al[row * SS + s] = lo;
    ds += a * (gam[(long)b * SS + s] - 1.0f);
  }
  ds = block_sum(ds, red);
  if (t == 0) denr[row] = (inv == 0.f) ? 1.0f : ds;
}

// ---------- out2 = msm(sqrt(s_b), msm(0.5, nom/den)) — IN-PLACE on planes ----------
__global__ void k_mid(short* gh, short* gl, const float* __restrict__ denr,
                      const float* __restrict__ ssb, float* __restrict__ o2) {
  __shared__ float red[256];
  long row = blockIdx.x;
  int b = (int)(row / TT);
  int t = threadIdx.x;
  float d = denr[row];
  if (fabsf(d) < 1e-10f) d = 1e-10f;

  float v[3]; float n2 = 0.f;
  #pragma unroll
  for (int j = 0; j < 3; j++) {
    int e = t + j * 256;
    v[j] = (bf2f(gh[row * EE + e]) + bf2f(gl[row * EE + e])) / d;
    n2 += v[j] * v[j];
  }
  n2 = block_sum(n2, red);
  float n = sqrtf(fmaxf(n2, EPSV));
  float f1 = tanhf(0.5f * atanhf(fminf(n, CLIPV))) / n;

  float m2 = 0.f;
  #pragma unroll
  for (int j = 0; j < 3; j++) { v[j] *= f1; m2 += v[j] * v[j]; }
  m2 = block_sum(m2, red);
  float n1 = sqrtf(fmaxf(m2, EPSV));
  float f2 = tanhf(ssb[b] * atanhf(fminf(n1, CLIPV))) / n1;

  float s2 = 0.f;
  #pragma unroll
  for (int j = 0; j < 3; j++) {
    int e = t + j * 256;
    v[j] *= f2; s2 += v[j] * v[j];
    short h, lo; bsplit(v[j], h, lo);
    gh[row * EE + e] = h; gl[row * EE + e] = lo;
  }
  s2 = block_sum(s2, red);
  if (t == 0) o2[row] = s2;
}

// ---------- final epilogue ----------
__global__ void k_final(const float* __restrict__ G, const float* __restrict__ xin,
                        const float* __restrict__ bout, const float* __restrict__ znout,
                        const float* __restrict__ x2, const float* __restrict__ o2,
                        float* __restrict__ outp) {
  __shared__ float red[256];
  long row = blockIdx.x;
  int t = threadIdx.x;
  float cx2 = o2[row];
  float dpl = fmaxf(1.0f - cx2, EPSV);

  float wv[2]; float sw2 = 0.f;
  #pragma unroll
  for (int j = 0; j < 2; j++) {
    int c = t + j * 256;
    float zn = znout[c];
    float u = G[row * CCH + c] / zn;
    float r2 = 2.0f * bout[c];
    float nm = 2.0f * u * coshf(r2) - (1.0f + cx2) * sinhf(r2);
    float y = 2.0f * zn * asinhf(nm / dpl);
    wv[j] = sinhf(y);
    sw2 += wv[j] * wv[j];
  }
  sw2 = block_sum(sw2, red);
  float pden = 1.0f + sqrtf(1.0f + sw2);

  float pv[2], xv[2];
  float xp = 0.f, p2 = 0.f;
  #pragma unroll
  for (int j = 0; j < 2; j++) {
    int c = t + j * 256;
    pv[j] = wv[j] / pden;
    xv[j] = xin[row * CCH + c];
    xp += xv[j] * pv[j]; p2 += pv[j] * pv[j];
  }
  xp = block_sum(xp, red);
  p2 = block_sum(p2, red);

  float xx = x2[row];
  float mden = fmaxf(1.0f + 2.0f * xp + xx * p2, EPSV);
  float cX = 1.0f + 2.0f * xp + p2;
  float cP = 1.0f - xx;
  float av[2]; float n2 = 0.f;
  #pragma unroll
  for (int j = 0; j < 2; j++) { av[j] = (cX * xv[j] + cP * pv[j]) / mden; n2 += av[j] * av[j]; }
  n2 = block_sum(n2, red);

  float n = sqrtf(fmaxf(n2, EPSV));
  float f = tanhf(0.70710678118654752f * atanhf(fminf(n, CLIPV))) / n;
  #pragma unroll
  for (int j = 0; j < 2; j++) { int c = t + j * 256; outp[row * CCH + c] = f * av[j]; }
}

extern "C" void kernel_launch(void* const* d_in, const int* in_sizes, int n_in,
                              void* d_out, int out_size, void* d_ws, size_t ws_size,
                              hipStream_t stream) {
  const float* x    = (const float*)d_in[0];
  const float* tgt  = (const float*)d_in[1];
  const float* enca = (const float*)d_in[2];
  const float* encb = (const float*)d_in[3];
  const void*  mraw = d_in[4];
  const float* win  = (const float*)d_in[5];
  const float* bin  = (const float*)d_in[6];
  const float* wout = (const float*)d_in[7];
  const float* bout = (const float*)d_in[8];
  const float* scalep = (const float*)d_in[9];

  float* out_main = (float*)d_out;                       // [B,T,CCH] f32 (33.55 MB)
  float* out_attn = out_main + (long)BB * TT * CCH;      // [B,T,S]  f32 (67.11 MB)

  // ---- d_out scratch aliases (all dead before their final contents are written) ----
  short* xh  = (short*)out_attn;                         // [B*T,CCH] planes, dead after GEMM1
  short* xl  = xh + (long)BB * TT * CCH;
  short* G4h = (short*)out_attn;                         // [B*T,EE] GEMM4-out planes -> k_mid in-place -> M planes
  short* G4l = G4h + (long)BB * TT * EE;
  short* ATh = (short*)out_main;                         // [B*T,SS] attn hi plane (exact 33.55 MB fit)

  // ---- workspace (104.1 MB total, proven budget) ----
  char* wb = (char*)d_ws;
  short* P0   = (short*)wb;  wb += (long)BB * TT * EE * 2;   // 25.17 MB
  short* P1   = (short*)wb;  wb += (long)BB * TT * EE * 2;   // 25.17 MB
  short* G1h = P0, *G1l = P1;        // GEMM1-out planes -> k_q in-place -> q planes
  short* ATl = P0;                   // attn lo plane (33.55 MB, spans P0+part of P1; q dead)
  short* tspH = (short*)wb;  wb += (long)BB * SS * EE * 2;   // 25.17 MB (eaT -> ebT)
  short* tspL = (short*)wb;  wb += (long)BB * SS * EE * 2;   // 25.17 MB
  float* Gw   = (float*)tspH;        // GEMM5 out f32 (33.55 MB <= 50.33; ebT dead)
  short* winTh  = (short*)wb;  wb += (long)CCH * EE * 2;
  short* winTl  = (short*)wb;  wb += (long)CCH * EE * 2;
  short* woutTh = (short*)wb;  wb += (long)EE * CCH * 2;
  short* woutTl = (short*)wb;  wb += (long)EE * CCH * 2;
  float* sm     = (float*)wb;
  float* x2a  = sm; sm += BB * TT;
  float* q2a  = sm; sm += BB * TT;
  float* y2a  = sm; sm += BB * SS;
  float* gam  = sm; sm += BB * SS;
  float* denr = sm; sm += BB * TT;
  float* o2a  = sm; sm += BB * TT;
  float* znin = sm; sm += EE;
  float* znout= sm; sm += CCH;
  float* ssb  = sm; sm += BB;
  float* fmask= sm; sm += BB * SS;
  int*   mflag= (int*)sm; sm += 1;

  // mask canonicalization
  k_maskdet<<<1, 256, 0, stream>>>((const unsigned char*)mraw, mflag);
  k_maskconv<<<BB * SS / 256, 256, 0, stream>>>(mraw, mflag, fmask);

  // prep
  k_colnorm<<<EE, 256, 0, stream>>>(win, znin, CCH, EE);
  k_colnorm<<<CCH, 256, 0, stream>>>(wout, znout, EE, CCH);
  k_row2<<<BB * TT, 256, 0, stream>>>(x, x2a, CCH);
  k_gamma<<<BB * SS, 256, 0, stream>>>(encb, gam);
  k_y2b<<<dim3(SS / 64, BB), 256, 0, stream>>>(enca, y2a);
  k_sb<<<BB, 256, 0, stream>>>(fmask, ssb);

  // weight transposes + split
  k_tsp<<<dim3(EE / 32, CCH / 32, 1), dim3(32, 8), 0, stream>>>(
      win, winTh, winTl, nullptr, CCH, EE, 0, 0);
  k_tsp<<<dim3(CCH / 32, EE / 32, 1), dim3(32, 8), 0, stream>>>(
      wout, woutTh, woutTl, nullptr, EE, CCH, 0, 0);

  // enc_a [E,S] -> eaT [S,E] hi/lo
  k_tsp<<<dim3(SS / 32, EE / 32, BB), dim3(32, 8), 0, stream>>>(
      enca, tspH, tspL, nullptr, EE, SS, (long)EE * SS, (long)SS * EE);

  // x -> hi/lo planes (GEMM1 A), scratch in out_attn region (free until GEMM2)
  k_split<<<(BB * TT * CCH / 4 + 255) / 256, 256, 0, stream>>>(
      x, xh, xl, (long)BB * TT * CCH / 4);

  // GEMM1: x @ w_in -> G1 planes (P0/P1)
  mgemm<2><<<dim3(EE / BN, BB * TT / BM, 1), 256, 0, stream>>>(
      xh, xl, winTh, winTl, nullptr, G1h, G1l, BB * TT, EE, CCH, 0, 0, 0,
      nullptr, nullptr, nullptr, nullptr);

  // k_q: in-place G1 planes -> q planes (+ q2)
  k_q<<<BB * TT, 256, 0, stream>>>(G1h, G1l, tgt, bin, znin, x2a, q2a);

  // GEMM2 (batched) + dist epilogue: scores -> out_attn f32 (x planes dead)
  mgemm<1><<<dim3(SS / BN, TT / BM, BB), 256, 0, stream>>>(
      G1h, G1l, tspH, tspL, out_attn, nullptr, nullptr, TT, SS, EE,
      (long)TT * EE, (long)SS * EE, (long)TT * SS, q2a, y2a, fmask, scalep);

  // enc_b [S,E] scaled by gamma -> ebT [E,S] hi/lo (overwrites eaT)
  k_tsp<<<dim3(EE / 32, SS / 32, BB), dim3(32, 8), 0, stream>>>(
      encb, tspH, tspL, gam, SS, EE, (long)SS * EE, (long)EE * SS);

  // softmax: scores f32 -> attn planes (ATh in out_main, ATl in pool) + denr
  k_softmax<<<BB * TT, 256, 0, stream>>>(out_attn, gam, denr, ATh, ATl);

  // GEMM4 (batched): attn @ (gamma*enc_b) -> G4 planes (out_attn region; scores dead)
  mgemm<2><<<dim3(EE / BN, TT / BM, BB), 256, 0, stream>>>(
      ATh, ATl, tspH, tspL, nullptr, G4h, G4l, TT, EE, SS,
      (long)TT * SS, (long)EE * SS, (long)TT * EE, nullptr, nullptr, nullptr, nullptr);

  // k_mid: in-place G4 planes -> M planes (+ o2)
  k_mid<<<BB * TT, 256, 0, stream>>>(G4h, G4l, denr, ssb, o2a);

  // GEMM5: M @ w_out -> Gw f32 (T region; ebT dead)
  mgemm<0><<<dim3(CCH / BN, BB * TT / BM, 1), 256, 0, stream>>>(
      G4h, G4l, woutTh, woutTl, Gw, nullptr, nullptr, BB * TT, CCH, EE, 0, 0, 0,
      nullptr, nullptr, nullptr, nullptr);

  // reconstruct attn f32 output from planes (M planes dead after GEMM5)
  k_rec<<<(int)((long)BB * TT * SS / 4 / 256), 256, 0, stream>>>(
      ATh, ATl, out_attn, (long)BB * TT * SS / 4);

  // final epilogue (overwrites out_main; ATh dead after k_rec)
  k_final<<<BB * TT, 256, 0, stream>>>(Gw, x, bout, znout, x2a, o2a, out_main);
}

// Round 5
// 869.239 us; speedup vs baseline: 1.9256x; 1.2366x over previous
//
#include <hip/hip_runtime.h>
#include <hip/hip_bf16.h>
#include <math.h>

#define BB 16
#define TT 1024
#define SS 1024
#define CCH 512
#define EE 768
#define EPSV 1e-15f
#define CLIPV (1.0f - 1e-5f)
#define LOG2E 1.4426950408889634f

#define BM 128
#define BN 128
#define BK 32

typedef __attribute__((ext_vector_type(8))) short short8_t;
typedef __attribute__((ext_vector_type(4))) short short4_t;
typedef __attribute__((ext_vector_type(4))) float floatx4;

union BFU { __hip_bfloat16 b; short s; };

static __device__ __forceinline__ void bsplit(float x, short& h, short& l) {
  BFU u1; u1.b = __float2bfloat16(x);
  float hf = __bfloat162float(u1.b);
  BFU u2; u2.b = __float2bfloat16(x - hf);
  h = u1.s; l = u2.s;
}

static __device__ __forceinline__ float bf2f(short s) {
  BFU u; u.s = s; return __bfloat162float(u.b);
}

static __device__ __forceinline__ float fexp2(float x) { return __builtin_amdgcn_exp2f(x); }
static __device__ __forceinline__ float flog2(float x) { return __builtin_amdgcn_logf(x); }
static __device__ __forceinline__ float frcp(float x)  { return __builtin_amdgcn_rcpf(x); }

// sinh(g * asinh(t)) = 0.5*(p^g - p^-g), p = |t| + sqrt(t^2+1), sign-restored
static __device__ __forceinline__ float sinh_g_asinh(float g, float t) {
  float s = fabsf(t);
  float p = s + sqrtf(fmaf(s, s, 1.0f));
  float P = fexp2(g * flog2(p));
  float w = 0.5f * (P - frcp(P));
  return copysignf(w, t);
}

// tanh(r * atanh(min(n,CLIP))) / n  via Q^r, Q=(1+m)/(1-m); exp clamped vs overflow
static __device__ __forceinline__ float tanh_r_atanh_over_n(float r, float n) {
  float m = fminf(n, CLIPV);
  float Q = (1.0f + m) * frcp(1.0f - m);
  float E = fminf(r * flog2(Q), 126.0f);
  float P = fexp2(E);
  float f = (P - 1.0f) * frcp((P + 1.0f) * n);
  return (n < 1e-4f) ? r : f;
}

// async global->LDS, 16 B per lane; LDS dest = wave-uniform base + lane*16
static __device__ __forceinline__ void gl16(const short* g, short* lds_base) {
  __builtin_amdgcn_global_load_lds(
      (const __attribute__((address_space(1))) unsigned int*)g,
      (__attribute__((address_space(3))) unsigned int*)lds_base, 16, 0, 0);
}

static __device__ __forceinline__ float wave_sum(float v) {
  #pragma unroll
  for (int m = 32; m; m >>= 1) v += __shfl_xor(v, m, 64);
  return v;
}
static __device__ __forceinline__ float wave_max(float v) {
  #pragma unroll
  for (int m = 32; m; m >>= 1) v = fmaxf(v, __shfl_xor(v, m, 64));
  return v;
}

__device__ __forceinline__ float block_sum(float v, float* red4) {
  v = wave_sum(v);
  int w = threadIdx.x >> 6;
  if ((threadIdx.x & 63) == 0) red4[w] = v;
  __syncthreads();
  float r = red4[0] + red4[1] + red4[2] + red4[3];
  __syncthreads();
  return r;
}

__device__ __forceinline__ float block_max(float v, float* red4) {
  v = wave_max(v);
  int w = threadIdx.x >> 6;
  if ((threadIdx.x & 63) == 0) red4[w] = v;
  __syncthreads();
  float r = fmaxf(fmaxf(red4[0], red4[1]), fmaxf(red4[2], red4[3]));
  __syncthreads();
  return r;
}

// ---------- mask dtype detection + conversion ----------
__global__ void k_maskdet(const unsigned char* __restrict__ mb, int* __restrict__ flag) {
  __shared__ int any;
  if (threadIdx.x == 0) any = 0;
  __syncthreads();
  int local = 0;
  for (int i = threadIdx.x; i < BB * SS; i += 256)
    if ((i & 3) && mb[i]) local = 1;
  if (local) atomicOr(&any, 1);
  __syncthreads();
  if (threadIdx.x == 0) *flag = any;
}

__global__ void k_maskconv(const void* __restrict__ mraw, const int* __restrict__ flag,
                           float* __restrict__ fmask) {
  int i = blockIdx.x * 256 + threadIdx.x;
  if (i >= BB * SS) return;
  int f = *flag;
  int v = f ? (int)((const unsigned char*)mraw)[i] : ((const int*)mraw)[i];
  fmask[i] = v ? 1.0f : 0.0f;
}

// ---------- prep ----------
__global__ void k_colnorm(const float* __restrict__ z, float* __restrict__ zn, int K, int N) {
  __shared__ float red4[4];
  int e = blockIdx.x;
  float s = 0.f;
  for (int k = threadIdx.x; k < K; k += 256) {
    float v = z[(long)k * N + e];
    s += v * v;
  }
  s = block_sum(s, red4);
  if (threadIdx.x == 0) zn[e] = sqrtf(fmaxf(s, EPSV));
}

// per-column invariants: cosh/sinh(2*bias), 1/zn, 2*zn — for both layers
__global__ void k_trig(const float* __restrict__ bin, const float* __restrict__ znin,
                       const float* __restrict__ bout, const float* __restrict__ znout,
                       float* __restrict__ ch2i, float* __restrict__ sh2i,
                       float* __restrict__ rzni, float* __restrict__ zn2i,
                       float* __restrict__ ch2o, float* __restrict__ sh2o,
                       float* __restrict__ rzno, float* __restrict__ zn2o) {
  int i = blockIdx.x * 256 + threadIdx.x;
  if (i < EE) {
    float r2 = 2.0f * bin[i];
    ch2i[i] = coshf(r2); sh2i[i] = sinhf(r2);
    float z = znin[i]; rzni[i] = 1.0f / z; zn2i[i] = 2.0f * z;
  }
  if (i < CCH) {
    float r2 = 2.0f * bout[i];
    ch2o[i] = coshf(r2); sh2o[i] = sinhf(r2);
    float z = znout[i]; rzno[i] = 1.0f / z; zn2o[i] = 2.0f * z;
  }
}

__global__ void k_row2(const float* __restrict__ xp, float* __restrict__ out, int D) {
  __shared__ float red4[4];
  long row = blockIdx.x;
  float s = 0.f;
  for (int c = threadIdx.x; c < D; c += 256) { float v = xp[row * D + c]; s += v * v; }
  s = block_sum(s, red4);
  if (threadIdx.x == 0) out[row] = s;
}

// gamma[b,s] = 2/max(1-|encb row|^2, EPS)
__global__ void k_gamma(const float* __restrict__ encb, float* __restrict__ gam) {
  __shared__ float red4[4];
  long row = blockIdx.x;
  int t = threadIdx.x;
  float s2 = 0.f;
  #pragma unroll
  for (int j = 0; j < 3; j++) { float v = encb[row * EE + t + j * 256]; s2 += v * v; }
  s2 = block_sum(s2, red4);
  if (t == 0) gam[row] = 2.0f / fmaxf(1.0f - s2, EPSV);
}

// y2a[b,s] = sum_e enc_a[b,e,s]^2  (enc_a is [B,E,S]); grid (S/64, B), 256 thr
__global__ void k_y2b(const float* __restrict__ enca, float* __restrict__ y2a) {
  __shared__ float red[256];
  int b = blockIdx.y, s0 = blockIdx.x * 64;
  int si = threadIdx.x & 63, eg = threadIdx.x >> 6;
  const float* p = enca + (long)b * EE * SS + s0 + si;
  float acc = 0.f;
  for (int e = eg; e < EE; e += 4) { float v = p[(long)e * SS]; acc += v * v; }
  red[threadIdx.x] = acc; __syncthreads();
  if (eg == 0)
    y2a[(long)b * SS + s0 + si] = red[si] + red[si + 64] + red[si + 128] + red[si + 192];
}

__global__ void k_sb(const float* __restrict__ fmask, float* __restrict__ ssb) {
  __shared__ float red4[4];
  int b = blockIdx.x;
  float cnt = 0.f;
  for (int s = threadIdx.x; s < SS; s += 256) cnt += fmask[(long)b * SS + s];
  cnt = block_sum(cnt, red4);
  if (threadIdx.x == 0) ssb[b] = sqrtf((float)SS - cnt);
}

// ---------- fp32 -> bf16 hi/lo plane split (row-major copy, vectorized) ----------
__global__ void k_split(const float* __restrict__ in, short* __restrict__ oh,
                        short* __restrict__ ol, long n4) {
  long i = (long)blockIdx.x * 256 + threadIdx.x;
  if (i >= n4) return;
  floatx4 v = ((const floatx4*)in)[i];
  short4_t h4, l4;
  #pragma unroll
  for (int c = 0; c < 4; c++) { short hh, ll; bsplit(v[c], hh, ll); h4[c] = hh; l4[c] = ll; }
  ((short4_t*)oh)[i] = h4;
  ((short4_t*)ol)[i] = l4;
}

// ---------- attn f32 reconstruction from hi/lo planes ----------
__global__ void k_rec(const short* __restrict__ ah, const short* __restrict__ al,
                      float* __restrict__ outp, long n4) {
  long i = (long)blockIdx.x * 256 + threadIdx.x;
  if (i >= n4) return;
  short4_t h4 = ((const short4_t*)ah)[i];
  short4_t l4 = ((const short4_t*)al)[i];
  floatx4 r;
  #pragma unroll
  for (int c = 0; c < 4; c++) r[c] = bf2f(h4[c]) + bf2f(l4[c]);
  ((floatx4*)outp)[i] = r;
}

// ---------- transpose + bf16 hi/lo split (optional per-input-row scale) ----------
__global__ void k_tsp(const float* __restrict__ in, short* __restrict__ oh,
                      short* __restrict__ ol, const float* __restrict__ rs,
                      int R, int C, long sin, long sout) {
  __shared__ float tile[32][33];
  int z = blockIdx.z;
  const float* ib = in + (long)z * sin;
  short* ohb = oh + (long)z * sout;
  short* olb = ol + (long)z * sout;
  int c0 = blockIdx.x * 32, r0 = blockIdx.y * 32;
  int tx = threadIdx.x, ty = threadIdx.y;
  #pragma unroll
  for (int i = 0; i < 4; i++) {
    int rr = ty + i * 8;
    float v = ib[(long)(r0 + rr) * C + c0 + tx];
    if (rs) v *= rs[(long)z * R + r0 + rr];
    tile[rr][tx] = v;
  }
  __syncthreads();
  #pragma unroll
  for (int i = 0; i < 4; i++) {
    int cc = ty + i * 8;
    float v = tile[tx][cc];
    short h, l; bsplit(v, h, l);
    long o = (long)(c0 + cc) * R + r0 + tx;
    ohb[o] = h; olb[o] = l;
  }
}

// ---------- split-bf16 MFMA GEMM, double-buffered (unchanged from R4) ----------
template <int EPI>
__global__ __launch_bounds__(256)
void mgemm(const short* __restrict__ Agh, const short* __restrict__ Agl,
           const short* __restrict__ BTh, const short* __restrict__ BTl,
           float* __restrict__ Cm, short* __restrict__ Ch, short* __restrict__ Cl,
           int M, int N, int K, long sA, long sBT, long sC,
           const float* __restrict__ q2, const float* __restrict__ y2a,
           const float* __restrict__ fmask, const float* __restrict__ scalep) {
  __shared__ alignas(16) short Ah[2][BM * BK];
  __shared__ alignas(16) short Al[2][BM * BK];
  __shared__ alignas(16) short Bh[2][BN * BK];
  __shared__ alignas(16) short Bl[2][BN * BK];

  int gx = gridDim.x, gy = gridDim.y;
  int nwg = gx * gy * gridDim.z;
  int lin = blockIdx.x + gx * (blockIdx.y + gy * blockIdx.z);
  int swz = (lin & 7) * (nwg >> 3) + (lin >> 3);
  int bx = swz % gx; int tmp = swz / gx; int by = tmp % gy; int bz = tmp / gy;

  int z = bz;
  const short* Ahb = Agh + (long)z * sA;
  const short* Alb = Agl + (long)z * sA;
  const short* Bhb = BTh + (long)z * sBT;
  const short* Blb = BTl + (long)z * sBT;
  int m0 = by * BM, n0 = bx * BN;
  int t = threadIdx.x;
  int w = t >> 6, l = t & 63;
  int wr = w >> 1, wc = w & 1;
  int quad = l >> 4, lm = l & 15;

  int srow = (w << 5) + (l >> 2);
  int scol = (l & 3) << 3;
  int wbase = (w << 10);

  auto STAGE = [&](int buf, int kk) {
    const short* gAh = Ahb + (long)(m0 + srow) * K + kk + scol;
    const short* gAl = Alb + (long)(m0 + srow) * K + kk + scol;
    const short* gBh = Bhb + (long)(n0 + srow) * K + kk + scol;
    const short* gBl = Blb + (long)(n0 + srow) * K + kk + scol;
    #pragma unroll
    for (int u = 0; u < 2; u++) {
      long go = (long)(u * 16) * K;
      gl16(gAh + go, &Ah[buf][wbase + (u << 9)]);
      gl16(gAl + go, &Al[buf][wbase + (u << 9)]);
      gl16(gBh + go, &Bh[buf][wbase + (u << 9)]);
      gl16(gBl + go, &Bl[buf][wbase + (u << 9)]);
    }
  };

  floatx4 acc[4][4];
  #pragma unroll
  for (int i = 0; i < 4; i++)
    #pragma unroll
    for (int j = 0; j < 4; j++) acc[i][j] = (floatx4){0.f, 0.f, 0.f, 0.f};

  STAGE(0, 0);
  __syncthreads();
  int cur = 0;

  for (int k0 = 0; k0 < K; k0 += BK) {
    int nxt = k0 + BK;
    if (nxt < K) STAGE(cur ^ 1, nxt);

    short8_t bfh[4], bfl[4];
    #pragma unroll
    for (int nj = 0; nj < 4; nj++) {
      int n = wc * 64 + nj * 16 + lm;
      bfh[nj] = *(const short8_t*)&Bh[cur][n * BK + quad * 8];
      bfl[nj] = *(const short8_t*)&Bl[cur][n * BK + quad * 8];
    }
    #pragma unroll
    for (int mi = 0; mi < 4; mi++) {
      int m = wr * 64 + mi * 16 + lm;
      short8_t afh = *(const short8_t*)&Ah[cur][m * BK + quad * 8];
      short8_t afl = *(const short8_t*)&Al[cur][m * BK + quad * 8];
      #pragma unroll
      for (int nj = 0; nj < 4; nj++) {
        acc[mi][nj] = __builtin_amdgcn_mfma_f32_16x16x32_bf16(afh, bfh[nj], acc[mi][nj], 0, 0, 0);
        acc[mi][nj] = __builtin_amdgcn_mfma_f32_16x16x32_bf16(afh, bfl[nj], acc[mi][nj], 0, 0, 0);
        acc[mi][nj] = __builtin_amdgcn_mfma_f32_16x16x32_bf16(afl, bfh[nj], acc[mi][nj], 0, 0, 0);
      }
    }
    __syncthreads();
    cur ^= 1;
  }

  float* Cb = Cm + (long)z * sC;
  short* Chb = Ch + (long)z * sC;
  short* Clb = Cl + (long)z * sC;
  float inv_es = 1.0f;
  if constexpr (EPI == 1) inv_es = 1.0f / expf(scalep[0]);

  #pragma unroll
  for (int mi = 0; mi < 4; mi++) {
    #pragma unroll
    for (int r = 0; r < 4; r++) {
      int gm = m0 + wr * 64 + mi * 16 + quad * 4 + r;
      #pragma unroll
      for (int nj = 0; nj < 4; nj++) {
        int gn = n0 + wc * 64 + nj * 16 + lm;
        float c = acc[mi][nj][r];
        if constexpr (EPI == 0) {
          Cb[(long)gm * N + gn] = c;
        } else if constexpr (EPI == 2) {
          short hh, ll; bsplit(c, hh, ll);
          Chb[(long)gm * N + gn] = hh;
          Clb[(long)gm * N + gn] = ll;
        } else {
          float xv = q2[(long)z * M + gm];
          float yv = y2a[(long)z * N + gn];
          float num = fmaxf(xv - 2.0f * c + yv, 0.0f);
          float den = fmaxf(1.0f - 2.0f * c + xv * yv, EPSV);
          float mm = sqrtf(num / den);
          float sc = -2.0f * atanhf(fminf(mm, CLIPV)) * inv_es;
          if (fmask[(long)z * N + gn] > 0.5f) sc = -INFINITY;
          Cb[(long)gm * N + gn] = sc;
        }
      }
    }
  }
}

// ---------- q = msm(sqrt(.5), mobius_add(tgt, poincare_linear(x,w_in,b_in))) ----------
// IN-PLACE on hi/lo planes. Fast-math forms + precomputed per-column invariants.
__global__ void k_q(short* gh, short* gl, const float* __restrict__ tgt,
                    const float* __restrict__ ch2, const float* __restrict__ sh2,
                    const float* __restrict__ rzn, const float* __restrict__ zn2,
                    const float* __restrict__ x2, float* __restrict__ q2) {
  __shared__ float red4[4];
  long row = blockIdx.x;
  int t = threadIdx.x;
  float cx2 = x2[row];
  float rdpl = 1.0f / fmaxf(1.0f - cx2, EPSV);
  float opc = 1.0f + cx2;

  float wv[3]; float sw2 = 0.f;
  #pragma unroll
  for (int j = 0; j < 3; j++) {
    int e = t + j * 256;
    float u = (bf2f(gh[row * EE + e]) + bf2f(gl[row * EE + e])) * rzn[e];
    float nm = fmaf(2.0f * u, ch2[e], -opc * sh2[e]);
    wv[j] = sinh_g_asinh(zn2[e], nm * rdpl);
    sw2 += wv[j] * wv[j];
  }
  sw2 = block_sum(sw2, red4);
  float rpden = 1.0f / (1.0f + sqrtf(1.0f + sw2));

  float pv[3], tv[3];
  float tp = 0.f, p2 = 0.f, t2 = 0.f;
  #pragma unroll
  for (int j = 0; j < 3; j++) {
    int e = t + j * 256;
    pv[j] = wv[j] * rpden;
    tv[j] = tgt[row * EE + e];
    tp += tv[j] * pv[j]; p2 += pv[j] * pv[j]; t2 += tv[j] * tv[j];
  }
  tp = block_sum(tp, red4);
  p2 = block_sum(p2, red4);
  t2 = block_sum(t2, red4);

  float rmden = 1.0f / fmaxf(1.0f + 2.0f * tp + t2 * p2, EPSV);
  float cT = 1.0f + 2.0f * tp + p2;
  float cP = 1.0f - t2;
  float av[3]; float n2 = 0.f;
  #pragma unroll
  for (int j = 0; j < 3; j++) { av[j] = (cT * tv[j] + cP * pv[j]) * rmden; n2 += av[j] * av[j]; }
  n2 = block_sum(n2, red4);

  float n = sqrtf(fmaxf(n2, EPSV));
  float f = tanh_r_atanh_over_n(0.70710678118654752f, n);
  #pragma unroll
  for (int j = 0; j < 3; j++) {
    int e = t + j * 256;
    short h, lo; bsplit(f * av[j], h, lo);
    gh[row * EE + e] = h; gl[row * EE + e] = lo;
  }
  if (t == 0) q2[row] = f * f * n2;
}

// ---------- softmax: reads f32 scores, writes attn hi/lo planes + den ----------
__global__ void k_softmax(const float* __restrict__ S, const float* __restrict__ gam,
                          float* __restrict__ denr,
                          short* __restrict__ ah, short* __restrict__ al) {
  __shared__ float red4[4];
  long row = blockIdx.x;
  int b = (int)(row / TT);
  int t = threadIdx.x;
  const float* rowp = S + row * SS;

  float v[4];
  float mx = -INFINITY;
  #pragma unroll
  for (int j = 0; j < 4; j++) { v[j] = rowp[t + j * 256]; mx = fmaxf(mx, v[j]); }
  mx = block_max(mx, red4);
  bool dead = !(mx > -INFINITY) || (mx != mx);
  float sum = 0.f;
  #pragma unroll
  for (int j = 0; j < 4; j++) {
    v[j] = dead ? 0.f : fexp2((v[j] - mx) * LOG2E);
    sum += v[j];
  }
  sum = block_sum(sum, red4);
  float inv = (sum > 0.f) ? 1.0f / sum : 0.f;
  float ds = 0.f;
  #pragma unroll
  for (int j = 0; j < 4; j++) {
    int s = t + j * 256;
    float a = v[j] * inv;
    short h, lo; bsplit(a, h, lo);
    ah[row * SS + s] = h; al[row * SS + s] = lo;
    ds += a * (gam[(long)b * SS + s] - 1.0f);
  }
  ds = block_sum(ds, red4);
  if (t == 0) denr[row] = (inv == 0.f) ? 1.0f : ds;
}

// ---------- out2 = msm(sqrt(s_b), msm(0.5, nom/den)) — IN-PLACE on planes ----------
__global__ void k_mid(short* gh, short* gl, const float* __restrict__ denr,
                      const float* __restrict__ ssb, float* __restrict__ o2) {
  __shared__ float red4[4];
  long row = blockIdx.x;
  int b = (int)(row / TT);
  int t = threadIdx.x;
  float d = denr[row];
  if (fabsf(d) < 1e-10f) d = 1e-10f;
  float rd = 1.0f / d;

  float v[3]; float n2 = 0.f;
  #pragma unroll
  for (int j = 0; j < 3; j++) {
    int e = t + j * 256;
    v[j] = (bf2f(gh[row * EE + e]) + bf2f(gl[row * EE + e])) * rd;
    n2 += v[j] * v[j];
  }
  n2 = block_sum(n2, red4);
  float n = sqrtf(fmaxf(n2, EPSV));
  // tanh(0.5*atanh(m))/n = m / ((1+sqrt(1-m^2))*n) — exact identity
  float m = fminf(n, CLIPV);
  float f1 = m / ((1.0f + sqrtf(fmaxf(1.0f - m * m, 0.0f))) * n);

  float m2 = 0.f;
  #pragma unroll
  for (int j = 0; j < 3; j++) { v[j] *= f1; m2 += v[j] * v[j]; }
  m2 = block_sum(m2, red4);
  float n1 = sqrtf(fmaxf(m2, EPSV));
  float f2 = tanh_r_atanh_over_n(ssb[b], n1);

  float s2 = 0.f;
  #pragma unroll
  for (int j = 0; j < 3; j++) {
    int e = t + j * 256;
    v[j] *= f2; s2 += v[j] * v[j];
    short h, lo; bsplit(v[j], h, lo);
    gh[row * EE + e] = h; gl[row * EE + e] = lo;
  }
  s2 = block_sum(s2, red4);
  if (t == 0) o2[row] = s2;
}

// ---------- final epilogue ----------
__global__ void k_final(const float* __restrict__ G, const float* __restrict__ xin,
                        const float* __restrict__ ch2, const float* __restrict__ sh2,
                        const float* __restrict__ rzn, const float* __restrict__ zn2,
                        const float* __restrict__ x2, const float* __restrict__ o2,
                        float* __restrict__ outp) {
  __shared__ float red4[4];
  long row = blockIdx.x;
  int t = threadIdx.x;
  float cx2 = o2[row];
  float rdpl = 1.0f / fmaxf(1.0f - cx2, EPSV);
  float opc = 1.0f + cx2;

  float wv[2]; float sw2 = 0.f;
  #pragma unroll
  for (int j = 0; j < 2; j++) {
    int c = t + j * 256;
    float u = G[row * CCH + c] * rzn[c];
    float nm = fmaf(2.0f * u, ch2[c], -opc * sh2[c]);
    wv[j] = sinh_g_asinh(zn2[c], nm * rdpl);
    sw2 += wv[j] * wv[j];
  }
  sw2 = block_sum(sw2, red4);
  float rpden = 1.0f / (1.0f + sqrtf(1.0f + sw2));

  float pv[2], xv[2];
  float xp = 0.f, p2 = 0.f;
  #pragma unroll
  for (int j = 0; j < 2; j++) {
    int c = t + j * 256;
    pv[j] = wv[j] * rpden;
    xv[j] = xin[row * CCH + c];
    xp += xv[j] * pv[j]; p2 += pv[j] * pv[j];
  }
  xp = block_sum(xp, red4);
  p2 = block_sum(p2, red4);

  float xx = x2[row];
  float rmden = 1.0f / fmaxf(1.0f + 2.0f * xp + xx * p2, EPSV);
  float cX = 1.0f + 2.0f * xp + p2;
  float cP = 1.0f - xx;
  float av[2]; float n2 = 0.f;
  #pragma unroll
  for (int j = 0; j < 2; j++) { av[j] = (cX * xv[j] + cP * pv[j]) * rmden; n2 += av[j] * av[j]; }
  n2 = block_sum(n2, red4);

  float n = sqrtf(fmaxf(n2, EPSV));
  float f = tanh_r_atanh_over_n(0.70710678118654752f, n);
  #pragma unroll
  for (int j = 0; j < 2; j++) { int c = t + j * 256; outp[row * CCH + c] = f * av[j]; }
}

extern "C" void kernel_launch(void* const* d_in, const int* in_sizes, int n_in,
                              void* d_out, int out_size, void* d_ws, size_t ws_size,
                              hipStream_t stream) {
  const float* x    = (const float*)d_in[0];
  const float* tgt  = (const float*)d_in[1];
  const float* enca = (const float*)d_in[2];
  const float* encb = (const float*)d_in[3];
  const void*  mraw = d_in[4];
  const float* win  = (const float*)d_in[5];
  const float* bin  = (const float*)d_in[6];
  const float* wout = (const float*)d_in[7];
  const float* bout = (const float*)d_in[8];
  const float* scalep = (const float*)d_in[9];

  float* out_main = (float*)d_out;                       // [B,T,CCH] f32 (33.55 MB)
  float* out_attn = out_main + (long)BB * TT * CCH;      // [B,T,S]  f32 (67.11 MB)

  // ---- d_out scratch aliases ----
  short* xh  = (short*)out_attn;
  short* xl  = xh + (long)BB * TT * CCH;
  short* G4h = (short*)out_attn;
  short* G4l = G4h + (long)BB * TT * EE;
  short* ATh = (short*)out_main;

  // ---- workspace (same proven 104.1 MB budget + few KB of invariants) ----
  char* wb = (char*)d_ws;
  short* P0   = (short*)wb;  wb += (long)BB * TT * EE * 2;
  short* P1   = (short*)wb;  wb += (long)BB * TT * EE * 2;
  short* G1h = P0, *G1l = P1;
  short* ATl = P0;
  short* tspH = (short*)wb;  wb += (long)BB * SS * EE * 2;
  short* tspL = (short*)wb;  wb += (long)BB * SS * EE * 2;
  float* Gw   = (float*)tspH;
  short* winTh  = (short*)wb;  wb += (long)CCH * EE * 2;
  short* winTl  = (short*)wb;  wb += (long)CCH * EE * 2;
  short* woutTh = (short*)wb;  wb += (long)EE * CCH * 2;
  short* woutTl = (short*)wb;  wb += (long)EE * CCH * 2;
  float* sm     = (float*)wb;
  float* x2a  = sm; sm += BB * TT;
  float* q2a  = sm; sm += BB * TT;
  float* y2a  = sm; sm += BB * SS;
  float* gam  = sm; sm += BB * SS;
  float* denr = sm; sm += BB * TT;
  float* o2a  = sm; sm += BB * TT;
  float* znin = sm; sm += EE;
  float* znout= sm; sm += CCH;
  float* ssb  = sm; sm += BB;
  float* fmask= sm; sm += BB * SS;
  float* ch2i = sm; sm += EE;
  float* sh2i = sm; sm += EE;
  float* rzni = sm; sm += EE;
  float* zn2i = sm; sm += EE;
  float* ch2o = sm; sm += CCH;
  float* sh2o = sm; sm += CCH;
  float* rzno = sm; sm += CCH;
  float* zn2o = sm; sm += CCH;
  int*   mflag= (int*)sm; sm += 1;

  // mask canonicalization
  k_maskdet<<<1, 256, 0, stream>>>((const unsigned char*)mraw, mflag);
  k_maskconv<<<BB * SS / 256, 256, 0, stream>>>(mraw, mflag, fmask);

  // prep
  k_colnorm<<<EE, 256, 0, stream>>>(win, znin, CCH, EE);
  k_colnorm<<<CCH, 256, 0, stream>>>(wout, znout, EE, CCH);
  k_trig<<<3, 256, 0, stream>>>(bin, znin, bout, znout,
                                ch2i, sh2i, rzni, zn2i, ch2o, sh2o, rzno, zn2o);
  k_row2<<<BB * TT, 256, 0, stream>>>(x, x2a, CCH);
  k_gamma<<<BB * SS, 256, 0, stream>>>(encb, gam);
  k_y2b<<<dim3(SS / 64, BB), 256, 0, stream>>>(enca, y2a);
  k_sb<<<BB, 256, 0, stream>>>(fmask, ssb);

  // weight transposes + split
  k_tsp<<<dim3(EE / 32, CCH / 32, 1), dim3(32, 8), 0, stream>>>(
      win, winTh, winTl, nullptr, CCH, EE, 0, 0);
  k_tsp<<<dim3(CCH / 32, EE / 32, 1), dim3(32, 8), 0, stream>>>(
      wout, woutTh, woutTl, nullptr, EE, CCH, 0, 0);

  // enc_a [E,S] -> eaT [S,E] hi/lo
  k_tsp<<<dim3(SS / 32, EE / 32, BB), dim3(32, 8), 0, stream>>>(
      enca, tspH, tspL, nullptr, EE, SS, (long)EE * SS, (long)SS * EE);

  // x -> hi/lo planes (GEMM1 A), scratch in out_attn region
  k_split<<<(BB * TT * CCH / 4 + 255) / 256, 256, 0, stream>>>(
      x, xh, xl, (long)BB * TT * CCH / 4);

  // GEMM1: x @ w_in -> G1 planes (P0/P1)
  mgemm<2><<<dim3(EE / BN, BB * TT / BM, 1), 256, 0, stream>>>(
      xh, xl, winTh, winTl, nullptr, G1h, G1l, BB * TT, EE, CCH, 0, 0, 0,
      nullptr, nullptr, nullptr, nullptr);

  // k_q: in-place G1 planes -> q planes (+ q2)
  k_q<<<BB * TT, 256, 0, stream>>>(G1h, G1l, tgt, ch2i, sh2i, rzni, zn2i, x2a, q2a);

  // GEMM2 (batched) + dist epilogue: scores -> out_attn f32
  mgemm<1><<<dim3(SS / BN, TT / BM, BB), 256, 0, stream>>>(
      G1h, G1l, tspH, tspL, out_attn, nullptr, nullptr, TT, SS, EE,
      (long)TT * EE, (long)SS * EE, (long)TT * SS, q2a, y2a, fmask, scalep);

  // enc_b [S,E] scaled by gamma -> ebT [E,S] hi/lo (overwrites eaT)
  k_tsp<<<dim3(EE / 32, SS / 32, BB), dim3(32, 8), 0, stream>>>(
      encb, tspH, tspL, gam, SS, EE, (long)SS * EE, (long)EE * SS);

  // softmax: scores f32 -> attn planes (ATh in out_main, ATl in pool) + denr
  k_softmax<<<BB * TT, 256, 0, stream>>>(out_attn, gam, denr, ATh, ATl);

  // GEMM4 (batched): attn @ (gamma*enc_b) -> G4 planes (out_attn region)
  mgemm<2><<<dim3(EE / BN, TT / BM, BB), 256, 0, stream>>>(
      ATh, ATl, tspH, tspL, nullptr, G4h, G4l, TT, EE, SS,
      (long)TT * SS, (long)EE * SS, (long)TT * EE, nullptr, nullptr, nullptr, nullptr);

  // k_mid: in-place G4 planes -> M planes (+ o2)
  k_mid<<<BB * TT, 256, 0, stream>>>(G4h, G4l, denr, ssb, o2a);

  // GEMM5: M @ w_out -> Gw f32 (T region; ebT dead)
  mgemm<0><<<dim3(CCH / BN, BB * TT / BM, 1), 256, 0, stream>>>(
      G4h, G4l, woutTh, woutTl, Gw, nullptr, nullptr, BB * TT, CCH, EE, 0, 0, 0,
      nullptr, nullptr, nullptr, nullptr);

  // reconstruct attn f32 output from planes
  k_rec<<<(int)((long)BB * TT * SS / 4 / 256), 256, 0, stream>>>(
      ATh, ATl, out_attn, (long)BB * TT * SS / 4);

  // final epilogue (overwrites out_main)
  k_final<<<BB * TT, 256, 0, stream>>>(Gw, x, ch2o, sh2o, rzno, zn2o, x2a, o2a, out_main);
}

// Round 6
// 814.821 us; speedup vs baseline: 2.0542x; 1.0668x over previous
//
#include <hip/hip_runtime.h>
#include <hip/hip_bf16.h>
#include <math.h>

#define BB 16
#define TT 1024
#define SS 1024
#define CCH 512
#define EE 768
#define EPSV 1e-15f
#define CLIPV (1.0f - 1e-5f)
#define LOG2E 1.4426950408889634f

#define BM 128
#define BN 128
#define BK 32

typedef __attribute__((ext_vector_type(8))) short short8_t;
typedef __attribute__((ext_vector_type(4))) short short4_t;
typedef __attribute__((ext_vector_type(4))) float floatx4;

union BFU { __hip_bfloat16 b; short s; };

static __device__ __forceinline__ void bsplit(float x, short& h, short& l) {
  BFU u1; u1.b = __float2bfloat16(x);
  float hf = __bfloat162float(u1.b);
  BFU u2; u2.b = __float2bfloat16(x - hf);
  h = u1.s; l = u2.s;
}

static __device__ __forceinline__ float bf2f(short s) {
  BFU u; u.s = s; return __bfloat162float(u.b);
}

static __device__ __forceinline__ float fexp2(float x) { return __builtin_amdgcn_exp2f(x); }
static __device__ __forceinline__ float flog2(float x) { return __builtin_amdgcn_logf(x); }
static __device__ __forceinline__ float frcp(float x)  { return __builtin_amdgcn_rcpf(x); }

// sinh(g * asinh(t)) = 0.5*(p^g - p^-g), p = |t| + sqrt(t^2+1), sign-restored
static __device__ __forceinline__ float sinh_g_asinh(float g, float t) {
  float s = fabsf(t);
  float p = s + sqrtf(fmaf(s, s, 1.0f));
  float P = fexp2(g * flog2(p));
  float w = 0.5f * (P - frcp(P));
  return copysignf(w, t);
}

// tanh(r * atanh(min(n,CLIP))) / n  via Q^r, Q=(1+m)/(1-m); exp clamped vs overflow
static __device__ __forceinline__ float tanh_r_atanh_over_n(float r, float n) {
  float m = fminf(n, CLIPV);
  float Q = (1.0f + m) * frcp(1.0f - m);
  float E = fminf(r * flog2(Q), 126.0f);
  float P = fexp2(E);
  float f = (P - 1.0f) * frcp((P + 1.0f) * n);
  return (n < 1e-4f) ? r : f;
}

// async global->LDS, 16 B per lane; LDS dest = wave-uniform base + lane*16
static __device__ __forceinline__ void gl16(const short* g, short* lds_base) {
  __builtin_amdgcn_global_load_lds(
      (const __attribute__((address_space(1))) unsigned int*)g,
      (__attribute__((address_space(3))) unsigned int*)lds_base, 16, 0, 0);
}

static __device__ __forceinline__ float wave_sum(float v) {
  #pragma unroll
  for (int m = 32; m; m >>= 1) v += __shfl_xor(v, m, 64);
  return v;
}
static __device__ __forceinline__ float wave_max(float v) {
  #pragma unroll
  for (int m = 32; m; m >>= 1) v = fmaxf(v, __shfl_xor(v, m, 64));
  return v;
}

__device__ __forceinline__ float block_sum(float v, float* red4) {
  v = wave_sum(v);
  int w = threadIdx.x >> 6;
  if ((threadIdx.x & 63) == 0) red4[w] = v;
  __syncthreads();
  float r = red4[0] + red4[1] + red4[2] + red4[3];
  __syncthreads();
  return r;
}

__device__ __forceinline__ float block_max(float v, float* red4) {
  v = wave_max(v);
  int w = threadIdx.x >> 6;
  if ((threadIdx.x & 63) == 0) red4[w] = v;
  __syncthreads();
  float r = fmaxf(fmaxf(red4[0], red4[1]), fmaxf(red4[2], red4[3]));
  __syncthreads();
  return r;
}

// ---------- mask dtype detection + conversion ----------
__global__ void k_maskdet(const unsigned char* __restrict__ mb, int* __restrict__ flag) {
  __shared__ int any;
  if (threadIdx.x == 0) any = 0;
  __syncthreads();
  int local = 0;
  for (int i = threadIdx.x; i < BB * SS; i += 256)
    if ((i & 3) && mb[i]) local = 1;
  if (local) atomicOr(&any, 1);
  __syncthreads();
  if (threadIdx.x == 0) *flag = any;
}

__global__ void k_maskconv(const void* __restrict__ mraw, const int* __restrict__ flag,
                           float* __restrict__ fmask) {
  int i = blockIdx.x * 256 + threadIdx.x;
  if (i >= BB * SS) return;
  int f = *flag;
  int v = f ? (int)((const unsigned char*)mraw)[i] : ((const int*)mraw)[i];
  fmask[i] = v ? 1.0f : 0.0f;
}

// ---------- prep ----------
__global__ void k_colnorm(const float* __restrict__ z, float* __restrict__ zn, int K, int N) {
  __shared__ float red4[4];
  int e = blockIdx.x;
  float s = 0.f;
  for (int k = threadIdx.x; k < K; k += 256) {
    float v = z[(long)k * N + e];
    s += v * v;
  }
  s = block_sum(s, red4);
  if (threadIdx.x == 0) zn[e] = sqrtf(fmaxf(s, EPSV));
}

// per-column invariants: cosh/sinh(2*bias), 1/zn, 2*zn — for both layers
__global__ void k_trig(const float* __restrict__ bin, const float* __restrict__ znin,
                       const float* __restrict__ bout, const float* __restrict__ znout,
                       float* __restrict__ ch2i, float* __restrict__ sh2i,
                       float* __restrict__ rzni, float* __restrict__ zn2i,
                       float* __restrict__ ch2o, float* __restrict__ sh2o,
                       float* __restrict__ rzno, float* __restrict__ zn2o) {
  int i = blockIdx.x * 256 + threadIdx.x;
  if (i < EE) {
    float r2 = 2.0f * bin[i];
    ch2i[i] = coshf(r2); sh2i[i] = sinhf(r2);
    float z = znin[i]; rzni[i] = 1.0f / z; zn2i[i] = 2.0f * z;
  }
  if (i < CCH) {
    float r2 = 2.0f * bout[i];
    ch2o[i] = coshf(r2); sh2o[i] = sinhf(r2);
    float z = znout[i]; rzno[i] = 1.0f / z; zn2o[i] = 2.0f * z;
  }
}

__global__ void k_row2(const float* __restrict__ xp, float* __restrict__ out, int D) {
  __shared__ float red4[4];
  long row = blockIdx.x;
  float s = 0.f;
  for (int c = threadIdx.x; c < D; c += 256) { float v = xp[row * D + c]; s += v * v; }
  s = block_sum(s, red4);
  if (threadIdx.x == 0) out[row] = s;
}

// gamma[b,s] = 2/max(1-|encb row|^2, EPS)
__global__ void k_gamma(const float* __restrict__ encb, float* __restrict__ gam) {
  __shared__ float red4[4];
  long row = blockIdx.x;
  int t = threadIdx.x;
  float s2 = 0.f;
  #pragma unroll
  for (int j = 0; j < 3; j++) { float v = encb[row * EE + t + j * 256]; s2 += v * v; }
  s2 = block_sum(s2, red4);
  if (t == 0) gam[row] = 2.0f / fmaxf(1.0f - s2, EPSV);
}

// y2a[b,s] = sum_e enc_a[b,e,s]^2  (enc_a is [B,E,S]); grid (S/64, B), 256 thr
__global__ void k_y2b(const float* __restrict__ enca, float* __restrict__ y2a) {
  __shared__ float red[256];
  int b = blockIdx.y, s0 = blockIdx.x * 64;
  int si = threadIdx.x & 63, eg = threadIdx.x >> 6;
  const float* p = enca + (long)b * EE * SS + s0 + si;
  float acc = 0.f;
  for (int e = eg; e < EE; e += 4) { float v = p[(long)e * SS]; acc += v * v; }
  red[threadIdx.x] = acc; __syncthreads();
  if (eg == 0)
    y2a[(long)b * SS + s0 + si] = red[si] + red[si + 64] + red[si + 128] + red[si + 192];
}

__global__ void k_sb(const float* __restrict__ fmask, float* __restrict__ ssb) {
  __shared__ float red4[4];
  int b = blockIdx.x;
  float cnt = 0.f;
  for (int s = threadIdx.x; s < SS; s += 256) cnt += fmask[(long)b * SS + s];
  cnt = block_sum(cnt, red4);
  if (threadIdx.x == 0) ssb[b] = sqrtf((float)SS - cnt);
}

// ---------- fp32 -> bf16 hi/lo plane split (row-major copy, vectorized) ----------
__global__ void k_split(const float* __restrict__ in, short* __restrict__ oh,
                        short* __restrict__ ol, long n4) {
  long i = (long)blockIdx.x * 256 + threadIdx.x;
  if (i >= n4) return;
  floatx4 v = ((const floatx4*)in)[i];
  short4_t h4, l4;
  #pragma unroll
  for (int c = 0; c < 4; c++) { short hh, ll; bsplit(v[c], hh, ll); h4[c] = hh; l4[c] = ll; }
  ((short4_t*)oh)[i] = h4;
  ((short4_t*)ol)[i] = l4;
}

// ---------- attn f32 reconstruction from hi/lo planes ----------
__global__ void k_rec(const short* __restrict__ ah, const short* __restrict__ al,
                      float* __restrict__ outp, long n4) {
  long i = (long)blockIdx.x * 256 + threadIdx.x;
  if (i >= n4) return;
  short4_t h4 = ((const short4_t*)ah)[i];
  short4_t l4 = ((const short4_t*)al)[i];
  floatx4 r;
  #pragma unroll
  for (int c = 0; c < 4; c++) r[c] = bf2f(h4[c]) + bf2f(l4[c]);
  ((floatx4*)outp)[i] = r;
}

// ---------- transpose + bf16 hi/lo split (optional per-input-row scale) ----------
__global__ void k_tsp(const float* __restrict__ in, short* __restrict__ oh,
                      short* __restrict__ ol, const float* __restrict__ rs,
                      int R, int C, long sin, long sout) {
  __shared__ float tile[32][33];
  int z = blockIdx.z;
  const float* ib = in + (long)z * sin;
  short* ohb = oh + (long)z * sout;
  short* olb = ol + (long)z * sout;
  int c0 = blockIdx.x * 32, r0 = blockIdx.y * 32;
  int tx = threadIdx.x, ty = threadIdx.y;
  #pragma unroll
  for (int i = 0; i < 4; i++) {
    int rr = ty + i * 8;
    float v = ib[(long)(r0 + rr) * C + c0 + tx];
    if (rs) v *= rs[(long)z * R + r0 + rr];
    tile[rr][tx] = v;
  }
  __syncthreads();
  #pragma unroll
  for (int i = 0; i < 4; i++) {
    int cc = ty + i * 8;
    float v = tile[tx][cc];
    short h, l; bsplit(v, h, l);
    long o = (long)(c0 + cc) * R + r0 + tx;
    ohb[o] = h; olb[o] = l;
  }
}

// ---------- split-bf16 MFMA GEMM, double-buffered, LDS chunk-swizzled.
// Swizzle (both-sides involution): LDS[row][slot16B] holds global[row][slot ^ ((row>>1)&3)].
// Stage side: source chunk = (l&3) ^ ((l>>3)&3)  (lane-constant).
// Read  side: slot = quad ^ ((lm>>1)&3)          (thread-constant).
// Each 16-lane read cycle then covers all 32 banks 2-way (free). ----------
template <int EPI>
__global__ __launch_bounds__(256)
void mgemm(const short* __restrict__ Agh, const short* __restrict__ Agl,
           const short* __restrict__ BTh, const short* __restrict__ BTl,
           float* __restrict__ Cm, short* __restrict__ Ch, short* __restrict__ Cl,
           int M, int N, int K, long sA, long sBT, long sC,
           const float* __restrict__ q2, const float* __restrict__ y2a,
           const float* __restrict__ fmask, const float* __restrict__ scalep) {
  __shared__ alignas(16) short Ah[2][BM * BK];
  __shared__ alignas(16) short Al[2][BM * BK];
  __shared__ alignas(16) short Bh[2][BN * BK];
  __shared__ alignas(16) short Bl[2][BN * BK];

  int gx = gridDim.x, gy = gridDim.y;
  int nwg = gx * gy * gridDim.z;
  int lin = blockIdx.x + gx * (blockIdx.y + gy * blockIdx.z);
  int swz = (lin & 7) * (nwg >> 3) + (lin >> 3);
  int bx = swz % gx; int tmp = swz / gx; int by = tmp % gy; int bz = tmp / gy;

  int z = bz;
  const short* Ahb = Agh + (long)z * sA;
  const short* Alb = Agl + (long)z * sA;
  const short* Bhb = BTh + (long)z * sBT;
  const short* Blb = BTl + (long)z * sBT;
  int m0 = by * BM, n0 = bx * BN;
  int t = threadIdx.x;
  int w = t >> 6, l = t & 63;
  int wr = w >> 1, wc = w & 1;
  int quad = l >> 4, lm = l & 15;

  int srow = (w << 5) + (l >> 2);
  int scol = (((l & 3) ^ ((l >> 3) & 3)) << 3);   // swizzled global source chunk
  int wbase = (w << 10);
  int qs = ((quad ^ ((lm >> 1) & 3)) << 3);       // swizzled LDS read slot (shorts)

  auto STAGE = [&](int buf, int kk) {
    const short* gAh = Ahb + (long)(m0 + srow) * K + kk + scol;
    const short* gAl = Alb + (long)(m0 + srow) * K + kk + scol;
    const short* gBh = Bhb + (long)(n0 + srow) * K + kk + scol;
    const short* gBl = Blb + (long)(n0 + srow) * K + kk + scol;
    #pragma unroll
    for (int u = 0; u < 2; u++) {
      long go = (long)(u * 16) * K;
      gl16(gAh + go, &Ah[buf][wbase + (u << 9)]);
      gl16(gAl + go, &Al[buf][wbase + (u << 9)]);
      gl16(gBh + go, &Bh[buf][wbase + (u << 9)]);
      gl16(gBl + go, &Bl[buf][wbase + (u << 9)]);
    }
  };

  floatx4 acc[4][4];
  #pragma unroll
  for (int i = 0; i < 4; i++)
    #pragma unroll
    for (int j = 0; j < 4; j++) acc[i][j] = (floatx4){0.f, 0.f, 0.f, 0.f};

  STAGE(0, 0);
  __syncthreads();
  int cur = 0;

  for (int k0 = 0; k0 < K; k0 += BK) {
    int nxt = k0 + BK;
    if (nxt < K) STAGE(cur ^ 1, nxt);

    short8_t bfh[4], bfl[4];
    #pragma unroll
    for (int nj = 0; nj < 4; nj++) {
      int n = wc * 64 + nj * 16 + lm;
      bfh[nj] = *(const short8_t*)&Bh[cur][n * BK + qs];
      bfl[nj] = *(const short8_t*)&Bl[cur][n * BK + qs];
    }
    #pragma unroll
    for (int mi = 0; mi < 4; mi++) {
      int m = wr * 64 + mi * 16 + lm;
      short8_t afh = *(const short8_t*)&Ah[cur][m * BK + qs];
      short8_t afl = *(const short8_t*)&Al[cur][m * BK + qs];
      #pragma unroll
      for (int nj = 0; nj < 4; nj++) {
        acc[mi][nj] = __builtin_amdgcn_mfma_f32_16x16x32_bf16(afh, bfh[nj], acc[mi][nj], 0, 0, 0);
        acc[mi][nj] = __builtin_amdgcn_mfma_f32_16x16x32_bf16(afh, bfl[nj], acc[mi][nj], 0, 0, 0);
        acc[mi][nj] = __builtin_amdgcn_mfma_f32_16x16x32_bf16(afl, bfh[nj], acc[mi][nj], 0, 0, 0);
      }
    }
    __syncthreads();
    cur ^= 1;
  }

  float* Cb = Cm + (long)z * sC;
  short* Chb = Ch + (long)z * sC;
  short* Clb = Cl + (long)z * sC;

  if constexpr (EPI == 1) {
    // fused Poincare distance + mask: -2*atanh(m)/exp(scale)
    //   = nls * log2((1+m)*rcp(1-m)),  nls = -ln2/exp(scale)
    float nls = -0.69314718055994531f * frcp(expf(scalep[0]));
    float yv4[4]; float mk4[4]; int gn4[4];
    #pragma unroll
    for (int nj = 0; nj < 4; nj++) {
      int gn = n0 + wc * 64 + nj * 16 + lm;
      gn4[nj] = gn;
      yv4[nj] = y2a[(long)z * N + gn];
      mk4[nj] = fmask[(long)z * N + gn];
    }
    #pragma unroll
    for (int mi = 0; mi < 4; mi++) {
      #pragma unroll
      for (int r = 0; r < 4; r++) {
        int gm = m0 + wr * 64 + mi * 16 + quad * 4 + r;
        float xv = q2[(long)z * M + gm];
        #pragma unroll
        for (int nj = 0; nj < 4; nj++) {
          float c = acc[mi][nj][r];
          float yv = yv4[nj];
          float num = fmaxf(xv - 2.0f * c + yv, 0.0f);
          float den = fmaxf(fmaf(xv, yv, 1.0f - 2.0f * c), EPSV);
          float mm = sqrtf(num * frcp(den));
          float m = fminf(mm, CLIPV);
          float sc = nls * flog2((1.0f + m) * frcp(1.0f - m));
          if (mk4[nj] > 0.5f) sc = -INFINITY;
          Cb[(long)gm * N + gn4[nj]] = sc;
        }
      }
    }
  } else {
    #pragma unroll
    for (int mi = 0; mi < 4; mi++) {
      #pragma unroll
      for (int r = 0; r < 4; r++) {
        int gm = m0 + wr * 64 + mi * 16 + quad * 4 + r;
        #pragma unroll
        for (int nj = 0; nj < 4; nj++) {
          int gn = n0 + wc * 64 + nj * 16 + lm;
          float c = acc[mi][nj][r];
          if constexpr (EPI == 0) {
            Cb[(long)gm * N + gn] = c;
          } else {
            short hh, ll; bsplit(c, hh, ll);
            Chb[(long)gm * N + gn] = hh;
            Clb[(long)gm * N + gn] = ll;
          }
        }
      }
    }
  }
}

// ---------- q = msm(sqrt(.5), mobius_add(tgt, poincare_linear(x,w_in,b_in))) ----------
__global__ void k_q(short* gh, short* gl, const float* __restrict__ tgt,
                    const float* __restrict__ ch2, const float* __restrict__ sh2,
                    const float* __restrict__ rzn, const float* __restrict__ zn2,
                    const float* __restrict__ x2, float* __restrict__ q2) {
  __shared__ float red4[4];
  long row = blockIdx.x;
  int t = threadIdx.x;
  float cx2 = x2[row];
  float rdpl = 1.0f / fmaxf(1.0f - cx2, EPSV);
  float opc = 1.0f + cx2;

  float wv[3]; float sw2 = 0.f;
  #pragma unroll
  for (int j = 0; j < 3; j++) {
    int e = t + j * 256;
    float u = (bf2f(gh[row * EE + e]) + bf2f(gl[row * EE + e])) * rzn[e];
    float nm = fmaf(2.0f * u, ch2[e], -opc * sh2[e]);
    wv[j] = sinh_g_asinh(zn2[e], nm * rdpl);
    sw2 += wv[j] * wv[j];
  }
  sw2 = block_sum(sw2, red4);
  float rpden = 1.0f / (1.0f + sqrtf(1.0f + sw2));

  float pv[3], tv[3];
  float tp = 0.f, p2 = 0.f, t2 = 0.f;
  #pragma unroll
  for (int j = 0; j < 3; j++) {
    int e = t + j * 256;
    pv[j] = wv[j] * rpden;
    tv[j] = tgt[row * EE + e];
    tp += tv[j] * pv[j]; p2 += pv[j] * pv[j]; t2 += tv[j] * tv[j];
  }
  tp = block_sum(tp, red4);
  p2 = block_sum(p2, red4);
  t2 = block_sum(t2, red4);

  float rmden = 1.0f / fmaxf(1.0f + 2.0f * tp + t2 * p2, EPSV);
  float cT = 1.0f + 2.0f * tp + p2;
  float cP = 1.0f - t2;
  float av[3]; float n2 = 0.f;
  #pragma unroll
  for (int j = 0; j < 3; j++) { av[j] = (cT * tv[j] + cP * pv[j]) * rmden; n2 += av[j] * av[j]; }
  n2 = block_sum(n2, red4);

  float n = sqrtf(fmaxf(n2, EPSV));
  float f = tanh_r_atanh_over_n(0.70710678118654752f, n);
  #pragma unroll
  for (int j = 0; j < 3; j++) {
    int e = t + j * 256;
    short h, lo; bsplit(f * av[j], h, lo);
    gh[row * EE + e] = h; gl[row * EE + e] = lo;
  }
  if (t == 0) q2[row] = f * f * n2;
}

// ---------- softmax: reads f32 scores, writes attn hi/lo planes + den ----------
__global__ void k_softmax(const float* __restrict__ S, const float* __restrict__ gam,
                          float* __restrict__ denr,
                          short* __restrict__ ah, short* __restrict__ al) {
  __shared__ float red4[4];
  long row = blockIdx.x;
  int b = (int)(row / TT);
  int t = threadIdx.x;
  const float* rowp = S + row * SS;

  float v[4];
  float mx = -INFINITY;
  #pragma unroll
  for (int j = 0; j < 4; j++) { v[j] = rowp[t + j * 256]; mx = fmaxf(mx, v[j]); }
  mx = block_max(mx, red4);
  bool dead = !(mx > -INFINITY) || (mx != mx);
  float sum = 0.f;
  #pragma unroll
  for (int j = 0; j < 4; j++) {
    v[j] = dead ? 0.f : fexp2((v[j] - mx) * LOG2E);
    sum += v[j];
  }
  sum = block_sum(sum, red4);
  float inv = (sum > 0.f) ? 1.0f / sum : 0.f;
  float ds = 0.f;
  #pragma unroll
  for (int j = 0; j < 4; j++) {
    int s = t + j * 256;
    float a = v[j] * inv;
    short h, lo; bsplit(a, h, lo);
    ah[row * SS + s] = h; al[row * SS + s] = lo;
    ds += a * (gam[(long)b * SS + s] - 1.0f);
  }
  ds = block_sum(ds, red4);
  if (t == 0) denr[row] = (inv == 0.f) ? 1.0f : ds;
}

// ---------- out2 = msm(sqrt(s_b), msm(0.5, nom/den)) — IN-PLACE on planes ----------
__global__ void k_mid(short* gh, short* gl, const float* __restrict__ denr,
                      const float* __restrict__ ssb, float* __restrict__ o2) {
  __shared__ float red4[4];
  long row = blockIdx.x;
  int b = (int)(row / TT);
  int t = threadIdx.x;
  float d = denr[row];
  if (fabsf(d) < 1e-10f) d = 1e-10f;
  float rd = 1.0f / d;

  float v[3]; float n2 = 0.f;
  #pragma unroll
  for (int j = 0; j < 3; j++) {
    int e = t + j * 256;
    v[j] = (bf2f(gh[row * EE + e]) + bf2f(gl[row * EE + e])) * rd;
    n2 += v[j] * v[j];
  }
  n2 = block_sum(n2, red4);
  float n = sqrtf(fmaxf(n2, EPSV));
  float m = fminf(n, CLIPV);
  float f1 = m / ((1.0f + sqrtf(fmaxf(1.0f - m * m, 0.0f))) * n);

  float m2 = 0.f;
  #pragma unroll
  for (int j = 0; j < 3; j++) { v[j] *= f1; m2 += v[j] * v[j]; }
  m2 = block_sum(m2, red4);
  float n1 = sqrtf(fmaxf(m2, EPSV));
  float f2 = tanh_r_atanh_over_n(ssb[b], n1);

  float s2 = 0.f;
  #pragma unroll
  for (int j = 0; j < 3; j++) {
    int e = t + j * 256;
    v[j] *= f2; s2 += v[j] * v[j];
    short h, lo; bsplit(v[j], h, lo);
    gh[row * EE + e] = h; gl[row * EE + e] = lo;
  }
  s2 = block_sum(s2, red4);
  if (t == 0) o2[row] = s2;
}

// ---------- final epilogue ----------
__global__ void k_final(const float* __restrict__ G, const float* __restrict__ xin,
                        const float* __restrict__ ch2, const float* __restrict__ sh2,
                        const float* __restrict__ rzn, const float* __restrict__ zn2,
                        const float* __restrict__ x2, const float* __restrict__ o2,
                        float* __restrict__ outp) {
  __shared__ float red4[4];
  long row = blockIdx.x;
  int t = threadIdx.x;
  float cx2 = o2[row];
  float rdpl = 1.0f / fmaxf(1.0f - cx2, EPSV);
  float opc = 1.0f + cx2;

  float wv[2]; float sw2 = 0.f;
  #pragma unroll
  for (int j = 0; j < 2; j++) {
    int c = t + j * 256;
    float u = G[row * CCH + c] * rzn[c];
    float nm = fmaf(2.0f * u, ch2[c], -opc * sh2[c]);
    wv[j] = sinh_g_asinh(zn2[c], nm * rdpl);
    sw2 += wv[j] * wv[j];
  }
  sw2 = block_sum(sw2, red4);
  float rpden = 1.0f / (1.0f + sqrtf(1.0f + sw2));

  float pv[2], xv[2];
  float xp = 0.f, p2 = 0.f;
  #pragma unroll
  for (int j = 0; j < 2; j++) {
    int c = t + j * 256;
    pv[j] = wv[j] * rpden;
    xv[j] = xin[row * CCH + c];
    xp += xv[j] * pv[j]; p2 += pv[j] * pv[j];
  }
  xp = block_sum(xp, red4);
  p2 = block_sum(p2, red4);

  float xx = x2[row];
  float rmden = 1.0f / fmaxf(1.0f + 2.0f * xp + xx * p2, EPSV);
  float cX = 1.0f + 2.0f * xp + p2;
  float cP = 1.0f - xx;
  float av[2]; float n2 = 0.f;
  #pragma unroll
  for (int j = 0; j < 2; j++) { av[j] = (cX * xv[j] + cP * pv[j]) * rmden; n2 += av[j] * av[j]; }
  n2 = block_sum(n2, red4);

  float n = sqrtf(fmaxf(n2, EPSV));
  float f = tanh_r_atanh_over_n(0.70710678118654752f, n);
  #pragma unroll
  for (int j = 0; j < 2; j++) { int c = t + j * 256; outp[row * CCH + c] = f * av[j]; }
}

extern "C" void kernel_launch(void* const* d_in, const int* in_sizes, int n_in,
                              void* d_out, int out_size, void* d_ws, size_t ws_size,
                              hipStream_t stream) {
  const float* x    = (const float*)d_in[0];
  const float* tgt  = (const float*)d_in[1];
  const float* enca = (const float*)d_in[2];
  const float* encb = (const float*)d_in[3];
  const void*  mraw = d_in[4];
  const float* win  = (const float*)d_in[5];
  const float* bin  = (const float*)d_in[6];
  const float* wout = (const float*)d_in[7];
  const float* bout = (const float*)d_in[8];
  const float* scalep = (const float*)d_in[9];

  float* out_main = (float*)d_out;                       // [B,T,CCH] f32 (33.55 MB)
  float* out_attn = out_main + (long)BB * TT * CCH;      // [B,T,S]  f32 (67.11 MB)

  // ---- d_out scratch aliases ----
  short* xh  = (short*)out_attn;
  short* xl  = xh + (long)BB * TT * CCH;
  short* G4h = (short*)out_attn;
  short* G4l = G4h + (long)BB * TT * EE;
  short* ATh = (short*)out_main;

  // ---- workspace (same proven 104.1 MB budget + few KB of invariants) ----
  char* wb = (char*)d_ws;
  short* P0   = (short*)wb;  wb += (long)BB * TT * EE * 2;
  short* P1   = (short*)wb;  wb += (long)BB * TT * EE * 2;
  short* G1h = P0, *G1l = P1;
  short* ATl = P0;
  short* tspH = (short*)wb;  wb += (long)BB * SS * EE * 2;
  short* tspL = (short*)wb;  wb += (long)BB * SS * EE * 2;
  float* Gw   = (float*)tspH;
  short* winTh  = (short*)wb;  wb += (long)CCH * EE * 2;
  short* winTl  = (short*)wb;  wb += (long)CCH * EE * 2;
  short* woutTh = (short*)wb;  wb += (long)EE * CCH * 2;
  short* woutTl = (short*)wb;  wb += (long)EE * CCH * 2;
  float* sm     = (float*)wb;
  float* x2a  = sm; sm += BB * TT;
  float* q2a  = sm; sm += BB * TT;
  float* y2a  = sm; sm += BB * SS;
  float* gam  = sm; sm += BB * SS;
  float* denr = sm; sm += BB * TT;
  float* o2a  = sm; sm += BB * TT;
  float* znin = sm; sm += EE;
  float* znout= sm; sm += CCH;
  float* ssb  = sm; sm += BB;
  float* fmask= sm; sm += BB * SS;
  float* ch2i = sm; sm += EE;
  float* sh2i = sm; sm += EE;
  float* rzni = sm; sm += EE;
  float* zn2i = sm; sm += EE;
  float* ch2o = sm; sm += CCH;
  float* sh2o = sm; sm += CCH;
  float* rzno = sm; sm += CCH;
  float* zn2o = sm; sm += CCH;
  int*   mflag= (int*)sm; sm += 1;

  // mask canonicalization
  k_maskdet<<<1, 256, 0, stream>>>((const unsigned char*)mraw, mflag);
  k_maskconv<<<BB * SS / 256, 256, 0, stream>>>(mraw, mflag, fmask);

  // prep
  k_colnorm<<<EE, 256, 0, stream>>>(win, znin, CCH, EE);
  k_colnorm<<<CCH, 256, 0, stream>>>(wout, znout, EE, CCH);
  k_trig<<<3, 256, 0, stream>>>(bin, znin, bout, znout,
                                ch2i, sh2i, rzni, zn2i, ch2o, sh2o, rzno, zn2o);
  k_row2<<<BB * TT, 256, 0, stream>>>(x, x2a, CCH);
  k_gamma<<<BB * SS, 256, 0, stream>>>(encb, gam);
  k_y2b<<<dim3(SS / 64, BB), 256, 0, stream>>>(enca, y2a);
  k_sb<<<BB, 256, 0, stream>>>(fmask, ssb);

  // weight transposes + split
  k_tsp<<<dim3(EE / 32, CCH / 32, 1), dim3(32, 8), 0, stream>>>(
      win, winTh, winTl, nullptr, CCH, EE, 0, 0);
  k_tsp<<<dim3(CCH / 32, EE / 32, 1), dim3(32, 8), 0, stream>>>(
      wout, woutTh, woutTl, nullptr, EE, CCH, 0, 0);

  // enc_a [E,S] -> eaT [S,E] hi/lo
  k_tsp<<<dim3(SS / 32, EE / 32, BB), dim3(32, 8), 0, stream>>>(
      enca, tspH, tspL, nullptr, EE, SS, (long)EE * SS, (long)SS * EE);

  // x -> hi/lo planes (GEMM1 A), scratch in out_attn region
  k_split<<<(BB * TT * CCH / 4 + 255) / 256, 256, 0, stream>>>(
      x, xh, xl, (long)BB * TT * CCH / 4);

  // GEMM1: x @ w_in -> G1 planes (P0/P1)
  mgemm<2><<<dim3(EE / BN, BB * TT / BM, 1), 256, 0, stream>>>(
      xh, xl, winTh, winTl, nullptr, G1h, G1l, BB * TT, EE, CCH, 0, 0, 0,
      nullptr, nullptr, nullptr, nullptr);

  // k_q: in-place G1 planes -> q planes (+ q2)
  k_q<<<BB * TT, 256, 0, stream>>>(G1h, G1l, tgt, ch2i, sh2i, rzni, zn2i, x2a, q2a);

  // GEMM2 (batched) + dist epilogue: scores -> out_attn f32
  mgemm<1><<<dim3(SS / BN, TT / BM, BB), 256, 0, stream>>>(
      G1h, G1l, tspH, tspL, out_attn, nullptr, nullptr, TT, SS, EE,
      (long)TT * EE, (long)SS * EE, (long)TT * SS, q2a, y2a, fmask, scalep);

  // enc_b [S,E] scaled by gamma -> ebT [E,S] hi/lo (overwrites eaT)
  k_tsp<<<dim3(EE / 32, SS / 32, BB), dim3(32, 8), 0, stream>>>(
      encb, tspH, tspL, gam, SS, EE, (long)SS * EE, (long)EE * SS);

  // softmax: scores f32 -> attn planes (ATh in out_main, ATl in pool) + denr
  k_softmax<<<BB * TT, 256, 0, stream>>>(out_attn, gam, denr, ATh, ATl);

  // GEMM4 (batched): attn @ (gamma*enc_b) -> G4 planes (out_attn region)
  mgemm<2><<<dim3(EE / BN, TT / BM, BB), 256, 0, stream>>>(
      ATh, ATl, tspH, tspL, nullptr, G4h, G4l, TT, EE, SS,
      (long)TT * SS, (long)EE * SS, (long)TT * EE, nullptr, nullptr, nullptr, nullptr);

  // k_mid: in-place G4 planes -> M planes (+ o2)
  k_mid<<<BB * TT, 256, 0, stream>>>(G4h, G4l, denr, ssb, o2a);

  // GEMM5: M @ w_out -> Gw f32 (T region; ebT dead)
  mgemm<0><<<dim3(CCH / BN, BB * TT / BM, 1), 256, 0, stream>>>(
      G4h, G4l, woutTh, woutTl, Gw, nullptr, nullptr, BB * TT, CCH, EE, 0, 0, 0,
      nullptr, nullptr, nullptr, nullptr);

  // reconstruct attn f32 output from planes
  k_rec<<<(int)((long)BB * TT * SS / 4 / 256), 256, 0, stream>>>(
      ATh, ATl, out_attn, (long)BB * TT * SS / 4);

  // final epilogue (overwrites out_main)
  k_final<<<BB * TT, 256, 0, stream>>>(Gw, x, ch2o, sh2o, rzno, zn2o, x2a, o2a, out_main);
}

// Round 7
// 811.198 us; speedup vs baseline: 2.0633x; 1.0045x over previous
//
#include <hip/hip_runtime.h>
#include <hip/hip_bf16.h>
#include <math.h>

#define BB 16
#define TT 1024
#define SS 1024
#define CCH 512
#define EE 768
#define EPSV 1e-15f
#define CLIPV (1.0f - 1e-5f)
#define LOG2E 1.4426950408889634f

#define BM 128
#define BN 128
#define BK 32

typedef __attribute__((ext_vector_type(8))) short short8_t;
typedef __attribute__((ext_vector_type(4))) short short4_t;
typedef __attribute__((ext_vector_type(4))) float floatx4;

union BFU { __hip_bfloat16 b; short s; };

static __device__ __forceinline__ void bsplit(float x, short& h, short& l) {
  BFU u1; u1.b = __float2bfloat16(x);
  float hf = __bfloat162float(u1.b);
  BFU u2; u2.b = __float2bfloat16(x - hf);
  h = u1.s; l = u2.s;
}

static __device__ __forceinline__ float bf2f(short s) {
  BFU u; u.s = s; return __bfloat162float(u.b);
}

static __device__ __forceinline__ float fexp2(float x) { return __builtin_amdgcn_exp2f(x); }
static __device__ __forceinline__ float flog2(float x) { return __builtin_amdgcn_logf(x); }
static __device__ __forceinline__ float frcp(float x)  { return __builtin_amdgcn_rcpf(x); }

// sinh(g * asinh(t)) = 0.5*(p^g - p^-g), p = |t| + sqrt(t^2+1), sign-restored
static __device__ __forceinline__ float sinh_g_asinh(float g, float t) {
  float s = fabsf(t);
  float p = s + sqrtf(fmaf(s, s, 1.0f));
  float P = fexp2(g * flog2(p));
  float w = 0.5f * (P - frcp(P));
  return copysignf(w, t);
}

// tanh(r * atanh(min(n,CLIP))) / n  via Q^r, Q=(1+m)/(1-m); exp clamped vs overflow
static __device__ __forceinline__ float tanh_r_atanh_over_n(float r, float n) {
  float m = fminf(n, CLIPV);
  float Q = (1.0f + m) * frcp(1.0f - m);
  float E = fminf(r * flog2(Q), 126.0f);
  float P = fexp2(E);
  float f = (P - 1.0f) * frcp((P + 1.0f) * n);
  return (n < 1e-4f) ? r : f;
}

// async global->LDS, 16 B per lane; LDS dest = wave-uniform base + lane*16
static __device__ __forceinline__ void gl16(const short* g, short* lds_base) {
  __builtin_amdgcn_global_load_lds(
      (const __attribute__((address_space(1))) unsigned int*)g,
      (__attribute__((address_space(3))) unsigned int*)lds_base, 16, 0, 0);
}

static __device__ __forceinline__ float wave_sum(float v) {
  #pragma unroll
  for (int m = 32; m; m >>= 1) v += __shfl_xor(v, m, 64);
  return v;
}
static __device__ __forceinline__ float wave_max(float v) {
  #pragma unroll
  for (int m = 32; m; m >>= 1) v = fmaxf(v, __shfl_xor(v, m, 64));
  return v;
}

__device__ __forceinline__ float block_sum(float v, float* red4) {
  v = wave_sum(v);
  int w = threadIdx.x >> 6;
  if ((threadIdx.x & 63) == 0) red4[w] = v;
  __syncthreads();
  float r = red4[0] + red4[1] + red4[2] + red4[3];
  __syncthreads();
  return r;
}

__device__ __forceinline__ float block_max(float v, float* red4) {
  v = wave_max(v);
  int w = threadIdx.x >> 6;
  if ((threadIdx.x & 63) == 0) red4[w] = v;
  __syncthreads();
  float r = fmaxf(fmaxf(red4[0], red4[1]), fmaxf(red4[2], red4[3]));
  __syncthreads();
  return r;
}

// ---------- mask dtype detection + conversion ----------
__global__ void k_maskdet(const unsigned char* __restrict__ mb, int* __restrict__ flag) {
  __shared__ int any;
  if (threadIdx.x == 0) any = 0;
  __syncthreads();
  int local = 0;
  for (int i = threadIdx.x; i < BB * SS; i += 256)
    if ((i & 3) && mb[i]) local = 1;
  if (local) atomicOr(&any, 1);
  __syncthreads();
  if (threadIdx.x == 0) *flag = any;
}

__global__ void k_maskconv(const void* __restrict__ mraw, const int* __restrict__ flag,
                           float* __restrict__ fmask) {
  int i = blockIdx.x * 256 + threadIdx.x;
  if (i >= BB * SS) return;
  int f = *flag;
  int v = f ? (int)((const unsigned char*)mraw)[i] : ((const int*)mraw)[i];
  fmask[i] = v ? 1.0f : 0.0f;
}

// ---------- prep ----------
__global__ void k_colnorm(const float* __restrict__ z, float* __restrict__ zn, int K, int N) {
  __shared__ float red4[4];
  int e = blockIdx.x;
  float s = 0.f;
  for (int k = threadIdx.x; k < K; k += 256) {
    float v = z[(long)k * N + e];
    s += v * v;
  }
  s = block_sum(s, red4);
  if (threadIdx.x == 0) zn[e] = sqrtf(fmaxf(s, EPSV));
}

// per-column invariants: cosh/sinh(2*bias), 1/zn, 2*zn — for both layers
__global__ void k_trig(const float* __restrict__ bin, const float* __restrict__ znin,
                       const float* __restrict__ bout, const float* __restrict__ znout,
                       float* __restrict__ ch2i, float* __restrict__ sh2i,
                       float* __restrict__ rzni, float* __restrict__ zn2i,
                       float* __restrict__ ch2o, float* __restrict__ sh2o,
                       float* __restrict__ rzno, float* __restrict__ zn2o) {
  int i = blockIdx.x * 256 + threadIdx.x;
  if (i < EE) {
    float r2 = 2.0f * bin[i];
    ch2i[i] = coshf(r2); sh2i[i] = sinhf(r2);
    float z = znin[i]; rzni[i] = 1.0f / z; zn2i[i] = 2.0f * z;
  }
  if (i < CCH) {
    float r2 = 2.0f * bout[i];
    ch2o[i] = coshf(r2); sh2o[i] = sinhf(r2);
    float z = znout[i]; rzno[i] = 1.0f / z; zn2o[i] = 2.0f * z;
  }
}

__global__ void k_row2(const float* __restrict__ xp, float* __restrict__ out, int D) {
  __shared__ float red4[4];
  long row = blockIdx.x;
  float s = 0.f;
  for (int c = threadIdx.x; c < D; c += 256) { float v = xp[row * D + c]; s += v * v; }
  s = block_sum(s, red4);
  if (threadIdx.x == 0) out[row] = s;
}

// gamma[b,s] = 2/max(1-|encb row|^2, EPS)
__global__ void k_gamma(const float* __restrict__ encb, float* __restrict__ gam) {
  __shared__ float red4[4];
  long row = blockIdx.x;
  int t = threadIdx.x;
  float s2 = 0.f;
  #pragma unroll
  for (int j = 0; j < 3; j++) { float v = encb[row * EE + t + j * 256]; s2 += v * v; }
  s2 = block_sum(s2, red4);
  if (t == 0) gam[row] = 2.0f / fmaxf(1.0f - s2, EPSV);
}

// y2a[b,s] = sum_e enc_a[b,e,s]^2  (enc_a is [B,E,S]); grid (S/64, B), 256 thr
__global__ void k_y2b(const float* __restrict__ enca, float* __restrict__ y2a) {
  __shared__ float red[256];
  int b = blockIdx.y, s0 = blockIdx.x * 64;
  int si = threadIdx.x & 63, eg = threadIdx.x >> 6;
  const float* p = enca + (long)b * EE * SS + s0 + si;
  float acc = 0.f;
  for (int e = eg; e < EE; e += 4) { float v = p[(long)e * SS]; acc += v * v; }
  red[threadIdx.x] = acc; __syncthreads();
  if (eg == 0)
    y2a[(long)b * SS + s0 + si] = red[si] + red[si + 64] + red[si + 128] + red[si + 192];
}

__global__ void k_sb(const float* __restrict__ fmask, float* __restrict__ ssb) {
  __shared__ float red4[4];
  int b = blockIdx.x;
  float cnt = 0.f;
  for (int s = threadIdx.x; s < SS; s += 256) cnt += fmask[(long)b * SS + s];
  cnt = block_sum(cnt, red4);
  if (threadIdx.x == 0) ssb[b] = sqrtf((float)SS - cnt);
}

// ---------- fp32 -> bf16 hi/lo plane split (row-major copy, vectorized) ----------
__global__ void k_split(const float* __restrict__ in, short* __restrict__ oh,
                        short* __restrict__ ol, long n4) {
  long i = (long)blockIdx.x * 256 + threadIdx.x;
  if (i >= n4) return;
  floatx4 v = ((const floatx4*)in)[i];
  short4_t h4, l4;
  #pragma unroll
  for (int c = 0; c < 4; c++) { short hh, ll; bsplit(v[c], hh, ll); h4[c] = hh; l4[c] = ll; }
  ((short4_t*)oh)[i] = h4;
  ((short4_t*)ol)[i] = l4;
}

// ---------- attn f32 reconstruction from hi/lo planes ----------
__global__ void k_rec(const short* __restrict__ ah, const short* __restrict__ al,
                      float* __restrict__ outp, long n4) {
  long i = (long)blockIdx.x * 256 + threadIdx.x;
  if (i >= n4) return;
  short4_t h4 = ((const short4_t*)ah)[i];
  short4_t l4 = ((const short4_t*)al)[i];
  floatx4 r;
  #pragma unroll
  for (int c = 0; c < 4; c++) r[c] = bf2f(h4[c]) + bf2f(l4[c]);
  ((floatx4*)outp)[i] = r;
}

// ---------- transpose + bf16 hi/lo split (optional per-input-row scale) ----------
__global__ void k_tsp(const float* __restrict__ in, short* __restrict__ oh,
                      short* __restrict__ ol, const float* __restrict__ rs,
                      int R, int C, long sin, long sout) {
  __shared__ float tile[32][33];
  int z = blockIdx.z;
  const float* ib = in + (long)z * sin;
  short* ohb = oh + (long)z * sout;
  short* olb = ol + (long)z * sout;
  int c0 = blockIdx.x * 32, r0 = blockIdx.y * 32;
  int tx = threadIdx.x, ty = threadIdx.y;
  #pragma unroll
  for (int i = 0; i < 4; i++) {
    int rr = ty + i * 8;
    float v = ib[(long)(r0 + rr) * C + c0 + tx];
    if (rs) v *= rs[(long)z * R + r0 + rr];
    tile[rr][tx] = v;
  }
  __syncthreads();
  #pragma unroll
  for (int i = 0; i < 4; i++) {
    int cc = ty + i * 8;
    float v = tile[tx][cc];
    short h, l; bsplit(v, h, l);
    long o = (long)(c0 + cc) * R + r0 + tx;
    ohb[o] = h; olb[o] = l;
  }
}

// ---------- split-bf16 MFMA GEMM, double-buffered, LDS chunk-swizzled,
// counted-vmcnt pipeline (T4): the K-loop never drains vmcnt to 0 — after
// issuing STAGE(t+1)'s 8 loads, s_waitcnt vmcnt(8) waits only for STAGE(t),
// then raw s_barrier. Second raw barrier after compute orders readers of
// buf[cur] before its restage. sched_barrier(0) pins LDS reads inside. ----------
template <int EPI>
__global__ __launch_bounds__(256)
void mgemm(const short* __restrict__ Agh, const short* __restrict__ Agl,
           const short* __restrict__ BTh, const short* __restrict__ BTl,
           float* __restrict__ Cm, short* __restrict__ Ch, short* __restrict__ Cl,
           int M, int N, int K, long sA, long sBT, long sC,
           const float* __restrict__ q2, const float* __restrict__ y2a,
           const float* __restrict__ fmask, const float* __restrict__ scalep) {
  __shared__ alignas(16) short Ah[2][BM * BK];
  __shared__ alignas(16) short Al[2][BM * BK];
  __shared__ alignas(16) short Bh[2][BN * BK];
  __shared__ alignas(16) short Bl[2][BN * BK];

  int gx = gridDim.x, gy = gridDim.y;
  int nwg = gx * gy * gridDim.z;
  int lin = blockIdx.x + gx * (blockIdx.y + gy * blockIdx.z);
  int swz = (lin & 7) * (nwg >> 3) + (lin >> 3);
  int bx = swz % gx; int tmp = swz / gx; int by = tmp % gy; int bz = tmp / gy;

  int z = bz;
  const short* Ahb = Agh + (long)z * sA;
  const short* Alb = Agl + (long)z * sA;
  const short* Bhb = BTh + (long)z * sBT;
  const short* Blb = BTl + (long)z * sBT;
  int m0 = by * BM, n0 = bx * BN;
  int t = threadIdx.x;
  int w = t >> 6, l = t & 63;
  int wr = w >> 1, wc = w & 1;
  int quad = l >> 4, lm = l & 15;

  int srow = (w << 5) + (l >> 2);
  int scol = (((l & 3) ^ ((l >> 3) & 3)) << 3);   // swizzled global source chunk
  int wbase = (w << 10);
  int qs = ((quad ^ ((lm >> 1) & 3)) << 3);       // swizzled LDS read slot (shorts)

  auto STAGE = [&](int buf, int kk) {
    const short* gAh = Ahb + (long)(m0 + srow) * K + kk + scol;
    const short* gAl = Alb + (long)(m0 + srow) * K + kk + scol;
    const short* gBh = Bhb + (long)(n0 + srow) * K + kk + scol;
    const short* gBl = Blb + (long)(n0 + srow) * K + kk + scol;
    #pragma unroll
    for (int u = 0; u < 2; u++) {
      long go = (long)(u * 16) * K;
      gl16(gAh + go, &Ah[buf][wbase + (u << 9)]);
      gl16(gAl + go, &Al[buf][wbase + (u << 9)]);
      gl16(gBh + go, &Bh[buf][wbase + (u << 9)]);
      gl16(gBl + go, &Bl[buf][wbase + (u << 9)]);
    }
  };

  floatx4 acc[4][4];
  #pragma unroll
  for (int i = 0; i < 4; i++)
    #pragma unroll
    for (int j = 0; j < 4; j++) acc[i][j] = (floatx4){0.f, 0.f, 0.f, 0.f};

  STAGE(0, 0);           // 8 loads in flight for buf0
  int cur = 0;

  for (int k0 = 0; k0 < K; k0 += BK) {
    int nxt = k0 + BK;
    if (nxt < K) {
      STAGE(cur ^ 1, nxt);                               // +8 loads (stay in flight)
      asm volatile("s_waitcnt vmcnt(8)" ::: "memory");   // buf[cur]'s 8 landed
    } else {
      asm volatile("s_waitcnt vmcnt(0)" ::: "memory");   // final tile: drain
    }
    __builtin_amdgcn_s_barrier();          // all waves: buf[cur] resident
    __builtin_amdgcn_sched_barrier(0);     // don't hoist ds_reads above barrier

    short8_t bfh[4], bfl[4];
    #pragma unroll
    for (int nj = 0; nj < 4; nj++) {
      int n = wc * 64 + nj * 16 + lm;
      bfh[nj] = *(const short8_t*)&Bh[cur][n * BK + qs];
      bfl[nj] = *(const short8_t*)&Bl[cur][n * BK + qs];
    }
    #pragma unroll
    for (int mi = 0; mi < 4; mi++) {
      int m = wr * 64 + mi * 16 + lm;
      short8_t afh = *(const short8_t*)&Ah[cur][m * BK + qs];
      short8_t afl = *(const short8_t*)&Al[cur][m * BK + qs];
      #pragma unroll
      for (int nj = 0; nj < 4; nj++) {
        acc[mi][nj] = __builtin_amdgcn_mfma_f32_16x16x32_bf16(afh, bfh[nj], acc[mi][nj], 0, 0, 0);
        acc[mi][nj] = __builtin_amdgcn_mfma_f32_16x16x32_bf16(afh, bfl[nj], acc[mi][nj], 0, 0, 0);
        acc[mi][nj] = __builtin_amdgcn_mfma_f32_16x16x32_bf16(afl, bfh[nj], acc[mi][nj], 0, 0, 0);
      }
    }
    __builtin_amdgcn_sched_barrier(0);     // don't sink ds_reads below barrier
    __builtin_amdgcn_s_barrier();          // all done reading buf[cur]; next iter restages it
    cur ^= 1;
  }

  float* Cb = Cm + (long)z * sC;
  short* Chb = Ch + (long)z * sC;
  short* Clb = Cl + (long)z * sC;

  if constexpr (EPI == 1) {
    // fused Poincare distance + mask: -2*atanh(m)/exp(scale)
    //   = nls * log2((1+m)*rcp(1-m)),  nls = -ln2/exp(scale)
    float nls = -0.69314718055994531f * frcp(expf(scalep[0]));
    float yv4[4]; float mk4[4]; int gn4[4];
    #pragma unroll
    for (int nj = 0; nj < 4; nj++) {
      int gn = n0 + wc * 64 + nj * 16 + lm;
      gn4[nj] = gn;
      yv4[nj] = y2a[(long)z * N + gn];
      mk4[nj] = fmask[(long)z * N + gn];
    }
    #pragma unroll
    for (int mi = 0; mi < 4; mi++) {
      #pragma unroll
      for (int r = 0; r < 4; r++) {
        int gm = m0 + wr * 64 + mi * 16 + quad * 4 + r;
        float xv = q2[(long)z * M + gm];
        #pragma unroll
        for (int nj = 0; nj < 4; nj++) {
          float c = acc[mi][nj][r];
          float yv = yv4[nj];
          float num = fmaxf(xv - 2.0f * c + yv, 0.0f);
          float den = fmaxf(fmaf(xv, yv, 1.0f - 2.0f * c), EPSV);
          float mm = sqrtf(num * frcp(den));
          float m = fminf(mm, CLIPV);
          float sc = nls * flog2((1.0f + m) * frcp(1.0f - m));
          if (mk4[nj] > 0.5f) sc = -INFINITY;
          Cb[(long)gm * N + gn4[nj]] = sc;
        }
      }
    }
  } else {
    #pragma unroll
    for (int mi = 0; mi < 4; mi++) {
      #pragma unroll
      for (int r = 0; r < 4; r++) {
        int gm = m0 + wr * 64 + mi * 16 + quad * 4 + r;
        #pragma unroll
        for (int nj = 0; nj < 4; nj++) {
          int gn = n0 + wc * 64 + nj * 16 + lm;
          float c = acc[mi][nj][r];
          if constexpr (EPI == 0) {
            Cb[(long)gm * N + gn] = c;
          } else {
            short hh, ll; bsplit(c, hh, ll);
            Chb[(long)gm * N + gn] = hh;
            Clb[(long)gm * N + gn] = ll;
          }
        }
      }
    }
  }
}

// ---------- q = msm(sqrt(.5), mobius_add(tgt, poincare_linear(x,w_in,b_in))) ----------
__global__ void k_q(short* gh, short* gl, const float* __restrict__ tgt,
                    const float* __restrict__ ch2, const float* __restrict__ sh2,
                    const float* __restrict__ rzn, const float* __restrict__ zn2,
                    const float* __restrict__ x2, float* __restrict__ q2) {
  __shared__ float red4[4];
  long row = blockIdx.x;
  int t = threadIdx.x;
  float cx2 = x2[row];
  float rdpl = 1.0f / fmaxf(1.0f - cx2, EPSV);
  float opc = 1.0f + cx2;

  float wv[3]; float sw2 = 0.f;
  #pragma unroll
  for (int j = 0; j < 3; j++) {
    int e = t + j * 256;
    float u = (bf2f(gh[row * EE + e]) + bf2f(gl[row * EE + e])) * rzn[e];
    float nm = fmaf(2.0f * u, ch2[e], -opc * sh2[e]);
    wv[j] = sinh_g_asinh(zn2[e], nm * rdpl);
    sw2 += wv[j] * wv[j];
  }
  sw2 = block_sum(sw2, red4);
  float rpden = 1.0f / (1.0f + sqrtf(1.0f + sw2));

  float pv[3], tv[3];
  float tp = 0.f, p2 = 0.f, t2 = 0.f;
  #pragma unroll
  for (int j = 0; j < 3; j++) {
    int e = t + j * 256;
    pv[j] = wv[j] * rpden;
    tv[j] = tgt[row * EE + e];
    tp += tv[j] * pv[j]; p2 += pv[j] * pv[j]; t2 += tv[j] * tv[j];
  }
  tp = block_sum(tp, red4);
  p2 = block_sum(p2, red4);
  t2 = block_sum(t2, red4);

  float rmden = 1.0f / fmaxf(1.0f + 2.0f * tp + t2 * p2, EPSV);
  float cT = 1.0f + 2.0f * tp + p2;
  float cP = 1.0f - t2;
  float av[3]; float n2 = 0.f;
  #pragma unroll
  for (int j = 0; j < 3; j++) { av[j] = (cT * tv[j] + cP * pv[j]) * rmden; n2 += av[j] * av[j]; }
  n2 = block_sum(n2, red4);

  float n = sqrtf(fmaxf(n2, EPSV));
  float f = tanh_r_atanh_over_n(0.70710678118654752f, n);
  #pragma unroll
  for (int j = 0; j < 3; j++) {
    int e = t + j * 256;
    short h, lo; bsplit(f * av[j], h, lo);
    gh[row * EE + e] = h; gl[row * EE + e] = lo;
  }
  if (t == 0) q2[row] = f * f * n2;
}

// ---------- softmax: reads f32 scores, writes attn hi/lo planes + den ----------
__global__ void k_softmax(const float* __restrict__ S, const float* __restrict__ gam,
                          float* __restrict__ denr,
                          short* __restrict__ ah, short* __restrict__ al) {
  __shared__ float red4[4];
  long row = blockIdx.x;
  int b = (int)(row / TT);
  int t = threadIdx.x;
  const float* rowp = S + row * SS;

  float v[4];
  float mx = -INFINITY;
  #pragma unroll
  for (int j = 0; j < 4; j++) { v[j] = rowp[t + j * 256]; mx = fmaxf(mx, v[j]); }
  mx = block_max(mx, red4);
  bool dead = !(mx > -INFINITY) || (mx != mx);
  float sum = 0.f;
  #pragma unroll
  for (int j = 0; j < 4; j++) {
    v[j] = dead ? 0.f : fexp2((v[j] - mx) * LOG2E);
    sum += v[j];
  }
  sum = block_sum(sum, red4);
  float inv = (sum > 0.f) ? 1.0f / sum : 0.f;
  float ds = 0.f;
  #pragma unroll
  for (int j = 0; j < 4; j++) {
    int s = t + j * 256;
    float a = v[j] * inv;
    short h, lo; bsplit(a, h, lo);
    ah[row * SS + s] = h; al[row * SS + s] = lo;
    ds += a * (gam[(long)b * SS + s] - 1.0f);
  }
  ds = block_sum(ds, red4);
  if (t == 0) denr[row] = (inv == 0.f) ? 1.0f : ds;
}

// ---------- out2 = msm(sqrt(s_b), msm(0.5, nom/den)) — IN-PLACE on planes ----------
__global__ void k_mid(short* gh, short* gl, const float* __restrict__ denr,
                      const float* __restrict__ ssb, float* __restrict__ o2) {
  __shared__ float red4[4];
  long row = blockIdx.x;
  int b = (int)(row / TT);
  int t = threadIdx.x;
  float d = denr[row];
  if (fabsf(d) < 1e-10f) d = 1e-10f;
  float rd = 1.0f / d;

  float v[3]; float n2 = 0.f;
  #pragma unroll
  for (int j = 0; j < 3; j++) {
    int e = t + j * 256;
    v[j] = (bf2f(gh[row * EE + e]) + bf2f(gl[row * EE + e])) * rd;
    n2 += v[j] * v[j];
  }
  n2 = block_sum(n2, red4);
  float n = sqrtf(fmaxf(n2, EPSV));
  float m = fminf(n, CLIPV);
  float f1 = m / ((1.0f + sqrtf(fmaxf(1.0f - m * m, 0.0f))) * n);

  float m2 = 0.f;
  #pragma unroll
  for (int j = 0; j < 3; j++) { v[j] *= f1; m2 += v[j] * v[j]; }
  m2 = block_sum(m2, red4);
  float n1 = sqrtf(fmaxf(m2, EPSV));
  float f2 = tanh_r_atanh_over_n(ssb[b], n1);

  float s2 = 0.f;
  #pragma unroll
  for (int j = 0; j < 3; j++) {
    int e = t + j * 256;
    v[j] *= f2; s2 += v[j] * v[j];
    short h, lo; bsplit(v[j], h, lo);
    gh[row * EE + e] = h; gl[row * EE + e] = lo;
  }
  s2 = block_sum(s2, red4);
  if (t == 0) o2[row] = s2;
}

// ---------- final epilogue ----------
__global__ void k_final(const float* __restrict__ G, const float* __restrict__ xin,
                        const float* __restrict__ ch2, const float* __restrict__ sh2,
                        const float* __restrict__ rzn, const float* __restrict__ zn2,
                        const float* __restrict__ x2, const float* __restrict__ o2,
                        float* __restrict__ outp) {
  __shared__ float red4[4];
  long row = blockIdx.x;
  int t = threadIdx.x;
  float cx2 = o2[row];
  float rdpl = 1.0f / fmaxf(1.0f - cx2, EPSV);
  float opc = 1.0f + cx2;

  float wv[2]; float sw2 = 0.f;
  #pragma unroll
  for (int j = 0; j < 2; j++) {
    int c = t + j * 256;
    float u = G[row * CCH + c] * rzn[c];
    float nm = fmaf(2.0f * u, ch2[c], -opc * sh2[c]);
    wv[j] = sinh_g_asinh(zn2[c], nm * rdpl);
    sw2 += wv[j] * wv[j];
  }
  sw2 = block_sum(sw2, red4);
  float rpden = 1.0f / (1.0f + sqrtf(1.0f + sw2));

  float pv[2], xv[2];
  float xp = 0.f, p2 = 0.f;
  #pragma unroll
  for (int j = 0; j < 2; j++) {
    int c = t + j * 256;
    pv[j] = wv[j] * rpden;
    xv[j] = xin[row * CCH + c];
    xp += xv[j] * pv[j]; p2 += pv[j] * pv[j];
  }
  xp = block_sum(xp, red4);
  p2 = block_sum(p2, red4);

  float xx = x2[row];
  float rmden = 1.0f / fmaxf(1.0f + 2.0f * xp + xx * p2, EPSV);
  float cX = 1.0f + 2.0f * xp + p2;
  float cP = 1.0f - xx;
  float av[2]; float n2 = 0.f;
  #pragma unroll
  for (int j = 0; j < 2; j++) { av[j] = (cX * xv[j] + cP * pv[j]) * rmden; n2 += av[j] * av[j]; }
  n2 = block_sum(n2, red4);

  float n = sqrtf(fmaxf(n2, EPSV));
  float f = tanh_r_atanh_over_n(0.70710678118654752f, n);
  #pragma unroll
  for (int j = 0; j < 2; j++) { int c = t + j * 256; outp[row * CCH + c] = f * av[j]; }
}

extern "C" void kernel_launch(void* const* d_in, const int* in_sizes, int n_in,
                              void* d_out, int out_size, void* d_ws, size_t ws_size,
                              hipStream_t stream) {
  const float* x    = (const float*)d_in[0];
  const float* tgt  = (const float*)d_in[1];
  const float* enca = (const float*)d_in[2];
  const float* encb = (const float*)d_in[3];
  const void*  mraw = d_in[4];
  const float* win  = (const float*)d_in[5];
  const float* bin  = (const float*)d_in[6];
  const float* wout = (const float*)d_in[7];
  const float* bout = (const float*)d_in[8];
  const float* scalep = (const float*)d_in[9];

  float* out_main = (float*)d_out;                       // [B,T,CCH] f32 (33.55 MB)
  float* out_attn = out_main + (long)BB * TT * CCH;      // [B,T,S]  f32 (67.11 MB)

  // ---- d_out scratch aliases ----
  short* xh  = (short*)out_attn;
  short* xl  = xh + (long)BB * TT * CCH;
  short* G4h = (short*)out_attn;
  short* G4l = G4h + (long)BB * TT * EE;
  short* ATh = (short*)out_main;

  // ---- workspace (same proven 104.1 MB budget + few KB of invariants) ----
  char* wb = (char*)d_ws;
  short* P0   = (short*)wb;  wb += (long)BB * TT * EE * 2;
  short* P1   = (short*)wb;  wb += (long)BB * TT * EE * 2;
  short* G1h = P0, *G1l = P1;
  short* ATl = P0;
  short* tspH = (short*)wb;  wb += (long)BB * SS * EE * 2;
  short* tspL = (short*)wb;  wb += (long)BB * SS * EE * 2;
  float* Gw   = (float*)tspH;
  short* winTh  = (short*)wb;  wb += (long)CCH * EE * 2;
  short* winTl  = (short*)wb;  wb += (long)CCH * EE * 2;
  short* woutTh = (short*)wb;  wb += (long)EE * CCH * 2;
  short* woutTl = (short*)wb;  wb += (long)EE * CCH * 2;
  float* sm     = (float*)wb;
  float* x2a  = sm; sm += BB * TT;
  float* q2a  = sm; sm += BB * TT;
  float* y2a  = sm; sm += BB * SS;
  float* gam  = sm; sm += BB * SS;
  float* denr = sm; sm += BB * TT;
  float* o2a  = sm; sm += BB * TT;
  float* znin = sm; sm += EE;
  float* znout= sm; sm += CCH;
  float* ssb  = sm; sm += BB;
  float* fmask= sm; sm += BB * SS;
  float* ch2i = sm; sm += EE;
  float* sh2i = sm; sm += EE;
  float* rzni = sm; sm += EE;
  float* zn2i = sm; sm += EE;
  float* ch2o = sm; sm += CCH;
  float* sh2o = sm; sm += CCH;
  float* rzno = sm; sm += CCH;
  float* zn2o = sm; sm += CCH;
  int*   mflag= (int*)sm; sm += 1;

  // mask canonicalization
  k_maskdet<<<1, 256, 0, stream>>>((const unsigned char*)mraw, mflag);
  k_maskconv<<<BB * SS / 256, 256, 0, stream>>>(mraw, mflag, fmask);

  // prep
  k_colnorm<<<EE, 256, 0, stream>>>(win, znin, CCH, EE);
  k_colnorm<<<CCH, 256, 0, stream>>>(wout, znout, EE, CCH);
  k_trig<<<3, 256, 0, stream>>>(bin, znin, bout, znout,
                                ch2i, sh2i, rzni, zn2i, ch2o, sh2o, rzno, zn2o);
  k_row2<<<BB * TT, 256, 0, stream>>>(x, x2a, CCH);
  k_gamma<<<BB * SS, 256, 0, stream>>>(encb, gam);
  k_y2b<<<dim3(SS / 64, BB), 256, 0, stream>>>(enca, y2a);
  k_sb<<<BB, 256, 0, stream>>>(fmask, ssb);

  // weight transposes + split
  k_tsp<<<dim3(EE / 32, CCH / 32, 1), dim3(32, 8), 0, stream>>>(
      win, winTh, winTl, nullptr, CCH, EE, 0, 0);
  k_tsp<<<dim3(CCH / 32, EE / 32, 1), dim3(32, 8), 0, stream>>>(
      wout, woutTh, woutTl, nullptr, EE, CCH, 0, 0);

  // enc_a [E,S] -> eaT [S,E] hi/lo
  k_tsp<<<dim3(SS / 32, EE / 32, BB), dim3(32, 8), 0, stream>>>(
      enca, tspH, tspL, nullptr, EE, SS, (long)EE * SS, (long)SS * EE);

  // x -> hi/lo planes (GEMM1 A), scratch in out_attn region
  k_split<<<(BB * TT * CCH / 4 + 255) / 256, 256, 0, stream>>>(
      x, xh, xl, (long)BB * TT * CCH / 4);

  // GEMM1: x @ w_in -> G1 planes (P0/P1)
  mgemm<2><<<dim3(EE / BN, BB * TT / BM, 1), 256, 0, stream>>>(
      xh, xl, winTh, winTl, nullptr, G1h, G1l, BB * TT, EE, CCH, 0, 0, 0,
      nullptr, nullptr, nullptr, nullptr);

  // k_q: in-place G1 planes -> q planes (+ q2)
  k_q<<<BB * TT, 256, 0, stream>>>(G1h, G1l, tgt, ch2i, sh2i, rzni, zn2i, x2a, q2a);

  // GEMM2 (batched) + dist epilogue: scores -> out_attn f32
  mgemm<1><<<dim3(SS / BN, TT / BM, BB), 256, 0, stream>>>(
      G1h, G1l, tspH, tspL, out_attn, nullptr, nullptr, TT, SS, EE,
      (long)TT * EE, (long)SS * EE, (long)TT * SS, q2a, y2a, fmask, scalep);

  // enc_b [S,E] scaled by gamma -> ebT [E,S] hi/lo (overwrites eaT)
  k_tsp<<<dim3(EE / 32, SS / 32, BB), dim3(32, 8), 0, stream>>>(
      encb, tspH, tspL, gam, SS, EE, (long)SS * EE, (long)EE * SS);

  // softmax: scores f32 -> attn planes (ATh in out_main, ATl in pool) + denr
  k_softmax<<<BB * TT, 256, 0, stream>>>(out_attn, gam, denr, ATh, ATl);

  // GEMM4 (batched): attn @ (gamma*enc_b) -> G4 planes (out_attn region)
  mgemm<2><<<dim3(EE / BN, TT / BM, BB), 256, 0, stream>>>(
      ATh, ATl, tspH, tspL, nullptr, G4h, G4l, TT, EE, SS,
      (long)TT * SS, (long)EE * SS, (long)TT * EE, nullptr, nullptr, nullptr, nullptr);

  // k_mid: in-place G4 planes -> M planes (+ o2)
  k_mid<<<BB * TT, 256, 0, stream>>>(G4h, G4l, denr, ssb, o2a);

  // GEMM5: M @ w_out -> Gw f32 (T region; ebT dead)
  mgemm<0><<<dim3(CCH / BN, BB * TT / BM, 1), 256, 0, stream>>>(
      G4h, G4l, woutTh, woutTl, Gw, nullptr, nullptr, BB * TT, CCH, EE, 0, 0, 0,
      nullptr, nullptr, nullptr, nullptr);

  // reconstruct attn f32 output from planes
  k_rec<<<(int)((long)BB * TT * SS / 4 / 256), 256, 0, stream>>>(
      ATh, ATl, out_attn, (long)BB * TT * SS / 4);

  // final epilogue (overwrites out_main)
  k_final<<<BB * TT, 256, 0, stream>>>(Gw, x, ch2o, sh2o, rzno, zn2o, x2a, o2a, out_main);
}

// Round 8
// 734.471 us; speedup vs baseline: 2.2789x; 1.1045x over previous
//
#include <hip/hip_runtime.h>
#include <hip/hip_bf16.h>
#include <math.h>

#define BB 16
#define TT 1024
#define SS 1024
#define CCH 512
#define EE 768
#define EPSV 1e-15f
#define CLIPV (1.0f - 1e-5f)
#define LOG2E 1.4426950408889634f

#define BM 128
#define BN 128
#define BK 32

typedef __attribute__((ext_vector_type(8))) short short8_t;
typedef __attribute__((ext_vector_type(4))) short short4_t;
typedef __attribute__((ext_vector_type(4))) float floatx4;

union BFU { __hip_bfloat16 b; short s; };

static __device__ __forceinline__ void bsplit(float x, short& h, short& l) {
  BFU u1; u1.b = __float2bfloat16(x);
  float hf = __bfloat162float(u1.b);
  BFU u2; u2.b = __float2bfloat16(x - hf);
  h = u1.s; l = u2.s;
}

static __device__ __forceinline__ float bf2f(short s) {
  BFU u; u.s = s; return __bfloat162float(u.b);
}

static __device__ __forceinline__ float fexp2(float x) { return __builtin_amdgcn_exp2f(x); }
static __device__ __forceinline__ float flog2(float x) { return __builtin_amdgcn_logf(x); }
static __device__ __forceinline__ float frcp(float x)  { return __builtin_amdgcn_rcpf(x); }

// sinh(g * asinh(t)) = 0.5*(p^g - p^-g), p = |t| + sqrt(t^2+1), sign-restored
static __device__ __forceinline__ float sinh_g_asinh(float g, float t) {
  float s = fabsf(t);
  float p = s + sqrtf(fmaf(s, s, 1.0f));
  float P = fexp2(g * flog2(p));
  float w = 0.5f * (P - frcp(P));
  return copysignf(w, t);
}

// tanh(r * atanh(min(n,CLIP))) / n  via Q^r, Q=(1+m)/(1-m); exp clamped vs overflow
static __device__ __forceinline__ float tanh_r_atanh_over_n(float r, float n) {
  float m = fminf(n, CLIPV);
  float Q = (1.0f + m) * frcp(1.0f - m);
  float E = fminf(r * flog2(Q), 126.0f);
  float P = fexp2(E);
  float f = (P - 1.0f) * frcp((P + 1.0f) * n);
  return (n < 1e-4f) ? r : f;
}

// async global->LDS, 16 B per lane; LDS dest = wave-uniform base + lane*16
static __device__ __forceinline__ void gl16(const short* g, short* lds_base) {
  __builtin_amdgcn_global_load_lds(
      (const __attribute__((address_space(1))) unsigned int*)g,
      (__attribute__((address_space(3))) unsigned int*)lds_base, 16, 0, 0);
}

static __device__ __forceinline__ float wave_sum(float v) {
  #pragma unroll
  for (int m = 32; m; m >>= 1) v += __shfl_xor(v, m, 64);
  return v;
}
static __device__ __forceinline__ float wave_max(float v) {
  #pragma unroll
  for (int m = 32; m; m >>= 1) v = fmaxf(v, __shfl_xor(v, m, 64));
  return v;
}

__device__ __forceinline__ float block_sum(float v, float* red4) {
  v = wave_sum(v);
  int w = threadIdx.x >> 6;
  if ((threadIdx.x & 63) == 0) red4[w] = v;
  __syncthreads();
  float r = red4[0] + red4[1] + red4[2] + red4[3];
  __syncthreads();
  return r;
}

__device__ __forceinline__ float block_max(float v, float* red4) {
  v = wave_max(v);
  int w = threadIdx.x >> 6;
  if ((threadIdx.x & 63) == 0) red4[w] = v;
  __syncthreads();
  float r = fmaxf(fmaxf(red4[0], red4[1]), fmaxf(red4[2], red4[3]));
  __syncthreads();
  return r;
}

// ---------- mask dtype detection ----------
__global__ void k_maskdet(const unsigned char* __restrict__ mb, int* __restrict__ flag) {
  __shared__ int any;
  if (threadIdx.x == 0) any = 0;
  __syncthreads();
  int local = 0;
  for (int i = threadIdx.x; i < BB * SS; i += 256)
    if ((i & 3) && mb[i]) local = 1;
  if (local) atomicOr(&any, 1);
  __syncthreads();
  if (threadIdx.x == 0) *flag = any;
}

// ---------- FUSED: mask conversion + per-batch sqrt(S - count) ----------
__global__ void k_maskrow(const void* __restrict__ mraw, const int* __restrict__ flag,
                          float* __restrict__ fmask, float* __restrict__ ssb) {
  __shared__ float red4[4];
  int b = blockIdx.x, t = threadIdx.x;
  int f = *flag;
  float cnt = 0.f;
  #pragma unroll
  for (int j = 0; j < 4; j++) {
    long i = (long)b * SS + t + j * 256;
    int v = f ? (int)((const unsigned char*)mraw)[i] : ((const int*)mraw)[i];
    float fv = v ? 1.0f : 0.0f;
    fmask[i] = fv; cnt += fv;
  }
  cnt = block_sum(cnt, red4);
  if (t == 0) ssb[b] = sqrtf((float)SS - cnt);
}

// ---------- FUSED: both weight col-norms + per-column trig invariants + y2a zero ----------
__global__ void k_wprep(const float* __restrict__ win, const float* __restrict__ wout,
                        const float* __restrict__ bin, const float* __restrict__ bout,
                        float* __restrict__ ch2i, float* __restrict__ sh2i,
                        float* __restrict__ rzni, float* __restrict__ zn2i,
                        float* __restrict__ ch2o, float* __restrict__ sh2o,
                        float* __restrict__ rzno, float* __restrict__ zn2o,
                        float* __restrict__ y2a) {
  __shared__ float red4[4];
  int bid = blockIdx.x, t = threadIdx.x;
  if (bid < (BB * SS) / 256) y2a[bid * 256 + t] = 0.f;   // zero before enc_a tsp atomics
  float s = 0.f;
  if (bid < EE) {
    int e = bid;
    for (int k = t; k < CCH; k += 256) { float v = win[(long)k * EE + e]; s += v * v; }
    s = block_sum(s, red4);
    if (t == 0) {
      float z = sqrtf(fmaxf(s, EPSV));
      float r2 = 2.0f * bin[e];
      ch2i[e] = coshf(r2); sh2i[e] = sinhf(r2);
      rzni[e] = 1.0f / z;  zn2i[e] = 2.0f * z;
    }
  } else {
    int e = bid - EE;
    for (int k = t; k < EE; k += 256) { float v = wout[(long)k * CCH + e]; s += v * v; }
    s = block_sum(s, red4);
    if (t == 0) {
      float z = sqrtf(fmaxf(s, EPSV));
      float r2 = 2.0f * bout[e];
      ch2o[e] = coshf(r2); sh2o[e] = sinhf(r2);
      rzno[e] = 1.0f / z;  zn2o[e] = 2.0f * z;
    }
  }
}

// gamma[b,s] = 2/max(1-|encb row|^2, EPS)
__global__ void k_gamma(const float* __restrict__ encb, float* __restrict__ gam) {
  __shared__ float red4[4];
  long row = blockIdx.x;
  int t = threadIdx.x;
  float s2 = 0.f;
  #pragma unroll
  for (int j = 0; j < 3; j++) { float v = encb[row * EE + t + j * 256]; s2 += v * v; }
  s2 = block_sum(s2, red4);
  if (t == 0) gam[row] = 2.0f / fmaxf(1.0f - s2, EPSV);
}

// ---------- FUSED: x -> bf16 hi/lo planes + row |x|^2 (x read once) ----------
__global__ void k_xprep(const float* __restrict__ x, short* __restrict__ oh,
                        short* __restrict__ ol, float* __restrict__ x2) {
  __shared__ float red4[4];
  long row = blockIdx.x;
  int t = threadIdx.x;
  float2 v = ((const float2*)(x + row * CCH))[t];
  float s = v.x * v.x + v.y * v.y;
  s = block_sum(s, red4);
  short h0, l0, h1, l1;
  bsplit(v.x, h0, l0); bsplit(v.y, h1, l1);
  int ph = (int)(unsigned short)h0 | ((int)(unsigned short)h1 << 16);
  int pl = (int)(unsigned short)l0 | ((int)(unsigned short)l1 << 16);
  ((int*)(oh + row * CCH))[t] = ph;
  ((int*)(ol + row * CCH))[t] = pl;
  if (t == 0) x2[row] = s;
}

// ---------- attn f32 reconstruction from hi/lo planes ----------
__global__ void k_rec(const short* __restrict__ ah, const short* __restrict__ al,
                      float* __restrict__ outp, long n4) {
  long i = (long)blockIdx.x * 256 + threadIdx.x;
  if (i >= n4) return;
  short4_t h4 = ((const short4_t*)ah)[i];
  short4_t l4 = ((const short4_t*)al)[i];
  floatx4 r;
  #pragma unroll
  for (int c = 0; c < 4; c++) r[c] = bf2f(h4[c]) + bf2f(l4[c]);
  ((floatx4*)outp)[i] = r;
}

// ---------- transpose + bf16 hi/lo split; optional per-input-row scale;
// optional column sum-of-squares accumulation (y2out != nullptr, raw values) ----------
__global__ void k_tsp(const float* __restrict__ in, short* __restrict__ oh,
                      short* __restrict__ ol, const float* __restrict__ rs,
                      int R, int C, long sin, long sout, float* __restrict__ y2out) {
  __shared__ float tile[32][33];
  __shared__ float ys[8][32];
  int z = blockIdx.z;
  const float* ib = in + (long)z * sin;
  short* ohb = oh + (long)z * sout;
  short* olb = ol + (long)z * sout;
  int c0 = blockIdx.x * 32, r0 = blockIdx.y * 32;
  int tx = threadIdx.x, ty = threadIdx.y;
  float psum = 0.f;
  #pragma unroll
  for (int i = 0; i < 4; i++) {
    int rr = ty + i * 8;
    float v = ib[(long)(r0 + rr) * C + c0 + tx];
    if (y2out) psum += v * v;
    if (rs) v *= rs[(long)z * R + r0 + rr];
    tile[rr][tx] = v;
  }
  if (y2out) ys[ty][tx] = psum;
  __syncthreads();
  #pragma unroll
  for (int i = 0; i < 4; i++) {
    int cc = ty + i * 8;
    float v = tile[tx][cc];
    short h, l; bsplit(v, h, l);
    long o = (long)(c0 + cc) * R + r0 + tx;
    ohb[o] = h; olb[o] = l;
  }
  if (y2out && ty == 0) {
    float tot = ys[0][tx] + ys[1][tx] + ys[2][tx] + ys[3][tx]
              + ys[4][tx] + ys[5][tx] + ys[6][tx] + ys[7][tx];
    atomicAdd(&y2out[(long)z * SS + c0 + tx], tot);
  }
}

// ---------- split-bf16 MFMA GEMM, double-buffered, LDS chunk-swizzled,
// counted-vmcnt pipeline (unchanged from R7). ----------
template <int EPI>
__global__ __launch_bounds__(256)
void mgemm(const short* __restrict__ Agh, const short* __restrict__ Agl,
           const short* __restrict__ BTh, const short* __restrict__ BTl,
           float* __restrict__ Cm, short* __restrict__ Ch, short* __restrict__ Cl,
           int M, int N, int K, long sA, long sBT, long sC,
           const float* __restrict__ q2, const float* __restrict__ y2a,
           const float* __restrict__ fmask, const float* __restrict__ scalep) {
  __shared__ alignas(16) short Ah[2][BM * BK];
  __shared__ alignas(16) short Al[2][BM * BK];
  __shared__ alignas(16) short Bh[2][BN * BK];
  __shared__ alignas(16) short Bl[2][BN * BK];

  int gx = gridDim.x, gy = gridDim.y;
  int nwg = gx * gy * gridDim.z;
  int lin = blockIdx.x + gx * (blockIdx.y + gy * blockIdx.z);
  int swz = (lin & 7) * (nwg >> 3) + (lin >> 3);
  int bx = swz % gx; int tmp = swz / gx; int by = tmp % gy; int bz = tmp / gy;

  int z = bz;
  const short* Ahb = Agh + (long)z * sA;
  const short* Alb = Agl + (long)z * sA;
  const short* Bhb = BTh + (long)z * sBT;
  const short* Blb = BTl + (long)z * sBT;
  int m0 = by * BM, n0 = bx * BN;
  int t = threadIdx.x;
  int w = t >> 6, l = t & 63;
  int wr = w >> 1, wc = w & 1;
  int quad = l >> 4, lm = l & 15;

  int srow = (w << 5) + (l >> 2);
  int scol = (((l & 3) ^ ((l >> 3) & 3)) << 3);   // swizzled global source chunk
  int wbase = (w << 10);
  int qs = ((quad ^ ((lm >> 1) & 3)) << 3);       // swizzled LDS read slot (shorts)

  auto STAGE = [&](int buf, int kk) {
    const short* gAh = Ahb + (long)(m0 + srow) * K + kk + scol;
    const short* gAl = Alb + (long)(m0 + srow) * K + kk + scol;
    const short* gBh = Bhb + (long)(n0 + srow) * K + kk + scol;
    const short* gBl = Blb + (long)(n0 + srow) * K + kk + scol;
    #pragma unroll
    for (int u = 0; u < 2; u++) {
      long go = (long)(u * 16) * K;
      gl16(gAh + go, &Ah[buf][wbase + (u << 9)]);
      gl16(gAl + go, &Al[buf][wbase + (u << 9)]);
      gl16(gBh + go, &Bh[buf][wbase + (u << 9)]);
      gl16(gBl + go, &Bl[buf][wbase + (u << 9)]);
    }
  };

  floatx4 acc[4][4];
  #pragma unroll
  for (int i = 0; i < 4; i++)
    #pragma unroll
    for (int j = 0; j < 4; j++) acc[i][j] = (floatx4){0.f, 0.f, 0.f, 0.f};

  STAGE(0, 0);           // 8 loads in flight for buf0
  int cur = 0;

  for (int k0 = 0; k0 < K; k0 += BK) {
    int nxt = k0 + BK;
    if (nxt < K) {
      STAGE(cur ^ 1, nxt);                               // +8 loads (stay in flight)
      asm volatile("s_waitcnt vmcnt(8)" ::: "memory");   // buf[cur]'s 8 landed
    } else {
      asm volatile("s_waitcnt vmcnt(0)" ::: "memory");   // final tile: drain
    }
    __builtin_amdgcn_s_barrier();          // all waves: buf[cur] resident
    __builtin_amdgcn_sched_barrier(0);     // don't hoist ds_reads above barrier

    short8_t bfh[4], bfl[4];
    #pragma unroll
    for (int nj = 0; nj < 4; nj++) {
      int n = wc * 64 + nj * 16 + lm;
      bfh[nj] = *(const short8_t*)&Bh[cur][n * BK + qs];
      bfl[nj] = *(const short8_t*)&Bl[cur][n * BK + qs];
    }
    #pragma unroll
    for (int mi = 0; mi < 4; mi++) {
      int m = wr * 64 + mi * 16 + lm;
      short8_t afh = *(const short8_t*)&Ah[cur][m * BK + qs];
      short8_t afl = *(const short8_t*)&Al[cur][m * BK + qs];
      #pragma unroll
      for (int nj = 0; nj < 4; nj++) {
        acc[mi][nj] = __builtin_amdgcn_mfma_f32_16x16x32_bf16(afh, bfh[nj], acc[mi][nj], 0, 0, 0);
        acc[mi][nj] = __builtin_amdgcn_mfma_f32_16x16x32_bf16(afh, bfl[nj], acc[mi][nj], 0, 0, 0);
        acc[mi][nj] = __builtin_amdgcn_mfma_f32_16x16x32_bf16(afl, bfh[nj], acc[mi][nj], 0, 0, 0);
      }
    }
    __builtin_amdgcn_sched_barrier(0);     // don't sink ds_reads below barrier
    __builtin_amdgcn_s_barrier();          // all done reading buf[cur]; next iter restages it
    cur ^= 1;
  }

  float* Cb = Cm + (long)z * sC;
  short* Chb = Ch + (long)z * sC;
  short* Clb = Cl + (long)z * sC;

  if constexpr (EPI == 1) {
    // fused Poincare distance + mask: -2*atanh(m)/exp(scale)
    //   = nls * log2((1+m)*rcp(1-m)),  nls = -ln2/exp(scale)
    float nls = -0.69314718055994531f * frcp(expf(scalep[0]));
    float yv4[4]; float mk4[4]; int gn4[4];
    #pragma unroll
    for (int nj = 0; nj < 4; nj++) {
      int gn = n0 + wc * 64 + nj * 16 + lm;
      gn4[nj] = gn;
      yv4[nj] = y2a[(long)z * N + gn];
      mk4[nj] = fmask[(long)z * N + gn];
    }
    #pragma unroll
    for (int mi = 0; mi < 4; mi++) {
      #pragma unroll
      for (int r = 0; r < 4; r++) {
        int gm = m0 + wr * 64 + mi * 16 + quad * 4 + r;
        float xv = q2[(long)z * M + gm];
        #pragma unroll
        for (int nj = 0; nj < 4; nj++) {
          float c = acc[mi][nj][r];
          float yv = yv4[nj];
          float num = fmaxf(xv - 2.0f * c + yv, 0.0f);
          float den = fmaxf(fmaf(xv, yv, 1.0f - 2.0f * c), EPSV);
          float mm = sqrtf(num * frcp(den));
          float m = fminf(mm, CLIPV);
          float sc = nls * flog2((1.0f + m) * frcp(1.0f - m));
          if (mk4[nj] > 0.5f) sc = -INFINITY;
          Cb[(long)gm * N + gn4[nj]] = sc;
        }
      }
    }
  } else {
    #pragma unroll
    for (int mi = 0; mi < 4; mi++) {
      #pragma unroll
      for (int r = 0; r < 4; r++) {
        int gm = m0 + wr * 64 + mi * 16 + quad * 4 + r;
        #pragma unroll
        for (int nj = 0; nj < 4; nj++) {
          int gn = n0 + wc * 64 + nj * 16 + lm;
          float c = acc[mi][nj][r];
          if constexpr (EPI == 0) {
            Cb[(long)gm * N + gn] = c;
          } else {
            short hh, ll; bsplit(c, hh, ll);
            Chb[(long)gm * N + gn] = hh;
            Clb[(long)gm * N + gn] = ll;
          }
        }
      }
    }
  }
}

// ---------- q = msm(sqrt(.5), mobius_add(tgt, poincare_linear(x,w_in,b_in))) ----------
__global__ void k_q(short* gh, short* gl, const float* __restrict__ tgt,
                    const float* __restrict__ ch2, const float* __restrict__ sh2,
                    const float* __restrict__ rzn, const float* __restrict__ zn2,
                    const float* __restrict__ x2, float* __restrict__ q2) {
  __shared__ float red4[4];
  long row = blockIdx.x;
  int t = threadIdx.x;
  float cx2 = x2[row];
  float rdpl = 1.0f / fmaxf(1.0f - cx2, EPSV);
  float opc = 1.0f + cx2;

  float wv[3]; float sw2 = 0.f;
  #pragma unroll
  for (int j = 0; j < 3; j++) {
    int e = t + j * 256;
    float u = (bf2f(gh[row * EE + e]) + bf2f(gl[row * EE + e])) * rzn[e];
    float nm = fmaf(2.0f * u, ch2[e], -opc * sh2[e]);
    wv[j] = sinh_g_asinh(zn2[e], nm * rdpl);
    sw2 += wv[j] * wv[j];
  }
  sw2 = block_sum(sw2, red4);
  float rpden = 1.0f / (1.0f + sqrtf(1.0f + sw2));

  float pv[3], tv[3];
  float tp = 0.f, p2 = 0.f, t2 = 0.f;
  #pragma unroll
  for (int j = 0; j < 3; j++) {
    int e = t + j * 256;
    pv[j] = wv[j] * rpden;
    tv[j] = tgt[row * EE + e];
    tp += tv[j] * pv[j]; p2 += pv[j] * pv[j]; t2 += tv[j] * tv[j];
  }
  tp = block_sum(tp, red4);
  p2 = block_sum(p2, red4);
  t2 = block_sum(t2, red4);

  float rmden = 1.0f / fmaxf(1.0f + 2.0f * tp + t2 * p2, EPSV);
  float cT = 1.0f + 2.0f * tp + p2;
  float cP = 1.0f - t2;
  float av[3]; float n2 = 0.f;
  #pragma unroll
  for (int j = 0; j < 3; j++) { av[j] = (cT * tv[j] + cP * pv[j]) * rmden; n2 += av[j] * av[j]; }
  n2 = block_sum(n2, red4);

  float n = sqrtf(fmaxf(n2, EPSV));
  float f = tanh_r_atanh_over_n(0.70710678118654752f, n);
  #pragma unroll
  for (int j = 0; j < 3; j++) {
    int e = t + j * 256;
    short h, lo; bsplit(f * av[j], h, lo);
    gh[row * EE + e] = h; gl[row * EE + e] = lo;
  }
  if (t == 0) q2[row] = f * f * n2;
}

// ---------- softmax: reads f32 scores, writes attn hi/lo planes + den ----------
__global__ void k_softmax(const float* __restrict__ S, const float* __restrict__ gam,
                          float* __restrict__ denr,
                          short* __restrict__ ah, short* __restrict__ al) {
  __shared__ float red4[4];
  long row = blockIdx.x;
  int b = (int)(row / TT);
  int t = threadIdx.x;
  const float* rowp = S + row * SS;

  float v[4];
  float mx = -INFINITY;
  #pragma unroll
  for (int j = 0; j < 4; j++) { v[j] = rowp[t + j * 256]; mx = fmaxf(mx, v[j]); }
  mx = block_max(mx, red4);
  bool dead = !(mx > -INFINITY) || (mx != mx);
  float sum = 0.f;
  #pragma unroll
  for (int j = 0; j < 4; j++) {
    v[j] = dead ? 0.f : fexp2((v[j] - mx) * LOG2E);
    sum += v[j];
  }
  sum = block_sum(sum, red4);
  float inv = (sum > 0.f) ? 1.0f / sum : 0.f;
  float ds = 0.f;
  #pragma unroll
  for (int j = 0; j < 4; j++) {
    int s = t + j * 256;
    float a = v[j] * inv;
    short h, lo; bsplit(a, h, lo);
    ah[row * SS + s] = h; al[row * SS + s] = lo;
    ds += a * (gam[(long)b * SS + s] - 1.0f);
  }
  ds = block_sum(ds, red4);
  if (t == 0) denr[row] = (inv == 0.f) ? 1.0f : ds;
}

// ---------- out2 = msm(sqrt(s_b), msm(0.5, nom/den)) — IN-PLACE on planes ----------
__global__ void k_mid(short* gh, short* gl, const float* __restrict__ denr,
                      const float* __restrict__ ssb, float* __restrict__ o2) {
  __shared__ float red4[4];
  long row = blockIdx.x;
  int b = (int)(row / TT);
  int t = threadIdx.x;
  float d = denr[row];
  if (fabsf(d) < 1e-10f) d = 1e-10f;
  float rd = 1.0f / d;

  float v[3]; float n2 = 0.f;
  #pragma unroll
  for (int j = 0; j < 3; j++) {
    int e = t + j * 256;
    v[j] = (bf2f(gh[row * EE + e]) + bf2f(gl[row * EE + e])) * rd;
    n2 += v[j] * v[j];
  }
  n2 = block_sum(n2, red4);
  float n = sqrtf(fmaxf(n2, EPSV));
  float m = fminf(n, CLIPV);
  float f1 = m / ((1.0f + sqrtf(fmaxf(1.0f - m * m, 0.0f))) * n);

  float m2 = 0.f;
  #pragma unroll
  for (int j = 0; j < 3; j++) { v[j] *= f1; m2 += v[j] * v[j]; }
  m2 = block_sum(m2, red4);
  float n1 = sqrtf(fmaxf(m2, EPSV));
  float f2 = tanh_r_atanh_over_n(ssb[b], n1);

  float s2 = 0.f;
  #pragma unroll
  for (int j = 0; j < 3; j++) {
    int e = t + j * 256;
    v[j] *= f2; s2 += v[j] * v[j];
    short h, lo; bsplit(v[j], h, lo);
    gh[row * EE + e] = h; gl[row * EE + e] = lo;
  }
  s2 = block_sum(s2, red4);
  if (t == 0) o2[row] = s2;
}

// ---------- final epilogue ----------
__global__ void k_final(const float* __restrict__ G, const float* __restrict__ xin,
                        const float* __restrict__ ch2, const float* __restrict__ sh2,
                        const float* __restrict__ rzn, const float* __restrict__ zn2,
                        const float* __restrict__ x2, const float* __restrict__ o2,
                        float* __restrict__ outp) {
  __shared__ float red4[4];
  long row = blockIdx.x;
  int t = threadIdx.x;
  float cx2 = o2[row];
  float rdpl = 1.0f / fmaxf(1.0f - cx2, EPSV);
  float opc = 1.0f + cx2;

  float wv[2]; float sw2 = 0.f;
  #pragma unroll
  for (int j = 0; j < 2; j++) {
    int c = t + j * 256;
    float u = G[row * CCH + c] * rzn[c];
    float nm = fmaf(2.0f * u, ch2[c], -opc * sh2[c]);
    wv[j] = sinh_g_asinh(zn2[c], nm * rdpl);
    sw2 += wv[j] * wv[j];
  }
  sw2 = block_sum(sw2, red4);
  float rpden = 1.0f / (1.0f + sqrtf(1.0f + sw2));

  float pv[2], xv[2];
  float xp = 0.f, p2 = 0.f;
  #pragma unroll
  for (int j = 0; j < 2; j++) {
    int c = t + j * 256;
    pv[j] = wv[j] * rpden;
    xv[j] = xin[row * CCH + c];
    xp += xv[j] * pv[j]; p2 += pv[j] * pv[j];
  }
  xp = block_sum(xp, red4);
  p2 = block_sum(p2, red4);

  float xx = x2[row];
  float rmden = 1.0f / fmaxf(1.0f + 2.0f * xp + xx * p2, EPSV);
  float cX = 1.0f + 2.0f * xp + p2;
  float cP = 1.0f - xx;
  float av[2]; float n2 = 0.f;
  #pragma unroll
  for (int j = 0; j < 2; j++) { av[j] = (cX * xv[j] + cP * pv[j]) * rmden; n2 += av[j] * av[j]; }
  n2 = block_sum(n2, red4);

  float n = sqrtf(fmaxf(n2, EPSV));
  float f = tanh_r_atanh_over_n(0.70710678118654752f, n);
  #pragma unroll
  for (int j = 0; j < 2; j++) { int c = t + j * 256; outp[row * CCH + c] = f * av[j]; }
}

extern "C" void kernel_launch(void* const* d_in, const int* in_sizes, int n_in,
                              void* d_out, int out_size, void* d_ws, size_t ws_size,
                              hipStream_t stream) {
  const float* x    = (const float*)d_in[0];
  const float* tgt  = (const float*)d_in[1];
  const float* enca = (const float*)d_in[2];
  const float* encb = (const float*)d_in[3];
  const void*  mraw = d_in[4];
  const float* win  = (const float*)d_in[5];
  const float* bin  = (const float*)d_in[6];
  const float* wout = (const float*)d_in[7];
  const float* bout = (const float*)d_in[8];
  const float* scalep = (const float*)d_in[9];

  float* out_main = (float*)d_out;                       // [B,T,CCH] f32 (33.55 MB)
  float* out_attn = out_main + (long)BB * TT * CCH;      // [B,T,S]  f32 (67.11 MB)

  // ---- d_out scratch aliases ----
  short* xh  = (short*)out_attn;
  short* xl  = xh + (long)BB * TT * CCH;
  short* G4h = (short*)out_attn;
  short* G4l = G4h + (long)BB * TT * EE;
  short* ATh = (short*)out_main;

  // ---- workspace (same proven budget) ----
  char* wb = (char*)d_ws;
  short* P0   = (short*)wb;  wb += (long)BB * TT * EE * 2;
  short* P1   = (short*)wb;  wb += (long)BB * TT * EE * 2;
  short* G1h = P0, *G1l = P1;
  short* ATl = P0;
  short* tspH = (short*)wb;  wb += (long)BB * SS * EE * 2;
  short* tspL = (short*)wb;  wb += (long)BB * SS * EE * 2;
  float* Gw   = (float*)tspH;
  short* winTh  = (short*)wb;  wb += (long)CCH * EE * 2;
  short* winTl  = (short*)wb;  wb += (long)CCH * EE * 2;
  short* woutTh = (short*)wb;  wb += (long)EE * CCH * 2;
  short* woutTl = (short*)wb;  wb += (long)EE * CCH * 2;
  float* sm     = (float*)wb;
  float* x2a  = sm; sm += BB * TT;
  float* q2a  = sm; sm += BB * TT;
  float* y2a  = sm; sm += BB * SS;
  float* gam  = sm; sm += BB * SS;
  float* denr = sm; sm += BB * TT;
  float* o2a  = sm; sm += BB * TT;
  float* ssb  = sm; sm += BB;
  float* fmask= sm; sm += BB * SS;
  float* ch2i = sm; sm += EE;
  float* sh2i = sm; sm += EE;
  float* rzni = sm; sm += EE;
  float* zn2i = sm; sm += EE;
  float* ch2o = sm; sm += CCH;
  float* sh2o = sm; sm += CCH;
  float* rzno = sm; sm += CCH;
  float* zn2o = sm; sm += CCH;
  int*   mflag= (int*)sm; sm += 1;

  // mask canonicalization (det -> fused conv+count)
  k_maskdet<<<1, 256, 0, stream>>>((const unsigned char*)mraw, mflag);
  k_maskrow<<<BB, 256, 0, stream>>>(mraw, mflag, fmask, ssb);

  // fused weight prep (both col-norms + trig invariants + y2a zero-init)
  k_wprep<<<EE + CCH, 256, 0, stream>>>(win, wout, bin, bout,
                                        ch2i, sh2i, rzni, zn2i,
                                        ch2o, sh2o, rzno, zn2o, y2a);
  k_gamma<<<BB * SS, 256, 0, stream>>>(encb, gam);

  // weight transposes + split
  k_tsp<<<dim3(EE / 32, CCH / 32, 1), dim3(32, 8), 0, stream>>>(
      win, winTh, winTl, nullptr, CCH, EE, 0, 0, nullptr);
  k_tsp<<<dim3(CCH / 32, EE / 32, 1), dim3(32, 8), 0, stream>>>(
      wout, woutTh, woutTl, nullptr, EE, CCH, 0, 0, nullptr);

  // enc_a [E,S] -> eaT [S,E] hi/lo, with fused y2a column-sum (atomic)
  k_tsp<<<dim3(SS / 32, EE / 32, BB), dim3(32, 8), 0, stream>>>(
      enca, tspH, tspL, nullptr, EE, SS, (long)EE * SS, (long)SS * EE, y2a);

  // fused x prep: planes (GEMM1 A, in out_attn region) + x2a, x read once
  k_xprep<<<BB * TT, 256, 0, stream>>>(x, xh, xl, x2a);

  // GEMM1: x @ w_in -> G1 planes (P0/P1)
  mgemm<2><<<dim3(EE / BN, BB * TT / BM, 1), 256, 0, stream>>>(
      xh, xl, winTh, winTl, nullptr, G1h, G1l, BB * TT, EE, CCH, 0, 0, 0,
      nullptr, nullptr, nullptr, nullptr);

  // k_q: in-place G1 planes -> q planes (+ q2)
  k_q<<<BB * TT, 256, 0, stream>>>(G1h, G1l, tgt, ch2i, sh2i, rzni, zn2i, x2a, q2a);

  // GEMM2 (batched) + dist epilogue: scores -> out_attn f32
  mgemm<1><<<dim3(SS / BN, TT / BM, BB), 256, 0, stream>>>(
      G1h, G1l, tspH, tspL, out_attn, nullptr, nullptr, TT, SS, EE,
      (long)TT * EE, (long)SS * EE, (long)TT * SS, q2a, y2a, fmask, scalep);

  // enc_b [S,E] scaled by gamma -> ebT [E,S] hi/lo (overwrites eaT)
  k_tsp<<<dim3(EE / 32, SS / 32, BB), dim3(32, 8), 0, stream>>>(
      encb, tspH, tspL, gam, SS, EE, (long)SS * EE, (long)EE * SS, nullptr);

  // softmax: scores f32 -> attn planes (ATh in out_main, ATl in pool) + denr
  k_softmax<<<BB * TT, 256, 0, stream>>>(out_attn, gam, denr, ATh, ATl);

  // GEMM4 (batched): attn @ (gamma*enc_b) -> G4 planes (out_attn region)
  mgemm<2><<<dim3(EE / BN, TT / BM, BB), 256, 0, stream>>>(
      ATh, ATl, tspH, tspL, nullptr, G4h, G4l, TT, EE, SS,
      (long)TT * SS, (long)EE * SS, (long)TT * EE, nullptr, nullptr, nullptr, nullptr);

  // k_mid: in-place G4 planes -> M planes (+ o2)
  k_mid<<<BB * TT, 256, 0, stream>>>(G4h, G4l, denr, ssb, o2a);

  // GEMM5: M @ w_out -> Gw f32 (T region; ebT dead)
  mgemm<0><<<dim3(CCH / BN, BB * TT / BM, 1), 256, 0, stream>>>(
      G4h, G4l, woutTh, woutTl, Gw, nullptr, nullptr, BB * TT, CCH, EE, 0, 0, 0,
      nullptr, nullptr, nullptr, nullptr);

  // reconstruct attn f32 output from planes
  k_rec<<<(int)((long)BB * TT * SS / 4 / 256), 256, 0, stream>>>(
      ATh, ATl, out_attn, (long)BB * TT * SS / 4);

  // final epilogue (overwrites out_main)
  k_final<<<BB * TT, 256, 0, stream>>>(Gw, x, ch2o, sh2o, rzno, zn2o, x2a, o2a, out_main);
}

// Round 10
// 723.032 us; speedup vs baseline: 2.3149x; 1.0158x over previous
//
#include <hip/hip_runtime.h>
#include <hip/hip_bf16.h>
#include <math.h>

#define BB 16
#define TT 1024
#define SS 1024
#define CCH 512
#define EE 768
#define EPSV 1e-15f
#define CLIPV (1.0f - 1e-5f)
#define LOG2E 1.4426950408889634f

#define BM 128
#define BN 128
#define BK 32

typedef __attribute__((ext_vector_type(8))) short short8_t;
typedef __attribute__((ext_vector_type(4))) short short4_t;
typedef __attribute__((ext_vector_type(4))) float floatx4;

union BFU { __hip_bfloat16 b; short s; };

static __device__ __forceinline__ void bsplit(float x, short& h, short& l) {
  BFU u1; u1.b = __float2bfloat16(x);
  float hf = __bfloat162float(u1.b);
  BFU u2; u2.b = __float2bfloat16(x - hf);
  h = u1.s; l = u2.s;
}

static __device__ __forceinline__ float bf2f(short s) {
  BFU u; u.s = s; return __bfloat162float(u.b);
}

static __device__ __forceinline__ float fexp2(float x) { return __builtin_amdgcn_exp2f(x); }
static __device__ __forceinline__ float flog2(float x) { return __builtin_amdgcn_logf(x); }
static __device__ __forceinline__ float frcp(float x)  { return __builtin_amdgcn_rcpf(x); }

// sinh(g * asinh(t)) = 0.5*(p^g - p^-g), p = |t| + sqrt(t^2+1), sign-restored
static __device__ __forceinline__ float sinh_g_asinh(float g, float t) {
  float s = fabsf(t);
  float p = s + sqrtf(fmaf(s, s, 1.0f));
  float P = fexp2(g * flog2(p));
  float w = 0.5f * (P - frcp(P));
  return copysignf(w, t);
}

// tanh(r * atanh(min(n,CLIP))) / n  via Q^r, Q=(1+m)/(1-m); exp clamped vs overflow
static __device__ __forceinline__ float tanh_r_atanh_over_n(float r, float n) {
  float m = fminf(n, CLIPV);
  float Q = (1.0f + m) * frcp(1.0f - m);
  float E = fminf(r * flog2(Q), 126.0f);
  float P = fexp2(E);
  float f = (P - 1.0f) * frcp((P + 1.0f) * n);
  return (n < 1e-4f) ? r : f;
}

// async global->LDS, 16 B per lane; LDS dest = wave-uniform base + lane*16
static __device__ __forceinline__ void gl16(const short* g, short* lds_base) {
  __builtin_amdgcn_global_load_lds(
      (const __attribute__((address_space(1))) unsigned int*)g,
      (__attribute__((address_space(3))) unsigned int*)lds_base, 16, 0, 0);
}

static __device__ __forceinline__ float wave_sum(float v) {
  #pragma unroll
  for (int m = 32; m; m >>= 1) v += __shfl_xor(v, m, 64);
  return v;
}

__device__ __forceinline__ float block_sum(float v, float* red4) {
  v = wave_sum(v);
  int w = threadIdx.x >> 6;
  if ((threadIdx.x & 63) == 0) red4[w] = v;
  __syncthreads();
  float r = red4[0] + red4[1] + red4[2] + red4[3];
  __syncthreads();
  return r;
}

// ---------- mask dtype detection ----------
__global__ void k_maskdet(const unsigned char* __restrict__ mb, int* __restrict__ flag) {
  __shared__ int any;
  if (threadIdx.x == 0) any = 0;
  __syncthreads();
  int local = 0;
  for (int i = threadIdx.x; i < BB * SS; i += 256)
    if ((i & 3) && mb[i]) local = 1;
  if (local) atomicOr(&any, 1);
  __syncthreads();
  if (threadIdx.x == 0) *flag = any;
}

// ---------- FUSED: mask conversion + per-batch len / sqrt(len) / Keff ----------
// mask is a suffix mask (arange >= len); len = S - count(masked).
__global__ void k_maskrow(const void* __restrict__ mraw, const int* __restrict__ flag,
                          float* __restrict__ fmask, float* __restrict__ ssb,
                          int* __restrict__ lensi, int* __restrict__ kbi) {
  __shared__ float red4[4];
  int b = blockIdx.x, t = threadIdx.x;
  int f = *flag;
  float cnt = 0.f;
  #pragma unroll
  for (int j = 0; j < 4; j++) {
    long i = (long)b * SS + t + j * 256;
    int v = f ? (int)((const unsigned char*)mraw)[i] : ((const int*)mraw)[i];
    float fv = v ? 1.0f : 0.0f;
    fmask[i] = fv; cnt += fv;
  }
  cnt = block_sum(cnt, red4);
  if (t == 0) {
    int len = SS - (int)cnt;
    ssb[b] = sqrtf((float)len);
    lensi[b] = len;
    kbi[b] = (len + 31) & ~31;   // K columns needed to cover all live entries
  }
}

// ---------- FUSED: both weight col-norms + per-column trig invariants + y2a zero ----------
__global__ void k_wprep(const float* __restrict__ win, const float* __restrict__ wout,
                        const float* __restrict__ bin, const float* __restrict__ bout,
                        float* __restrict__ ch2i, float* __restrict__ sh2i,
                        float* __restrict__ rzni, float* __restrict__ zn2i,
                        float* __restrict__ ch2o, float* __restrict__ sh2o,
                        float* __restrict__ rzno, float* __restrict__ zn2o,
                        float* __restrict__ y2a) {
  __shared__ float red4[4];
  int bid = blockIdx.x, t = threadIdx.x;
  if (bid < (BB * SS) / 256) y2a[bid * 256 + t] = 0.f;   // zero before enc_a tsp atomics
  float s = 0.f;
  if (bid < EE) {
    int e = bid;
    for (int k = t; k < CCH; k += 256) { float v = win[(long)k * EE + e]; s += v * v; }
    s = block_sum(s, red4);
    if (t == 0) {
      float z = sqrtf(fmaxf(s, EPSV));
      float r2 = 2.0f * bin[e];
      ch2i[e] = coshf(r2); sh2i[e] = sinhf(r2);
      rzni[e] = 1.0f / z;  zn2i[e] = 2.0f * z;
    }
  } else {
    int e = bid - EE;
    for (int k = t; k < EE; k += 256) { float v = wout[(long)k * CCH + e]; s += v * v; }
    s = block_sum(s, red4);
    if (t == 0) {
      float z = sqrtf(fmaxf(s, EPSV));
      float r2 = 2.0f * bout[e];
      ch2o[e] = coshf(r2); sh2o[e] = sinhf(r2);
      rzno[e] = 1.0f / z;  zn2o[e] = 2.0f * z;
    }
  }
}

// gamma[b,s] = 2/max(1-|encb row|^2, EPS)
__global__ void k_gamma(const float* __restrict__ encb, float* __restrict__ gam) {
  __shared__ float red4[4];
  long row = blockIdx.x;
  int t = threadIdx.x;
  float s2 = 0.f;
  #pragma unroll
  for (int j = 0; j < 3; j++) { float v = encb[row * EE + t + j * 256]; s2 += v * v; }
  s2 = block_sum(s2, red4);
  if (t == 0) gam[row] = 2.0f / fmaxf(1.0f - s2, EPSV);
}

// ---------- FUSED: x -> bf16 hi/lo planes + row |x|^2 (x read once) ----------
__global__ void k_xprep(const float* __restrict__ x, short* __restrict__ oh,
                        short* __restrict__ ol, float* __restrict__ x2) {
  __shared__ float red4[4];
  long row = blockIdx.x;
  int t = threadIdx.x;
  float2 v = ((const float2*)(x + row * CCH))[t];
  float s = v.x * v.x + v.y * v.y;
  s = block_sum(s, red4);
  short h0, l0, h1, l1;
  bsplit(v.x, h0, l0); bsplit(v.y, h1, l1);
  int ph = (int)(unsigned short)h0 | ((int)(unsigned short)h1 << 16);
  int pl = (int)(unsigned short)l0 | ((int)(unsigned short)l1 << 16);
  ((int*)(oh + row * CCH))[t] = ph;
  ((int*)(ol + row * CCH))[t] = pl;
  if (t == 0) x2[row] = s;
}

// ---------- attn f32 reconstruction from hi/lo planes ----------
__global__ void k_rec(const short* __restrict__ ah, const short* __restrict__ al,
                      float* __restrict__ outp, long n4) {
  long i = (long)blockIdx.x * 256 + threadIdx.x;
  if (i >= n4) return;
  short4_t h4 = ((const short4_t*)ah)[i];
  short4_t l4 = ((const short4_t*)al)[i];
  floatx4 r;
  #pragma unroll
  for (int c = 0; c < 4; c++) r[c] = bf2f(h4[c]) + bf2f(l4[c]);
  ((floatx4*)outp)[i] = r;
}

// ---------- transpose + bf16 hi/lo split; optional per-input-row scale;
// optional column sum-of-squares accumulation (y2out != nullptr, raw values) ----------
__global__ void k_tsp(const float* __restrict__ in, short* __restrict__ oh,
                      short* __restrict__ ol, const float* __restrict__ rs,
                      int R, int C, long sin, long sout, float* __restrict__ y2out) {
  __shared__ float tile[32][33];
  __shared__ float ys[8][32];
  int z = blockIdx.z;
  const float* ib = in + (long)z * sin;
  short* ohb = oh + (long)z * sout;
  short* olb = ol + (long)z * sout;
  int c0 = blockIdx.x * 32, r0 = blockIdx.y * 32;
  int tx = threadIdx.x, ty = threadIdx.y;
  float psum = 0.f;
  #pragma unroll
  for (int i = 0; i < 4; i++) {
    int rr = ty + i * 8;
    float v = ib[(long)(r0 + rr) * C + c0 + tx];
    if (y2out) psum += v * v;
    if (rs) v *= rs[(long)z * R + r0 + rr];
    tile[rr][tx] = v;
  }
  if (y2out) ys[ty][tx] = psum;
  __syncthreads();
  #pragma unroll
  for (int i = 0; i < 4; i++) {
    int cc = ty + i * 8;
    float v = tile[tx][cc];
    short h, l; bsplit(v, h, l);
    long o = (long)(c0 + cc) * R + r0 + tx;
    ohb[o] = h; olb[o] = l;
  }
  if (y2out && ty == 0) {
    float tot = ys[0][tx] + ys[1][tx] + ys[2][tx] + ys[3][tx]
              + ys[4][tx] + ys[5][tx] + ys[6][tx] + ys[7][tx];
    atomicAdd(&y2out[(long)z * SS + c0 + tx], tot);
  }
}

// ---------- split-bf16 MFMA GEMM, double-buffered, LDS chunk-swizzled,
// counted-vmcnt pipeline. Mask structure exploited WITHOUT new control flow:
//  - EPI=1, fully-masked N-block (suffix mask): Klen=0 -> K-loop skipped, acc=0;
//    the normal epilogue's fmask check writes -INF for every column anyway.
//  - kb (per-batch K bound, GEMM4): attn columns beyond len are exactly 0,
//    so trimming the K-loop is bit-exact.
// Prologue STAGE guarded by Klen>0; barrier structure identical to the proven R8. ----------
template <int EPI>
__global__ __launch_bounds__(256)
void mgemm(const short* __restrict__ Agh, const short* __restrict__ Agl,
           const short* __restrict__ BTh, const short* __restrict__ BTl,
           float* __restrict__ Cm, short* __restrict__ Ch, short* __restrict__ Cl,
           int M, int N, int K, long sA, long sBT, long sC,
           const float* __restrict__ q2, const float* __restrict__ y2a,
           const float* __restrict__ fmask, const float* __restrict__ scalep,
           const int* __restrict__ lensi, const int* __restrict__ kb) {
  __shared__ alignas(16) short Ah[2][BM * BK];
  __shared__ alignas(16) short Al[2][BM * BK];
  __shared__ alignas(16) short Bh[2][BN * BK];
  __shared__ alignas(16) short Bl[2][BN * BK];

  int gx = gridDim.x, gy = gridDim.y;
  int nwg = gx * gy * gridDim.z;
  int lin = blockIdx.x + gx * (blockIdx.y + gy * blockIdx.z);
  int swz = (lin & 7) * (nwg >> 3) + (lin >> 3);
  int bx = swz % gx; int tmp = swz / gx; int by = tmp % gy; int bz = tmp / gy;

  int z = bz;
  int m0 = by * BM, n0 = bx * BN;
  int t = threadIdx.x;
  int w = t >> 6, l = t & 63;
  int wr = w >> 1, wc = w & 1;
  int quad = l >> 4, lm = l & 15;

  int Klen = K;
  if constexpr (EPI == 1) {
    if (n0 >= lensi[z]) Klen = 0;     // whole block masked: epilogue emits -INF
  }
  if (kb) Klen = kb[z];               // per-batch live-K bound (GEMM4)

  const short* Ahb = Agh + (long)z * sA;
  const short* Alb = Agl + (long)z * sA;
  const short* Bhb = BTh + (long)z * sBT;
  const short* Blb = BTl + (long)z * sBT;

  int srow = (w << 5) + (l >> 2);
  int scol = (((l & 3) ^ ((l >> 3) & 3)) << 3);   // swizzled global source chunk
  int wbase = (w << 10);
  int qs = ((quad ^ ((lm >> 1) & 3)) << 3);       // swizzled LDS read slot (shorts)

  auto STAGE = [&](int buf, int kk) {
    const short* gAh = Ahb + (long)(m0 + srow) * K + kk + scol;
    const short* gAl = Alb + (long)(m0 + srow) * K + kk + scol;
    const short* gBh = Bhb + (long)(n0 + srow) * K + kk + scol;
    const short* gBl = Blb + (long)(n0 + srow) * K + kk + scol;
    #pragma unroll
    for (int u = 0; u < 2; u++) {
      long go = (long)(u * 16) * K;
      gl16(gAh + go, &Ah[buf][wbase + (u << 9)]);
      gl16(gAl + go, &Al[buf][wbase + (u << 9)]);
      gl16(gBh + go, &Bh[buf][wbase + (u << 9)]);
      gl16(gBl + go, &Bl[buf][wbase + (u << 9)]);
    }
  };

  floatx4 acc[4][4];
  #pragma unroll
  for (int i = 0; i < 4; i++)
    #pragma unroll
    for (int j = 0; j < 4; j++) acc[i][j] = (floatx4){0.f, 0.f, 0.f, 0.f};

  if (Klen > 0) STAGE(0, 0);          // 8 loads in flight for buf0
  int cur = 0;

  for (int k0 = 0; k0 < Klen; k0 += BK) {
    int nxt = k0 + BK;
    if (nxt < Klen) {
      STAGE(cur ^ 1, nxt);                               // +8 loads (stay in flight)
      asm volatile("s_waitcnt vmcnt(8)" ::: "memory");   // buf[cur]'s 8 landed
    } else {
      asm volatile("s_waitcnt vmcnt(0)" ::: "memory");   // final tile: drain
    }
    __builtin_amdgcn_s_barrier();          // all waves: buf[cur] resident
    __builtin_amdgcn_sched_barrier(0);     // don't hoist ds_reads above barrier

    short8_t bfh[4], bfl[4];
    #pragma unroll
    for (int nj = 0; nj < 4; nj++) {
      int n = wc * 64 + nj * 16 + lm;
      bfh[nj] = *(const short8_t*)&Bh[cur][n * BK + qs];
      bfl[nj] = *(const short8_t*)&Bl[cur][n * BK + qs];
    }
    #pragma unroll
    for (int mi = 0; mi < 4; mi++) {
      int m = wr * 64 + mi * 16 + lm;
      short8_t afh = *(const short8_t*)&Ah[cur][m * BK + qs];
      short8_t afl = *(const short8_t*)&Al[cur][m * BK + qs];
      #pragma unroll
      for (int nj = 0; nj < 4; nj++) {
        acc[mi][nj] = __builtin_amdgcn_mfma_f32_16x16x32_bf16(afh, bfh[nj], acc[mi][nj], 0, 0, 0);
        acc[mi][nj] = __builtin_amdgcn_mfma_f32_16x16x32_bf16(afh, bfl[nj], acc[mi][nj], 0, 0, 0);
        acc[mi][nj] = __builtin_amdgcn_mfma_f32_16x16x32_bf16(afl, bfh[nj], acc[mi][nj], 0, 0, 0);
      }
    }
    __builtin_amdgcn_sched_barrier(0);     // don't sink ds_reads below barrier
    __builtin_amdgcn_s_barrier();          // all done reading buf[cur]; next iter restages it
    cur ^= 1;
  }

  float* Cb = Cm + (long)z * sC;
  short* Chb = Ch + (long)z * sC;
  short* Clb = Cl + (long)z * sC;

  if constexpr (EPI == 1) {
    // fused Poincare distance + mask: -2*atanh(m)/exp(scale)
    //   = nls * log2((1+m)*rcp(1-m)),  nls = -ln2/exp(scale)
    float nls = -0.69314718055994531f * frcp(expf(scalep[0]));
    float yv4[4]; float mk4[4]; int gn4[4];
    #pragma unroll
    for (int nj = 0; nj < 4; nj++) {
      int gn = n0 + wc * 64 + nj * 16 + lm;
      gn4[nj] = gn;
      yv4[nj] = y2a[(long)z * N + gn];
      mk4[nj] = fmask[(long)z * N + gn];
    }
    #pragma unroll
    for (int mi = 0; mi < 4; mi++) {
      #pragma unroll
      for (int r = 0; r < 4; r++) {
        int gm = m0 + wr * 64 + mi * 16 + quad * 4 + r;
        float xv = q2[(long)z * M + gm];
        #pragma unroll
        for (int nj = 0; nj < 4; nj++) {
          float c = acc[mi][nj][r];
          float yv = yv4[nj];
          float num = fmaxf(xv - 2.0f * c + yv, 0.0f);
          float den = fmaxf(fmaf(xv, yv, 1.0f - 2.0f * c), EPSV);
          float mm = sqrtf(num * frcp(den));
          float m = fminf(mm, CLIPV);
          float sc = nls * flog2((1.0f + m) * frcp(1.0f - m));
          if (mk4[nj] > 0.5f) sc = -INFINITY;
          Cb[(long)gm * N + gn4[nj]] = sc;
        }
      }
    }
  } else {
    #pragma unroll
    for (int mi = 0; mi < 4; mi++) {
      #pragma unroll
      for (int r = 0; r < 4; r++) {
        int gm = m0 + wr * 64 + mi * 16 + quad * 4 + r;
        #pragma unroll
        for (int nj = 0; nj < 4; nj++) {
          int gn = n0 + wc * 64 + nj * 16 + lm;
          float c = acc[mi][nj][r];
          if constexpr (EPI == 0) {
            Cb[(long)gm * N + gn] = c;
          } else {
            short hh, ll; bsplit(c, hh, ll);
            Chb[(long)gm * N + gn] = hh;
            Clb[(long)gm * N + gn] = ll;
          }
        }
      }
    }
  }
}

// ---------- q = msm(sqrt(.5), mobius_add(tgt, poincare_linear(x,w_in,b_in))) ----------
__global__ void k_q(short* gh, short* gl, const float* __restrict__ tgt,
                    const float* __restrict__ ch2, const float* __restrict__ sh2,
                    const float* __restrict__ rzn, const float* __restrict__ zn2,
                    const float* __restrict__ x2, float* __restrict__ q2) {
  __shared__ float red4[4];
  long row = blockIdx.x;
  int t = threadIdx.x;
  float cx2 = x2[row];
  float rdpl = 1.0f / fmaxf(1.0f - cx2, EPSV);
  float opc = 1.0f + cx2;

  float wv[3]; float sw2 = 0.f;
  #pragma unroll
  for (int j = 0; j < 3; j++) {
    int e = t + j * 256;
    float u = (bf2f(gh[row * EE + e]) + bf2f(gl[row * EE + e])) * rzn[e];
    float nm = fmaf(2.0f * u, ch2[e], -opc * sh2[e]);
    wv[j] = sinh_g_asinh(zn2[e], nm * rdpl);
    sw2 += wv[j] * wv[j];
  }
  sw2 = block_sum(sw2, red4);
  float rpden = 1.0f / (1.0f + sqrtf(1.0f + sw2));

  float pv[3], tv[3];
  float tp = 0.f, p2 = 0.f, t2 = 0.f;
  #pragma unroll
  for (int j = 0; j < 3; j++) {
    int e = t + j * 256;
    pv[j] = wv[j] * rpden;
    tv[j] = tgt[row * EE + e];
    tp += tv[j] * pv[j]; p2 += pv[j] * pv[j]; t2 += tv[j] * tv[j];
  }
  tp = block_sum(tp, red4);
  p2 = block_sum(p2, red4);
  t2 = block_sum(t2, red4);

  float rmden = 1.0f / fmaxf(1.0f + 2.0f * tp + t2 * p2, EPSV);
  float cT = 1.0f + 2.0f * tp + p2;
  float cP = 1.0f - t2;
  float av[3]; float n2 = 0.f;
  #pragma unroll
  for (int j = 0; j < 3; j++) { av[j] = (cT * tv[j] + cP * pv[j]) * rmden; n2 += av[j] * av[j]; }
  n2 = block_sum(n2, red4);

  float n = sqrtf(fmaxf(n2, EPSV));
  float f = tanh_r_atanh_over_n(0.70710678118654752f, n);
  #pragma unroll
  for (int j = 0; j < 3; j++) {
    int e = t + j * 256;
    short h, lo; bsplit(f * av[j], h, lo);
    gh[row * EE + e] = h; gl[row * EE + e] = lo;
  }
  if (t == 0) q2[row] = f * f * n2;
}

// ---------- softmax: scores are <= 0 (or -inf) by construction, so no max pass.
// reads f32 scores, writes attn hi/lo planes + den ----------
__global__ void k_softmax(const float* __restrict__ S, const float* __restrict__ gam,
                          float* __restrict__ denr,
                          short* __restrict__ ah, short* __restrict__ al) {
  __shared__ float red4[4];
  long row = blockIdx.x;
  int b = (int)(row / TT);
  int t = threadIdx.x;
  const float* rowp = S + row * SS;

  float v[4];
  float sum = 0.f;
  #pragma unroll
  for (int j = 0; j < 4; j++) {
    v[j] = fexp2(rowp[t + j * 256] * LOG2E);   // exp2(-inf)=0; scores bounded in [-~12.3, 0]
    sum += v[j];
  }
  sum = block_sum(sum, red4);
  float inv = (sum > 0.f) ? 1.0f / sum : 0.f;
  float ds = 0.f;
  #pragma unroll
  for (int j = 0; j < 4; j++) {
    int s = t + j * 256;
    float a = v[j] * inv;
    short h, lo; bsplit(a, h, lo);
    ah[row * SS + s] = h; al[row * SS + s] = lo;
    ds += a * (gam[(long)b * SS + s] - 1.0f);
  }
  ds = block_sum(ds, red4);
  if (t == 0) denr[row] = (inv == 0.f) ? 1.0f : ds;
}

// ---------- out2 = msm(sqrt(s_b), msm(0.5, nom/den)) — IN-PLACE on planes ----------
__global__ void k_mid(short* gh, short* gl, const float* __restrict__ denr,
                      const float* __restrict__ ssb, float* __restrict__ o2) {
  __shared__ float red4[4];
  long row = blockIdx.x;
  int b = (int)(row / TT);
  int t = threadIdx.x;
  float d = denr[row];
  if (fabsf(d) < 1e-10f) d = 1e-10f;
  float rd = 1.0f / d;

  float v[3]; float n2 = 0.f;
  #pragma unroll
  for (int j = 0; j < 3; j++) {
    int e = t + j * 256;
    v[j] = (bf2f(gh[row * EE + e]) + bf2f(gl[row * EE + e])) * rd;
    n2 += v[j] * v[j];
  }
  n2 = block_sum(n2, red4);
  float n = sqrtf(fmaxf(n2, EPSV));
  float m = fminf(n, CLIPV);
  float f1 = m / ((1.0f + sqrtf(fmaxf(1.0f - m * m, 0.0f))) * n);

  float m2 = 0.f;
  #pragma unroll
  for (int j = 0; j < 3; j++) { v[j] *= f1; m2 += v[j] * v[j]; }
  m2 = block_sum(m2, red4);
  float n1 = sqrtf(fmaxf(m2, EPSV));
  float f2 = tanh_r_atanh_over_n(ssb[b], n1);

  float s2 = 0.f;
  #pragma unroll
  for (int j = 0; j < 3; j++) {
    int e = t + j * 256;
    v[j] *= f2; s2 += v[j] * v[j];
    short h, lo; bsplit(v[j], h, lo);
    gh[row * EE + e] = h; gl[row * EE + e] = lo;
  }
  s2 = block_sum(s2, red4);
  if (t == 0) o2[row] = s2;
}

// ---------- final epilogue ----------
__global__ void k_final(const float* __restrict__ G, const float* __restrict__ xin,
                        const float* __restrict__ ch2, const float* __restrict__ sh2,
                        const float* __restrict__ rzn, const float* __restrict__ zn2,
                        const float* __restrict__ x2, const float* __restrict__ o2,
                        float* __restrict__ outp) {
  __shared__ float red4[4];
  long row = blockIdx.x;
  int t = threadIdx.x;
  float cx2 = o2[row];
  float rdpl = 1.0f / fmaxf(1.0f - cx2, EPSV);
  float opc = 1.0f + cx2;

  float wv[2]; float sw2 = 0.f;
  #pragma unroll
  for (int j = 0; j < 2; j++) {
    int c = t + j * 256;
    float u = G[row * CCH + c] * rzn[c];
    float nm = fmaf(2.0f * u, ch2[c], -opc * sh2[c]);
    wv[j] = sinh_g_asinh(zn2[c], nm * rdpl);
    sw2 += wv[j] * wv[j];
  }
  sw2 = block_sum(sw2, red4);
  float rpden = 1.0f / (1.0f + sqrtf(1.0f + sw2));

  float pv[2], xv[2];
  float xp = 0.f, p2 = 0.f;
  #pragma unroll
  for (int j = 0; j < 2; j++) {
    int c = t + j * 256;
    pv[j] = wv[j] * rpden;
    xv[j] = xin[row * CCH + c];
    xp += xv[j] * pv[j]; p2 += pv[j] * pv[j];
  }
  xp = block_sum(xp, red4);
  p2 = block_sum(p2, red4);

  float xx = x2[row];
  float rmden = 1.0f / fmaxf(1.0f + 2.0f * xp + xx * p2, EPSV);
  float cX = 1.0f + 2.0f * xp + p2;
  float cP = 1.0f - xx;
  float av[2]; float n2 = 0.f;
  #pragma unroll
  for (int j = 0; j < 2; j++) { av[j] = (cX * xv[j] + cP * pv[j]) * rmden; n2 += av[j] * av[j]; }
  n2 = block_sum(n2, red4);

  float n = sqrtf(fmaxf(n2, EPSV));
  float f = tanh_r_atanh_over_n(0.70710678118654752f, n);
  #pragma unroll
  for (int j = 0; j < 2; j++) { int c = t + j * 256; outp[row * CCH + c] = f * av[j]; }
}

extern "C" void kernel_launch(void* const* d_in, const int* in_sizes, int n_in,
                              void* d_out, int out_size, void* d_ws, size_t ws_size,
                              hipStream_t stream) {
  const float* x    = (const float*)d_in[0];
  const float* tgt  = (const float*)d_in[1];
  const float* enca = (const float*)d_in[2];
  const float* encb = (const float*)d_in[3];
  const void*  mraw = d_in[4];
  const float* win  = (const float*)d_in[5];
  const float* bin  = (const float*)d_in[6];
  const float* wout = (const float*)d_in[7];
  const float* bout = (const float*)d_in[8];
  const float* scalep = (const float*)d_in[9];

  float* out_main = (float*)d_out;                       // [B,T,CCH] f32 (33.55 MB)
  float* out_attn = out_main + (long)BB * TT * CCH;      // [B,T,S]  f32 (67.11 MB)

  // ---- d_out scratch aliases ----
  short* xh  = (short*)out_attn;
  short* xl  = xh + (long)BB * TT * CCH;
  short* G4h = (short*)out_attn;
  short* G4l = G4h + (long)BB * TT * EE;
  short* ATh = (short*)out_main;

  // ---- workspace (same proven budget) ----
  char* wb = (char*)d_ws;
  short* P0   = (short*)wb;  wb += (long)BB * TT * EE * 2;
  short* P1   = (short*)wb;  wb += (long)BB * TT * EE * 2;
  short* G1h = P0, *G1l = P1;
  short* ATl = P0;
  short* tspH = (short*)wb;  wb += (long)BB * SS * EE * 2;
  short* tspL = (short*)wb;  wb += (long)BB * SS * EE * 2;
  float* Gw   = (float*)tspH;
  short* winTh  = (short*)wb;  wb += (long)CCH * EE * 2;
  short* winTl  = (short*)wb;  wb += (long)CCH * EE * 2;
  short* woutTh = (short*)wb;  wb += (long)EE * CCH * 2;
  short* woutTl = (short*)wb;  wb += (long)EE * CCH * 2;
  float* sm     = (float*)wb;
  float* x2a  = sm; sm += BB * TT;
  float* q2a  = sm; sm += BB * TT;
  float* y2a  = sm; sm += BB * SS;
  float* gam  = sm; sm += BB * SS;
  float* denr = sm; sm += BB * TT;
  float* o2a  = sm; sm += BB * TT;
  float* ssb  = sm; sm += BB;
  float* fmask= sm; sm += BB * SS;
  float* ch2i = sm; sm += EE;
  float* sh2i = sm; sm += EE;
  float* rzni = sm; sm += EE;
  float* zn2i = sm; sm += EE;
  float* ch2o = sm; sm += CCH;
  float* sh2o = sm; sm += CCH;
  float* rzno = sm; sm += CCH;
  float* zn2o = sm; sm += CCH;
  int*   lensi= (int*)sm; sm += BB;
  int*   kbi  = (int*)sm; sm += BB;
  int*   mflag= (int*)sm; sm += 1;

  // mask canonicalization (det -> fused conv + len/ssb/Keff)
  k_maskdet<<<1, 256, 0, stream>>>((const unsigned char*)mraw, mflag);
  k_maskrow<<<BB, 256, 0, stream>>>(mraw, mflag, fmask, ssb, lensi, kbi);

  // fused weight prep (both col-norms + trig invariants + y2a zero-init)
  k_wprep<<<EE + CCH, 256, 0, stream>>>(win, wout, bin, bout,
                                        ch2i, sh2i, rzni, zn2i,
                                        ch2o, sh2o, rzno, zn2o, y2a);
  k_gamma<<<BB * SS, 256, 0, stream>>>(encb, gam);

  // weight transposes + split
  k_tsp<<<dim3(EE / 32, CCH / 32, 1), dim3(32, 8), 0, stream>>>(
      win, winTh, winTl, nullptr, CCH, EE, 0, 0, nullptr);
  k_tsp<<<dim3(CCH / 32, EE / 32, 1), dim3(32, 8), 0, stream>>>(
      wout, woutTh, woutTl, nullptr, EE, CCH, 0, 0, nullptr);

  // enc_a [E,S] -> eaT [S,E] hi/lo, with fused y2a column-sum (atomic)
  k_tsp<<<dim3(SS / 32, EE / 32, BB), dim3(32, 8), 0, stream>>>(
      enca, tspH, tspL, nullptr, EE, SS, (long)EE * SS, (long)SS * EE, y2a);

  // fused x prep: planes (GEMM1 A, in out_attn region) + x2a, x read once
  k_xprep<<<BB * TT, 256, 0, stream>>>(x, xh, xl, x2a);

  // GEMM1: x @ w_in -> G1 planes (P0/P1)
  mgemm<2><<<dim3(EE / BN, BB * TT / BM, 1), 256, 0, stream>>>(
      xh, xl, winTh, winTl, nullptr, G1h, G1l, BB * TT, EE, CCH, 0, 0, 0,
      nullptr, nullptr, nullptr, nullptr, nullptr, nullptr);

  // k_q: in-place G1 planes -> q planes (+ q2)
  k_q<<<BB * TT, 256, 0, stream>>>(G1h, G1l, tgt, ch2i, sh2i, rzni, zn2i, x2a, q2a);

  // GEMM2 (batched) + dist epilogue: scores -> out_attn f32; dead N-blocks Klen=0
  mgemm<1><<<dim3(SS / BN, TT / BM, BB), 256, 0, stream>>>(
      G1h, G1l, tspH, tspL, out_attn, nullptr, nullptr, TT, SS, EE,
      (long)TT * EE, (long)SS * EE, (long)TT * SS, q2a, y2a, fmask, scalep,
      lensi, nullptr);

  // enc_b [S,E] scaled by gamma -> ebT [E,S] hi/lo (overwrites eaT)
  k_tsp<<<dim3(EE / 32, SS / 32, BB), dim3(32, 8), 0, stream>>>(
      encb, tspH, tspL, gam, SS, EE, (long)SS * EE, (long)EE * SS, nullptr);

  // softmax (no max pass): scores f32 -> attn planes (ATh out_main, ATl pool) + denr
  k_softmax<<<BB * TT, 256, 0, stream>>>(out_attn, gam, denr, ATh, ATl);

  // GEMM4 (batched): attn @ (gamma*enc_b) -> G4 planes; K trimmed to live columns
  mgemm<2><<<dim3(EE / BN, TT / BM, BB), 256, 0, stream>>>(
      ATh, ATl, tspH, tspL, nullptr, G4h, G4l, TT, EE, SS,
      (long)TT * SS, (long)EE * SS, (long)TT * EE, nullptr, nullptr, nullptr, nullptr,
      nullptr, kbi);

  // k_mid: in-place G4 planes -> M planes (+ o2)
  k_mid<<<BB * TT, 256, 0, stream>>>(G4h, G4l, denr, ssb, o2a);

  // GEMM5: M @ w_out -> Gw f32 (T region; ebT dead)
  mgemm<0><<<dim3(CCH / BN, BB * TT / BM, 1), 256, 0, stream>>>(
      G4h, G4l, woutTh, woutTl, Gw, nullptr, nullptr, BB * TT, CCH, EE, 0, 0, 0,
      nullptr, nullptr, nullptr, nullptr, nullptr, nullptr);

  // reconstruct attn f32 output from planes
  k_rec<<<(int)((long)BB * TT * SS / 4 / 256), 256, 0, stream>>>(
      ATh, ATl, out_attn, (long)BB * TT * SS / 4);

  // final epilogue (overwrites out_main)
  k_final<<<BB * TT, 256, 0, stream>>>(Gw, x, ch2o, sh2o, rzno, zn2o, x2a, o2a, out_main);
}